// Round 3
// baseline (1011.094 us; speedup 1.0000x reference)
//
#include <hip/hip_runtime.h>

#define NPAR 384
#define NEPI 384
#define DD   256

using bf16x8 = __bf16 __attribute__((ext_vector_type(8)));
using f32x4  = float __attribute__((ext_vector_type(4)));

__device__ __forceinline__ float sigm(float x) { return 1.0f / (1.0f + __expf(-x)); }
__device__ __forceinline__ float silu(float x) { return x / (1.0f + __expf(-x)); }
__device__ __forceinline__ unsigned short f2bf(float f) {
  unsigned u = __float_as_uint(f);
  u += 0x7fffu + ((u >> 16) & 1u);
  return (unsigned short)(u >> 16);
}
__device__ __forceinline__ float bf2f(unsigned short h) {
  return __uint_as_float(((unsigned)h) << 16);
}
__device__ __forceinline__ uint2 pack4(float a, float b, float c, float d) {
  uint2 r;
  r.x = (unsigned)f2bf(a) | ((unsigned)f2bf(b) << 16);
  r.y = (unsigned)f2bf(c) | ((unsigned)f2bf(d) << 16);
  return r;
}

// ---------------- precompute kernels ----------------

__global__ void fold_kernel(const float* __restrict__ res_w2, const float* __restrict__ atom_w2,
                            const float* __restrict__ int_w1, const float* __restrict__ simw,
                            float* __restrict__ MrF, float* __restrict__ MaF) {
  const int i = blockIdx.x & 255;
  const bool isMa = blockIdx.x >= 256;
  const float wmix = 1.0f / (1.0f + __expf(-simw[0]));
  const float sc = isMa ? (1.0f - wmix) : wmix;
  const float* W2 = isMa ? atom_w2 : res_w2;
  const int j = threadIdx.x;
  float acc = 0.f;
  for (int k = 0; k < 256; ++k)
    acc += W2[i * 256 + k] * int_w1[(512 + k) * 256 + j];
  (isMa ? MaF : MrF)[i * 256 + j] = acc * sc;
}

__global__ void cvec_kernel(const float* __restrict__ res_b2, const float* __restrict__ atom_b2,
                            const float* __restrict__ int_b1, const float* __restrict__ int_w1,
                            const float* __restrict__ simw, float* __restrict__ cvec) {
  const int j = threadIdx.x;
  const float wmix = 1.0f / (1.0f + __expf(-simw[0]));
  float acc = int_b1[j];
  for (int k = 0; k < 256; ++k) {
    float bm = wmix * res_b2[k] + (1.0f - wmix) * atom_b2[k];
    acc += bm * int_w1[(512 + k) * 256 + j];
  }
  cvec[j] = acc;
}

// 32x32-tiled transpose: AT[i][j] = A[j][i], 256x256
__global__ void transpose_k(const float* __restrict__ A, float* __restrict__ AT) {
  __shared__ float tile[32][33];
  const int bx = blockIdx.x & 7, by = blockIdx.x >> 3;
  const int tx = threadIdx.x & 31, ty = threadIdx.x >> 5;
  for (int r = 0; r < 32; r += 8)
    tile[ty + r][tx] = A[(by * 32 + ty + r) * 256 + bx * 32 + tx];
  __syncthreads();
  for (int r = 0; r < 32; r += 8)
    AT[(bx * 32 + ty + r) * 256 + by * 32 + tx] = tile[tx][ty + r];
}

// g[d] = sum_c wk[d,c] * bq[c]
__global__ void gvec_kernel(const float* __restrict__ wk, const float* __restrict__ bq,
                            float* __restrict__ gv) {
  const int d = threadIdx.x;
  float acc = 0.f;
  for (int c = 0; c < 256; ++c) acc += wk[d * 256 + c] * bq[c];
  gv[d] = acc;
}

// pack 5 [256,256] matrices into MFMA fragment order:
// wpack[m][((ks*16+tile)*64 + lane)*8 + j] = W[k = ks*32 + (lane>>4)*8 + j][n = tile*16 + (lane&15)]
// slots: 0=Mr 1=Ma 2=int_w2 3=wg 4=Wqk
__global__ void pack_kernel(const float* __restrict__ MrF, const float* __restrict__ MaF,
                            const float* __restrict__ w2, const float* __restrict__ wg,
                            const float* __restrict__ WqkF, unsigned short* __restrict__ wpack) {
  const int idx = blockIdx.x * 256 + threadIdx.x;
  const int m = idx >> 16;
  const int r = idx & 65535;
  const int chunk = r >> 9;
  const int lane = (r >> 3) & 63;
  const int j = r & 7;
  const int k = (chunk >> 4) * 32 + (lane >> 4) * 8 + j;
  const int n = (chunk & 15) * 16 + (lane & 15);
  const float* src;
  switch (m) {
    case 0: src = MrF; break;
    case 1: src = MaF; break;
    case 2: src = w2; break;
    case 3: src = wg; break;
    default: src = WqkF; break;
  }
  wpack[idx] = f2bf(src[k * 256 + n]);
}

// C[r][j] = sum_k A[r][k] * B[k][j]  (grid = #rows)
__global__ void mm_rows(const float* __restrict__ A, const float* __restrict__ B,
                        float* __restrict__ C) {
  const int r = blockIdx.x, j = threadIdx.x;
  float acc = 0.f;
  for (int k = 0; k < 256; ++k)
    acc += A[r * 256 + k] * B[k * 256 + j];
  C[r * 256 + j] = acc;
}

// ---------------- pairwise GEMM-chain kernel ----------------

__device__ __forceinline__ void zero_acc(f32x4 (&acc)[4][8]) {
#pragma unroll
  for (int mt = 0; mt < 4; ++mt)
#pragma unroll
    for (int nt = 0; nt < 8; ++nt)
      acc[mt][nt] = (f32x4){0.f, 0.f, 0.f, 0.f};
}

// transposed-acc trick: mfma(Wfrag, ActFrag) -> acc^T[d][e]
// d = wv*64 + mt*16 + l4*4 + r, e = nt*16 + l15
__device__ __forceinline__ void gemm_k256(f32x4 (&acc)[4][8],
                                          const unsigned short* __restrict__ wp,
                                          const unsigned short* ub, int lane, int wv) {
  const int l15 = lane & 15, l4 = lane >> 4;
#pragma unroll
  for (int ks = 0; ks < 8; ++ks) {
    bf16x8 a[4];
#pragma unroll
    for (int mt = 0; mt < 4; ++mt)
      a[mt] = *reinterpret_cast<const bf16x8*>(wp + ((ks * 16 + wv * 4 + mt) * 64 + lane) * 8);
#pragma unroll
    for (int nt = 0; nt < 8; ++nt) {
      bf16x8 b = *reinterpret_cast<const bf16x8*>(ub + (nt * 16 + l15) * 264 + ks * 32 + l4 * 8);
#pragma unroll
      for (int mt = 0; mt < 4; ++mt)
        acc[mt][nt] = __builtin_amdgcn_mfma_f32_16x16x32_bf16(a[mt], b, acc[mt][nt], 0, 0, 0);
    }
  }
}

__global__ __launch_bounds__(256, 2) void pair_kernel(
    const float* __restrict__ Xg,
    const float* __restrict__ res_w1, const float* __restrict__ res_b1,
    const float* __restrict__ atom_w1, const float* __restrict__ atom_b1,
    const float* __restrict__ int_b2, const float* __restrict__ wg_b,
    const unsigned short* __restrict__ wpack, const float* __restrict__ cvec,
    const float* __restrict__ gv,
    const float* __restrict__ P1, const float* __restrict__ P2,
    const float* __restrict__ Hpl, const float* __restrict__ Her,
    float* __restrict__ ftri, float* __restrict__ vbuf,
    unsigned short* __restrict__ Zg) {
  __shared__ __align__(16) unsigned short ubuf[128 * 264];
  __shared__ float Sv[128];
  __shared__ float pc[DD];
  __shared__ float vred[512];
  const int t = threadIdx.x, lane = t & 63, wv = t >> 6;
  const int l15 = lane & 15, l4 = lane >> 4;
  const int p = blockIdx.x / 3, e0 = (blockIdx.x % 3) * 128;
  const int d0 = wv * 64;

  if (t < 128) {
    const int e = e0 + t;
    float dx = Xg[p * 42 + 3] - Xg[(NPAR + e) * 42 + 3];
    float dy = Xg[p * 42 + 4] - Xg[(NPAR + e) * 42 + 4];
    float dz = Xg[p * 42 + 5] - Xg[(NPAR + e) * 42 + 5];
    Sv[t] = dx * dx + dy * dy + dz * dz;
  }
  pc[t] = P1[p * DD + t] + cvec[t];
  __syncthreads();

  f32x4 acc[4][8];
  zero_acc(acc);

  // fill u_r
  {
    const f32x4 w1q = *reinterpret_cast<const f32x4*>(&res_w1[lane * 4]);
    const f32x4 b1q = *reinterpret_cast<const f32x4*>(&res_b1[lane * 4]);
#pragma unroll 4
    for (int e = wv; e < 128; e += 4) {
      const float s = Sv[e];
      uint2 pk = pack4(silu(fmaf(s, w1q[0], b1q[0])), silu(fmaf(s, w1q[1], b1q[1])),
                       silu(fmaf(s, w1q[2], b1q[2])), silu(fmaf(s, w1q[3], b1q[3])));
      *reinterpret_cast<uint2*>(&ubuf[e * 264 + lane * 4]) = pk;
    }
  }
  __syncthreads();
  gemm_k256(acc, wpack + 0 * 65536, ubuf, lane, wv);
  __syncthreads();
  // fill u_a
  {
    const f32x4 w1q = *reinterpret_cast<const f32x4*>(&atom_w1[lane * 4]);
    const f32x4 b1q = *reinterpret_cast<const f32x4*>(&atom_b1[lane * 4]);
#pragma unroll 4
    for (int e = wv; e < 128; e += 4) {
      const float s = Sv[e];
      uint2 pk = pack4(silu(fmaf(s, w1q[0], b1q[0])), silu(fmaf(s, w1q[1], b1q[1])),
                       silu(fmaf(s, w1q[2], b1q[2])), silu(fmaf(s, w1q[3], b1q[3])));
      *reinterpret_cast<uint2*>(&ubuf[e * 264 + lane * 4]) = pk;
    }
  }
  __syncthreads();
  gemm_k256(acc, wpack + 1 * 65536, ubuf, lane, wv);
  __syncthreads();

  // epilogue: h = silu(zpre^T + pc[d] + P2[e][d]) -> ubuf[e][d]
#pragma unroll
  for (int mt = 0; mt < 4; ++mt) {
    const int d = d0 + mt * 16 + l4 * 4;
    const f32x4 pcv = *reinterpret_cast<const f32x4*>(&pc[d]);
#pragma unroll
    for (int nt = 0; nt < 8; ++nt) {
      const int e = nt * 16 + l15;
      const f32x4 p2v = *reinterpret_cast<const f32x4*>(&P2[(e0 + e) * DD + d]);
      uint2 pk = pack4(silu(acc[mt][nt][0] + pcv[0] + p2v[0]),
                       silu(acc[mt][nt][1] + pcv[1] + p2v[1]),
                       silu(acc[mt][nt][2] + pcv[2] + p2v[2]),
                       silu(acc[mt][nt][3] + pcv[3] + p2v[3]));
      *reinterpret_cast<uint2*>(&ubuf[e * 264 + d]) = pk;
    }
  }
  __syncthreads();

  // Z = h @ int_w2 + int_b2 -> ubuf + Zg; also v[e] = Z[e,:] . gv
  zero_acc(acc);
  gemm_k256(acc, wpack + 2 * 65536, ubuf, lane, wv);
  __syncthreads();
  {
    float vp[8] = {0.f, 0.f, 0.f, 0.f, 0.f, 0.f, 0.f, 0.f};
#pragma unroll
    for (int mt = 0; mt < 4; ++mt) {
      const int d = d0 + mt * 16 + l4 * 4;
      const f32x4 bb = *reinterpret_cast<const f32x4*>(&int_b2[d]);
      const f32x4 gq = *reinterpret_cast<const f32x4*>(&gv[d]);
#pragma unroll
      for (int nt = 0; nt < 8; ++nt) {
        const int e = nt * 16 + l15;
        float z0 = acc[mt][nt][0] + bb[0];
        float z1 = acc[mt][nt][1] + bb[1];
        float z2 = acc[mt][nt][2] + bb[2];
        float z3 = acc[mt][nt][3] + bb[3];
        uint2 pk = pack4(z0, z1, z2, z3);
        *reinterpret_cast<uint2*>(&ubuf[e * 264 + d]) = pk;
        *reinterpret_cast<uint2*>(&Zg[(size_t)(p * NEPI + e0 + e) * DD + d]) = pk;
        vp[nt] += z0 * gq[0] + z1 * gq[1] + z2 * gq[2] + z3 * gq[3];
      }
    }
#pragma unroll
    for (int nt = 0; nt < 8; ++nt) {
      float v = vp[nt];
      v += __shfl_xor(v, 16);
      v += __shfl_xor(v, 32);
      if (lane < 16) vred[wv * 128 + nt * 16 + lane] = v;
    }
  }
  __syncthreads();
  if (t < 128)
    vbuf[p * NEPI + e0 + t] = vred[t] + vred[128 + t] + vred[256 + t] + vred[384 + t];

  // gate: f_tri[d] += sum_e sigm(Zg^T + b) * Hpl[p][d] * Her[e][d]
  zero_acc(acc);
  gemm_k256(acc, wpack + 3 * 65536, ubuf, lane, wv);
#pragma unroll
  for (int mt = 0; mt < 4; ++mt) {
    const int d = d0 + mt * 16 + l4 * 4;
    const f32x4 bb = *reinterpret_cast<const f32x4*>(&wg_b[d]);
    const f32x4 hl = *reinterpret_cast<const f32x4*>(&Hpl[p * DD + d]);
    f32x4 fs = (f32x4){0.f, 0.f, 0.f, 0.f};
#pragma unroll
    for (int nt = 0; nt < 8; ++nt) {
      const int e = e0 + nt * 16 + l15;
      const f32x4 hr = *reinterpret_cast<const f32x4*>(&Her[e * DD + d]);
#pragma unroll
      for (int r = 0; r < 4; ++r)
        fs[r] += sigm(acc[mt][nt][r] + bb[r]) * hl[r] * hr[r];
    }
#pragma unroll
    for (int r = 0; r < 4; ++r) {
      float v = fs[r];
      v += __shfl_xor(v, 1);
      v += __shfl_xor(v, 2);
      v += __shfl_xor(v, 4);
      v += __shfl_xor(v, 8);
      if (l15 == 0) atomicAdd(&ftri[p * DD + d + r], v);
    }
  }
}

// ---------------- fused attention kernel: block = (p, 64-row chunk) ----------------
// scores = (Z_c Wqk Z^T + 1 v^T) / 16 ; col-sums of softmax -> cbufg[p]

__global__ __launch_bounds__(256, 1) void attn_kernel(
    const unsigned short* __restrict__ Zg, const float* __restrict__ vbuf,
    const unsigned short* __restrict__ wpack, float* __restrict__ cbufg) {
  __shared__ __align__(16) unsigned short Zc[64 * 264];
  __shared__ __align__(16) unsigned short Tc[64 * 264];
  __shared__ __align__(16) unsigned short Zf[128 * 264];
  __shared__ float vb[NEPI];
  __shared__ float red[256];
  __shared__ float red2[256];
  const int t = threadIdx.x, lane = t & 63, wv = t >> 6;
  const int l15 = lane & 15, l4 = lane >> 4;
  // XCD swizzle: all 6 chunks of one p land on the same XCD (xcd = blk % 8)
  const int xcd = blockIdx.x & 7, inner = blockIdx.x >> 3;
  const int p = (inner / 6) * 8 + xcd, c = inner % 6;
  const unsigned short* Zp = Zg + (size_t)p * NEPI * DD;
  const unsigned short* wqk = wpack + 4 * 65536;

  // stage this chunk's 64 Z rows
#pragma unroll
  for (int i = 0; i < 8; ++i) {
    const int idx = i * 256 + t;
    const int row = idx >> 5, c16 = idx & 31;
    *reinterpret_cast<uint4*>(&Zc[row * 264 + c16 * 8]) =
        *reinterpret_cast<const uint4*>(&Zp[(c * 64 + row) * DD + c16 * 8]);
  }
  for (int i = t; i < NEPI; i += 256) vb[i] = vbuf[p * NEPI + i];
  __syncthreads();

  // T = Zc @ Wqk  (transposed acc: lane holds 4 contiguous d for one e)
  {
    f32x4 ta[4][4];
#pragma unroll
    for (int mt = 0; mt < 4; ++mt)
#pragma unroll
      for (int nt = 0; nt < 4; ++nt) ta[mt][nt] = (f32x4){0.f, 0.f, 0.f, 0.f};
#pragma unroll
    for (int ks = 0; ks < 8; ++ks) {
      bf16x8 a[4];
#pragma unroll
      for (int mt = 0; mt < 4; ++mt)
        a[mt] = *reinterpret_cast<const bf16x8*>(wqk + ((ks * 16 + wv * 4 + mt) * 64 + lane) * 8);
#pragma unroll
      for (int nt = 0; nt < 4; ++nt) {
        bf16x8 b = *reinterpret_cast<const bf16x8*>(&Zc[(nt * 16 + l15) * 264 + ks * 32 + l4 * 8]);
#pragma unroll
        for (int mt = 0; mt < 4; ++mt)
          ta[mt][nt] = __builtin_amdgcn_mfma_f32_16x16x32_bf16(a[mt], b, ta[mt][nt], 0, 0, 0);
      }
    }
#pragma unroll
    for (int mt = 0; mt < 4; ++mt) {
      const int d = wv * 64 + mt * 16 + l4 * 4;
#pragma unroll
      for (int nt = 0; nt < 4; ++nt) {
        const int e = nt * 16 + l15;
        *reinterpret_cast<uint2*>(&Tc[e * 264 + d]) =
            pack4(ta[mt][nt][0], ta[mt][nt][1], ta[mt][nt][2], ta[mt][nt][3]);
      }
    }
  }
  __syncthreads();

  // S = Tc @ Z^T over 3 staged f-tiles of 128; wave wv owns f = s*128 + wv*32 + {0..31}
  f32x4 sc[4][6];
#pragma unroll
  for (int mt = 0; mt < 4; ++mt)
#pragma unroll
    for (int j = 0; j < 6; ++j) sc[mt][j] = (f32x4){0.f, 0.f, 0.f, 0.f};

  for (int s = 0; s < 3; ++s) {
#pragma unroll
    for (int i = 0; i < 16; ++i) {
      const int idx = i * 256 + t;
      const int row = idx >> 5, c16 = idx & 31;
      *reinterpret_cast<uint4*>(&Zf[row * 264 + c16 * 8]) =
          *reinterpret_cast<const uint4*>(&Zp[(s * 128 + row) * DD + c16 * 8]);
    }
    __syncthreads();
#pragma unroll
    for (int ks = 0; ks < 8; ++ks) {
      bf16x8 a[4], b[2];
#pragma unroll
      for (int mt = 0; mt < 4; ++mt)
        a[mt] = *reinterpret_cast<const bf16x8*>(&Tc[(mt * 16 + l15) * 264 + ks * 32 + l4 * 8]);
#pragma unroll
      for (int j2 = 0; j2 < 2; ++j2)
        b[j2] = *reinterpret_cast<const bf16x8*>(&Zf[(wv * 32 + j2 * 16 + l15) * 264 + ks * 32 + l4 * 8]);
#pragma unroll
      for (int j2 = 0; j2 < 2; ++j2)
#pragma unroll
        for (int mt = 0; mt < 4; ++mt)
          sc[mt][s * 2 + j2] =
              __builtin_amdgcn_mfma_f32_16x16x32_bf16(a[mt], b[j2], sc[mt][s * 2 + j2], 0, 0, 0);
    }
    __syncthreads();
  }

  // softmax over f (384 cols), rows e = mt*16 + l4*4 + r
  const float scl = 0.0625f;
  float fv[6];
#pragma unroll
  for (int j = 0; j < 6; ++j)
    fv[j] = vb[(j >> 1) * 128 + wv * 32 + (j & 1) * 16 + l15];

  float rmax[4][4];
#pragma unroll
  for (int mt = 0; mt < 4; ++mt) {
#pragma unroll
    for (int r = 0; r < 4; ++r) {
      float m = -1e30f;
#pragma unroll
      for (int j = 0; j < 6; ++j) {
        sc[mt][j][r] = (sc[mt][j][r] + fv[j]) * scl;
        m = fmaxf(m, sc[mt][j][r]);
      }
      m = fmaxf(m, __shfl_xor(m, 1));
      m = fmaxf(m, __shfl_xor(m, 2));
      m = fmaxf(m, __shfl_xor(m, 4));
      m = fmaxf(m, __shfl_xor(m, 8));
      rmax[mt][r] = m;
    }
  }
  if (l15 == 0) {
#pragma unroll
    for (int mt = 0; mt < 4; ++mt)
#pragma unroll
      for (int r = 0; r < 4; ++r)
        red[wv * 64 + mt * 16 + l4 * 4 + r] = rmax[mt][r];
  }
  __syncthreads();
#pragma unroll
  for (int mt = 0; mt < 4; ++mt) {
#pragma unroll
    for (int r = 0; r < 4; ++r) {
      const int row = mt * 16 + l4 * 4 + r;
      rmax[mt][r] = fmaxf(fmaxf(red[row], red[64 + row]), fmaxf(red[128 + row], red[192 + row]));
    }
  }

  float rsum[4][4];
#pragma unroll
  for (int mt = 0; mt < 4; ++mt) {
#pragma unroll
    for (int r = 0; r < 4; ++r) {
      float sSum = 0.f;
#pragma unroll
      for (int j = 0; j < 6; ++j) {
        float e = __expf(sc[mt][j][r] - rmax[mt][r]);
        sc[mt][j][r] = e;
        sSum += e;
      }
      sSum += __shfl_xor(sSum, 1);
      sSum += __shfl_xor(sSum, 2);
      sSum += __shfl_xor(sSum, 4);
      sSum += __shfl_xor(sSum, 8);
      rsum[mt][r] = sSum;
    }
  }
  if (l15 == 0) {
#pragma unroll
    for (int mt = 0; mt < 4; ++mt)
#pragma unroll
      for (int r = 0; r < 4; ++r)
        red2[wv * 64 + mt * 16 + l4 * 4 + r] = rsum[mt][r];
  }
  __syncthreads();
  float rinv[4][4];
#pragma unroll
  for (int mt = 0; mt < 4; ++mt) {
#pragma unroll
    for (int r = 0; r < 4; ++r) {
      const int row = mt * 16 + l4 * 4 + r;
      rinv[mt][r] = 1.0f / (red2[row] + red2[64 + row] + red2[128 + row] + red2[192 + row]);
    }
  }

  // column sums of A over this chunk's 64 rows -> cbufg
#pragma unroll
  for (int j = 0; j < 6; ++j) {
    float v = 0.f;
#pragma unroll
    for (int mt = 0; mt < 4; ++mt)
#pragma unroll
      for (int r = 0; r < 4; ++r)
        v += sc[mt][j][r] * rinv[mt][r];
    v += __shfl_xor(v, 16);
    v += __shfl_xor(v, 32);
    if (lane < 16)
      atomicAdd(&cbufg[p * NEPI + (j >> 1) * 128 + wv * 32 + (j & 1) * 16 + lane], v);
  }
}

// ---------------- output kernel ----------------
// out[p] = (ftri[p] + (c^T Z_p) @ wv + 384*bv) / 384

__global__ __launch_bounds__(256) void out_kernel(
    const unsigned short* __restrict__ Zg, const float* __restrict__ ftri,
    const float* __restrict__ cbufg, const float* __restrict__ wvw,
    const float* __restrict__ wvb, float* __restrict__ out) {
  __shared__ float cb[NEPI];
  __shared__ float u[DD];
  const int p = blockIdx.x, t = threadIdx.x;
  for (int i = t; i < NEPI; i += 256) cb[i] = cbufg[p * NEPI + i];
  __syncthreads();
  const unsigned short* Zp = Zg + (size_t)p * NEPI * DD;
  float a0 = 0.f, a1 = 0.f, a2 = 0.f, a3 = 0.f;
  for (int f = 0; f < NEPI; f += 4) {
    a0 = fmaf(cb[f + 0], bf2f(Zp[(f + 0) * DD + t]), a0);
    a1 = fmaf(cb[f + 1], bf2f(Zp[(f + 1) * DD + t]), a1);
    a2 = fmaf(cb[f + 2], bf2f(Zp[(f + 2) * DD + t]), a2);
    a3 = fmaf(cb[f + 3], bf2f(Zp[(f + 3) * DD + t]), a3);
  }
  u[t] = a0 + a1 + a2 + a3;
  __syncthreads();
  float acc = ftri[p * DD + t] + 384.0f * wvb[t];
  for (int d = 0; d < DD; ++d)
    acc = fmaf(u[d], wvw[d * DD + t], acc);
  out[p * DD + t] = acc * (1.0f / 384.0f);
}

// ---------------- launch ----------------

extern "C" void kernel_launch(void* const* d_in, const int* in_sizes, int n_in,
                              void* d_out, int out_size, void* d_ws, size_t ws_size,
                              hipStream_t stream) {
  (void)in_sizes; (void)n_in; (void)out_size; (void)ws_size;
  const float* H = (const float*)d_in[0];
  const float* X = (const float*)d_in[1];
  const float* res_w1 = (const float*)d_in[4];
  const float* res_b1 = (const float*)d_in[5];
  const float* res_w2 = (const float*)d_in[6];
  const float* res_b2 = (const float*)d_in[7];
  const float* atom_w1 = (const float*)d_in[8];
  const float* atom_b1 = (const float*)d_in[9];
  const float* atom_w2 = (const float*)d_in[10];
  const float* atom_b2 = (const float*)d_in[11];
  const float* simw = (const float*)d_in[12];
  const float* int_w1 = (const float*)d_in[13];
  const float* int_b1 = (const float*)d_in[14];
  const float* int_w2 = (const float*)d_in[15];
  const float* int_b2 = (const float*)d_in[16];
  const float* wl = (const float*)d_in[17];
  const float* wr = (const float*)d_in[18];
  const float* wg_w = (const float*)d_in[19];
  const float* wg_b = (const float*)d_in[20];
  const float* wq_w = (const float*)d_in[21];
  const float* wk_w = (const float*)d_in[23];
  const float* wk_b = (const float*)d_in[24];
  const float* wv_w = (const float*)d_in[25];
  const float* wv_b = (const float*)d_in[26];
  const float* wq_b = (const float*)d_in[22];

  char* ws = (char*)d_ws;
  unsigned short* wpack = (unsigned short*)(ws + 0);      //  655360 B (5 slots)
  float* MrF   = (float*)(ws + 655360);
  float* MaF   = (float*)(ws + 917504);
  float* WqkF  = (float*)(ws + 1179648);
  float* wkT   = (float*)(ws + 1441792);
  float* cvec  = (float*)(ws + 1703936);
  float* gv    = (float*)(ws + 1704960);
  float* P1    = (float*)(ws + 1705984);
  float* P2    = (float*)(ws + 2099200);
  float* Hpl   = (float*)(ws + 2492416);
  float* Her   = (float*)(ws + 2885632);
  float* ftri  = (float*)(ws + 3278848);
  float* vbuf  = (float*)(ws + 3672064);                  //  589824 B
  float* cbufg = (float*)(ws + 4261888);                  //  589824 B
  unsigned short* Zg = (unsigned short*)(ws + 4851712);   // 75497472 B

  hipMemsetAsync(ftri, 0, NPAR * DD * sizeof(float), stream);
  hipMemsetAsync(cbufg, 0, NPAR * NEPI * sizeof(float), stream);
  transpose_k<<<64, 256, 0, stream>>>(wk_w, wkT);
  fold_kernel<<<512, 256, 0, stream>>>(res_w2, atom_w2, int_w1, simw, MrF, MaF);
  cvec_kernel<<<1, 256, 0, stream>>>(res_b2, atom_b2, int_b1, int_w1, simw, cvec);
  mm_rows<<<256, 256, 0, stream>>>(wq_w, wkT, WqkF);        // Wqk = wq @ wk^T
  gvec_kernel<<<1, 256, 0, stream>>>(wk_w, wq_b, gv);       // g = wk @ bq
  pack_kernel<<<1280, 256, 0, stream>>>(MrF, MaF, int_w2, wg_w, WqkF, wpack);
  mm_rows<<<384, 256, 0, stream>>>(H, wl, Hpl);
  mm_rows<<<384, 256, 0, stream>>>(H + NPAR * DD, wr, Her);
  mm_rows<<<384, 256, 0, stream>>>(H, int_w1, P1);
  mm_rows<<<384, 256, 0, stream>>>(H + NPAR * DD, int_w1 + DD * DD, P2);
  pair_kernel<<<1152, 256, 0, stream>>>(X, res_w1, res_b1, atom_w1, atom_b1,
                                        int_b2, wg_b, wpack, cvec, gv,
                                        P1, P2, Hpl, Her, ftri, vbuf, Zg);
  attn_kernel<<<2304, 256, 0, stream>>>(Zg, vbuf, wpack, cbufg);
  out_kernel<<<384, 256, 0, stream>>>(Zg, ftri, cbufg, wv_w, wv_b, (float*)d_out);
  hipMemcpyAsync((float*)d_out + NPAR * DD, H + NPAR * DD,
                 (1024 - NPAR) * DD * sizeof(float), hipMemcpyDeviceToDevice, stream);
}

// Round 4
// 553.764 us; speedup vs baseline: 1.8259x; 1.8259x over previous
//
#include <hip/hip_runtime.h>

#define NPAR 384
#define NEPI 384
#define DD   256

using bf16x8 = __bf16 __attribute__((ext_vector_type(8)));
using f32x4  = float __attribute__((ext_vector_type(4)));

__device__ __forceinline__ float sigm(float x) { return 1.0f / (1.0f + __expf(-x)); }
__device__ __forceinline__ float silu(float x) { return x / (1.0f + __expf(-x)); }
__device__ __forceinline__ unsigned short f2bf(float f) {
  unsigned u = __float_as_uint(f);
  u += 0x7fffu + ((u >> 16) & 1u);
  return (unsigned short)(u >> 16);
}
__device__ __forceinline__ float bf2f(unsigned short h) {
  return __uint_as_float(((unsigned)h) << 16);
}
__device__ __forceinline__ uint2 pack4(float a, float b, float c, float d) {
  uint2 r;
  r.x = (unsigned)f2bf(a) | ((unsigned)f2bf(b) << 16);
  r.y = (unsigned)f2bf(c) | ((unsigned)f2bf(d) << 16);
  return r;
}

// ---------------- precompute kernels ----------------

__global__ void fold_kernel(const float* __restrict__ res_w2, const float* __restrict__ atom_w2,
                            const float* __restrict__ int_w1, const float* __restrict__ simw,
                            float* __restrict__ MrF, float* __restrict__ MaF) {
  const int i = blockIdx.x & 255;
  const bool isMa = blockIdx.x >= 256;
  const float wmix = 1.0f / (1.0f + __expf(-simw[0]));
  const float sc = isMa ? (1.0f - wmix) : wmix;
  const float* W2 = isMa ? atom_w2 : res_w2;
  const int j = threadIdx.x;
  float acc = 0.f;
  for (int k = 0; k < 256; ++k)
    acc += W2[i * 256 + k] * int_w1[(512 + k) * 256 + j];
  (isMa ? MaF : MrF)[i * 256 + j] = acc * sc;
}

__global__ void cvec_kernel(const float* __restrict__ res_b2, const float* __restrict__ atom_b2,
                            const float* __restrict__ int_b1, const float* __restrict__ int_w1,
                            const float* __restrict__ simw, float* __restrict__ cvec) {
  const int j = threadIdx.x;
  const float wmix = 1.0f / (1.0f + __expf(-simw[0]));
  float acc = int_b1[j];
  for (int k = 0; k < 256; ++k) {
    float bm = wmix * res_b2[k] + (1.0f - wmix) * atom_b2[k];
    acc += bm * int_w1[(512 + k) * 256 + j];
  }
  cvec[j] = acc;
}

// 32x32-tiled transpose: AT[i][j] = A[j][i], 256x256
__global__ void transpose_k(const float* __restrict__ A, float* __restrict__ AT) {
  __shared__ float tile[32][33];
  const int bx = blockIdx.x & 7, by = blockIdx.x >> 3;
  const int tx = threadIdx.x & 31, ty = threadIdx.x >> 5;
  for (int r = 0; r < 32; r += 8)
    tile[ty + r][tx] = A[(by * 32 + ty + r) * 256 + bx * 32 + tx];
  __syncthreads();
  for (int r = 0; r < 32; r += 8)
    AT[(bx * 32 + ty + r) * 256 + by * 32 + tx] = tile[tx][ty + r];
}

// g[d] = sum_c wk[d,c] * bq[c]
__global__ void gvec_kernel(const float* __restrict__ wk, const float* __restrict__ bq,
                            float* __restrict__ gv) {
  const int d = threadIdx.x;
  float acc = 0.f;
  for (int c = 0; c < 256; ++c) acc += wk[d * 256 + c] * bq[c];
  gv[d] = acc;
}

// pack 5 [256,256] matrices into MFMA fragment order:
// wpack[m][((ks*16+tile)*64 + lane)*8 + j] = W[k = ks*32 + (lane>>4)*8 + j][n = tile*16 + (lane&15)]
// slots: 0=Mr 1=Ma 2=int_w2 3=wg 4=Wqk
__global__ void pack_kernel(const float* __restrict__ MrF, const float* __restrict__ MaF,
                            const float* __restrict__ w2, const float* __restrict__ wg,
                            const float* __restrict__ WqkF, unsigned short* __restrict__ wpack) {
  const int idx = blockIdx.x * 256 + threadIdx.x;
  const int m = idx >> 16;
  const int r = idx & 65535;
  const int chunk = r >> 9;
  const int lane = (r >> 3) & 63;
  const int j = r & 7;
  const int k = (chunk >> 4) * 32 + (lane >> 4) * 8 + j;
  const int n = (chunk & 15) * 16 + (lane & 15);
  const float* src;
  switch (m) {
    case 0: src = MrF; break;
    case 1: src = MaF; break;
    case 2: src = w2; break;
    case 3: src = wg; break;
    default: src = WqkF; break;
  }
  wpack[idx] = f2bf(src[k * 256 + n]);
}

// C[r][j] = sum_k A[r][k] * B[k][j]  (grid = #rows)
__global__ void mm_rows(const float* __restrict__ A, const float* __restrict__ B,
                        float* __restrict__ C) {
  const int r = blockIdx.x, j = threadIdx.x;
  float acc = 0.f;
  for (int k = 0; k < 256; ++k)
    acc += A[r * 256 + k] * B[k * 256 + j];
  C[r * 256 + j] = acc;
}

// ---------------- pairwise GEMM-chain kernel ----------------

__device__ __forceinline__ void zero_acc(f32x4 (&acc)[4][8]) {
#pragma unroll
  for (int mt = 0; mt < 4; ++mt)
#pragma unroll
    for (int nt = 0; nt < 8; ++nt)
      acc[mt][nt] = (f32x4){0.f, 0.f, 0.f, 0.f};
}

// transposed-acc trick: mfma(Wfrag, ActFrag) -> acc^T[d][e]
// d = wv*64 + mt*16 + l4*4 + r, e = nt*16 + l15
__device__ __forceinline__ void gemm_k256(f32x4 (&acc)[4][8],
                                          const unsigned short* __restrict__ wp,
                                          const unsigned short* ub, int lane, int wv) {
  const int l15 = lane & 15, l4 = lane >> 4;
#pragma unroll
  for (int ks = 0; ks < 8; ++ks) {
    bf16x8 a[4];
#pragma unroll
    for (int mt = 0; mt < 4; ++mt)
      a[mt] = *reinterpret_cast<const bf16x8*>(wp + ((ks * 16 + wv * 4 + mt) * 64 + lane) * 8);
#pragma unroll
    for (int nt = 0; nt < 8; ++nt) {
      bf16x8 b = *reinterpret_cast<const bf16x8*>(ub + (nt * 16 + l15) * 264 + ks * 32 + l4 * 8);
#pragma unroll
      for (int mt = 0; mt < 4; ++mt)
        acc[mt][nt] = __builtin_amdgcn_mfma_f32_16x16x32_bf16(a[mt], b, acc[mt][nt], 0, 0, 0);
    }
  }
}

__global__ __launch_bounds__(256, 2) void pair_kernel(
    const float* __restrict__ Xg,
    const float* __restrict__ res_w1, const float* __restrict__ res_b1,
    const float* __restrict__ atom_w1, const float* __restrict__ atom_b1,
    const float* __restrict__ int_b2, const float* __restrict__ wg_b,
    const unsigned short* __restrict__ wpack, const float* __restrict__ cvec,
    const float* __restrict__ gv,
    const float* __restrict__ P1, const float* __restrict__ P2,
    const float* __restrict__ Hpl, const float* __restrict__ Her,
    float* __restrict__ ftri, float* __restrict__ vbuf,
    unsigned short* __restrict__ Zg) {
  __shared__ __align__(16) unsigned short ubuf[128 * 264];
  __shared__ float Sv[128];
  __shared__ float pc[DD];
  __shared__ float vred[512];
  const int t = threadIdx.x, lane = t & 63, wv = t >> 6;
  const int l15 = lane & 15, l4 = lane >> 4;
  const int p = blockIdx.x / 3, e0 = (blockIdx.x % 3) * 128;
  const int d0 = wv * 64;

  if (t < 128) {
    const int e = e0 + t;
    float dx = Xg[p * 42 + 3] - Xg[(NPAR + e) * 42 + 3];
    float dy = Xg[p * 42 + 4] - Xg[(NPAR + e) * 42 + 4];
    float dz = Xg[p * 42 + 5] - Xg[(NPAR + e) * 42 + 5];
    Sv[t] = dx * dx + dy * dy + dz * dz;
  }
  pc[t] = P1[p * DD + t] + cvec[t];
  __syncthreads();

  f32x4 acc[4][8];
  zero_acc(acc);

  // fill u_r
  {
    const f32x4 w1q = *reinterpret_cast<const f32x4*>(&res_w1[lane * 4]);
    const f32x4 b1q = *reinterpret_cast<const f32x4*>(&res_b1[lane * 4]);
#pragma unroll 4
    for (int e = wv; e < 128; e += 4) {
      const float s = Sv[e];
      uint2 pk = pack4(silu(fmaf(s, w1q[0], b1q[0])), silu(fmaf(s, w1q[1], b1q[1])),
                       silu(fmaf(s, w1q[2], b1q[2])), silu(fmaf(s, w1q[3], b1q[3])));
      *reinterpret_cast<uint2*>(&ubuf[e * 264 + lane * 4]) = pk;
    }
  }
  __syncthreads();
  gemm_k256(acc, wpack + 0 * 65536, ubuf, lane, wv);
  __syncthreads();
  // fill u_a
  {
    const f32x4 w1q = *reinterpret_cast<const f32x4*>(&atom_w1[lane * 4]);
    const f32x4 b1q = *reinterpret_cast<const f32x4*>(&atom_b1[lane * 4]);
#pragma unroll 4
    for (int e = wv; e < 128; e += 4) {
      const float s = Sv[e];
      uint2 pk = pack4(silu(fmaf(s, w1q[0], b1q[0])), silu(fmaf(s, w1q[1], b1q[1])),
                       silu(fmaf(s, w1q[2], b1q[2])), silu(fmaf(s, w1q[3], b1q[3])));
      *reinterpret_cast<uint2*>(&ubuf[e * 264 + lane * 4]) = pk;
    }
  }
  __syncthreads();
  gemm_k256(acc, wpack + 1 * 65536, ubuf, lane, wv);
  __syncthreads();

  // epilogue: h = silu(zpre^T + pc[d] + P2[e][d]) -> ubuf[e][d]
#pragma unroll
  for (int mt = 0; mt < 4; ++mt) {
    const int d = d0 + mt * 16 + l4 * 4;
    const f32x4 pcv = *reinterpret_cast<const f32x4*>(&pc[d]);
#pragma unroll
    for (int nt = 0; nt < 8; ++nt) {
      const int e = nt * 16 + l15;
      const f32x4 p2v = *reinterpret_cast<const f32x4*>(&P2[(e0 + e) * DD + d]);
      uint2 pk = pack4(silu(acc[mt][nt][0] + pcv[0] + p2v[0]),
                       silu(acc[mt][nt][1] + pcv[1] + p2v[1]),
                       silu(acc[mt][nt][2] + pcv[2] + p2v[2]),
                       silu(acc[mt][nt][3] + pcv[3] + p2v[3]));
      *reinterpret_cast<uint2*>(&ubuf[e * 264 + d]) = pk;
    }
  }
  __syncthreads();

  // Z = h @ int_w2 + int_b2 -> ubuf + Zg; also v[e] = Z[e,:] . gv
  zero_acc(acc);
  gemm_k256(acc, wpack + 2 * 65536, ubuf, lane, wv);
  __syncthreads();
  {
    float vp[8] = {0.f, 0.f, 0.f, 0.f, 0.f, 0.f, 0.f, 0.f};
#pragma unroll
    for (int mt = 0; mt < 4; ++mt) {
      const int d = d0 + mt * 16 + l4 * 4;
      const f32x4 bb = *reinterpret_cast<const f32x4*>(&int_b2[d]);
      const f32x4 gq = *reinterpret_cast<const f32x4*>(&gv[d]);
#pragma unroll
      for (int nt = 0; nt < 8; ++nt) {
        const int e = nt * 16 + l15;
        float z0 = acc[mt][nt][0] + bb[0];
        float z1 = acc[mt][nt][1] + bb[1];
        float z2 = acc[mt][nt][2] + bb[2];
        float z3 = acc[mt][nt][3] + bb[3];
        uint2 pk = pack4(z0, z1, z2, z3);
        *reinterpret_cast<uint2*>(&ubuf[e * 264 + d]) = pk;
        *reinterpret_cast<uint2*>(&Zg[(size_t)(p * NEPI + e0 + e) * DD + d]) = pk;
        vp[nt] += z0 * gq[0] + z1 * gq[1] + z2 * gq[2] + z3 * gq[3];
      }
    }
#pragma unroll
    for (int nt = 0; nt < 8; ++nt) {
      float v = vp[nt];
      v += __shfl_xor(v, 16);
      v += __shfl_xor(v, 32);
      if (lane < 16) vred[wv * 128 + nt * 16 + lane] = v;
    }
  }
  __syncthreads();
  if (t < 128)
    vbuf[p * NEPI + e0 + t] = vred[t] + vred[128 + t] + vred[256 + t] + vred[384 + t];

  // gate: f_tri[d] += sum_e sigm(Zg^T + b) * Hpl[p][d] * Her[e][d]
  zero_acc(acc);
  gemm_k256(acc, wpack + 3 * 65536, ubuf, lane, wv);
#pragma unroll
  for (int mt = 0; mt < 4; ++mt) {
    const int d = d0 + mt * 16 + l4 * 4;
    const f32x4 bb = *reinterpret_cast<const f32x4*>(&wg_b[d]);
    const f32x4 hl = *reinterpret_cast<const f32x4*>(&Hpl[p * DD + d]);
    f32x4 fs = (f32x4){0.f, 0.f, 0.f, 0.f};
#pragma unroll
    for (int nt = 0; nt < 8; ++nt) {
      const int e = e0 + nt * 16 + l15;
      const f32x4 hr = *reinterpret_cast<const f32x4*>(&Her[e * DD + d]);
#pragma unroll
      for (int r = 0; r < 4; ++r)
        fs[r] += sigm(acc[mt][nt][r] + bb[r]) * hl[r] * hr[r];
    }
#pragma unroll
    for (int r = 0; r < 4; ++r) {
      float v = fs[r];
      v += __shfl_xor(v, 1);
      v += __shfl_xor(v, 2);
      v += __shfl_xor(v, 4);
      v += __shfl_xor(v, 8);
      if (l15 == 0) atomicAdd(&ftri[p * DD + d + r], v);
    }
  }
}

// ---------------- fused attention kernel: block = (p, 64-row chunk) ----------------
// scores = (Z_c Wqk Z^T + 1 v^T) / 16 ; col-sums of softmax -> cbufg[p]
// r4 fix: stage loop fully unrolled (6 x 64-row stages) so the score accumulator
// is never dynamically indexed (r3 put it in scratch: 788 MB HBM writes);
// ZS aliases chunk-stage and f-stages -> LDS 71 KB -> 2 blocks/CU.

__global__ __launch_bounds__(256, 2) void attn_kernel(
    const unsigned short* __restrict__ Zg, const float* __restrict__ vbuf,
    const unsigned short* __restrict__ wpack, float* __restrict__ cbufg) {
  __shared__ __align__(16) unsigned short ZS[64 * 264];
  __shared__ __align__(16) unsigned short Tc[64 * 264];
  __shared__ float vb[NEPI];
  __shared__ float red[256];
  __shared__ float red2[256];
  const int t = threadIdx.x, lane = t & 63, wv = t >> 6;
  const int l15 = lane & 15, l4 = lane >> 4;
  // XCD swizzle: all 6 chunks of one p land on the same XCD (xcd = blk % 8)
  const int xcd = blockIdx.x & 7, inner = blockIdx.x >> 3;
  const int p = (inner / 6) * 8 + xcd, c = inner % 6;
  const unsigned short* Zp = Zg + (size_t)p * NEPI * DD;
  const unsigned short* wqk = wpack + 4 * 65536;

  // stage this chunk's 64 Z rows into ZS
#pragma unroll
  for (int i = 0; i < 8; ++i) {
    const int idx = i * 256 + t;
    const int row = idx >> 5, c16 = idx & 31;
    *reinterpret_cast<uint4*>(&ZS[row * 264 + c16 * 8]) =
        *reinterpret_cast<const uint4*>(&Zp[(c * 64 + row) * DD + c16 * 8]);
  }
  for (int i = t; i < NEPI; i += 256) vb[i] = vbuf[p * NEPI + i];
  __syncthreads();

  // T = Zc @ Wqk  (transposed acc: lane holds 4 contiguous d for one e)
  {
    f32x4 ta[4][4];
#pragma unroll
    for (int mt = 0; mt < 4; ++mt)
#pragma unroll
      for (int nt = 0; nt < 4; ++nt) ta[mt][nt] = (f32x4){0.f, 0.f, 0.f, 0.f};
#pragma unroll
    for (int ks = 0; ks < 8; ++ks) {
      bf16x8 a[4];
#pragma unroll
      for (int mt = 0; mt < 4; ++mt)
        a[mt] = *reinterpret_cast<const bf16x8*>(wqk + ((ks * 16 + wv * 4 + mt) * 64 + lane) * 8);
#pragma unroll
      for (int nt = 0; nt < 4; ++nt) {
        bf16x8 b = *reinterpret_cast<const bf16x8*>(&ZS[(nt * 16 + l15) * 264 + ks * 32 + l4 * 8]);
#pragma unroll
        for (int mt = 0; mt < 4; ++mt)
          ta[mt][nt] = __builtin_amdgcn_mfma_f32_16x16x32_bf16(a[mt], b, ta[mt][nt], 0, 0, 0);
      }
    }
#pragma unroll
    for (int mt = 0; mt < 4; ++mt) {
      const int d = wv * 64 + mt * 16 + l4 * 4;
#pragma unroll
      for (int nt = 0; nt < 4; ++nt) {
        const int e = nt * 16 + l15;
        *reinterpret_cast<uint2*>(&Tc[e * 264 + d]) =
            pack4(ta[mt][nt][0], ta[mt][nt][1], ta[mt][nt][2], ta[mt][nt][3]);
      }
    }
  }
  __syncthreads();

  // S = Tc @ Z^T, 6 fully-unrolled stages of 64 f-rows; wave wv owns f = s*64 + wv*16 + l15
  f32x4 sc[4][6];
#pragma unroll
  for (int mt = 0; mt < 4; ++mt)
#pragma unroll
    for (int s = 0; s < 6; ++s) sc[mt][s] = (f32x4){0.f, 0.f, 0.f, 0.f};

#pragma unroll
  for (int s = 0; s < 6; ++s) {
#pragma unroll
    for (int i = 0; i < 8; ++i) {
      const int idx = i * 256 + t;
      const int row = idx >> 5, c16 = idx & 31;
      *reinterpret_cast<uint4*>(&ZS[row * 264 + c16 * 8]) =
          *reinterpret_cast<const uint4*>(&Zp[(s * 64 + row) * DD + c16 * 8]);
    }
    __syncthreads();
#pragma unroll
    for (int ks = 0; ks < 8; ++ks) {
      bf16x8 a[4];
#pragma unroll
      for (int mt = 0; mt < 4; ++mt)
        a[mt] = *reinterpret_cast<const bf16x8*>(&Tc[(mt * 16 + l15) * 264 + ks * 32 + l4 * 8]);
      bf16x8 b = *reinterpret_cast<const bf16x8*>(&ZS[(wv * 16 + l15) * 264 + ks * 32 + l4 * 8]);
#pragma unroll
      for (int mt = 0; mt < 4; ++mt)
        sc[mt][s] = __builtin_amdgcn_mfma_f32_16x16x32_bf16(a[mt], b, sc[mt][s], 0, 0, 0);
    }
    __syncthreads();
  }

  // softmax over f (384 cols), rows e = mt*16 + l4*4 + r
  const float scl = 0.0625f;
  float fv[6];
#pragma unroll
  for (int s = 0; s < 6; ++s)
    fv[s] = vb[s * 64 + wv * 16 + l15];

  float rmax[4][4];
#pragma unroll
  for (int mt = 0; mt < 4; ++mt) {
#pragma unroll
    for (int r = 0; r < 4; ++r) {
      float m = -1e30f;
#pragma unroll
      for (int s = 0; s < 6; ++s) {
        sc[mt][s][r] = (sc[mt][s][r] + fv[s]) * scl;
        m = fmaxf(m, sc[mt][s][r]);
      }
      m = fmaxf(m, __shfl_xor(m, 1));
      m = fmaxf(m, __shfl_xor(m, 2));
      m = fmaxf(m, __shfl_xor(m, 4));
      m = fmaxf(m, __shfl_xor(m, 8));
      rmax[mt][r] = m;
    }
  }
  if (l15 == 0) {
#pragma unroll
    for (int mt = 0; mt < 4; ++mt)
#pragma unroll
      for (int r = 0; r < 4; ++r)
        red[wv * 64 + mt * 16 + l4 * 4 + r] = rmax[mt][r];
  }
  __syncthreads();
#pragma unroll
  for (int mt = 0; mt < 4; ++mt) {
#pragma unroll
    for (int r = 0; r < 4; ++r) {
      const int row = mt * 16 + l4 * 4 + r;
      rmax[mt][r] = fmaxf(fmaxf(red[row], red[64 + row]), fmaxf(red[128 + row], red[192 + row]));
    }
  }

  float rsum[4][4];
#pragma unroll
  for (int mt = 0; mt < 4; ++mt) {
#pragma unroll
    for (int r = 0; r < 4; ++r) {
      float sSum = 0.f;
#pragma unroll
      for (int s = 0; s < 6; ++s) {
        float e = __expf(sc[mt][s][r] - rmax[mt][r]);
        sc[mt][s][r] = e;
        sSum += e;
      }
      sSum += __shfl_xor(sSum, 1);
      sSum += __shfl_xor(sSum, 2);
      sSum += __shfl_xor(sSum, 4);
      sSum += __shfl_xor(sSum, 8);
      rsum[mt][r] = sSum;
    }
  }
  if (l15 == 0) {
#pragma unroll
    for (int mt = 0; mt < 4; ++mt)
#pragma unroll
      for (int r = 0; r < 4; ++r)
        red2[wv * 64 + mt * 16 + l4 * 4 + r] = rsum[mt][r];
  }
  __syncthreads();
  float rinv[4][4];
#pragma unroll
  for (int mt = 0; mt < 4; ++mt) {
#pragma unroll
    for (int r = 0; r < 4; ++r) {
      const int row = mt * 16 + l4 * 4 + r;
      rinv[mt][r] = 1.0f / (red2[row] + red2[64 + row] + red2[128 + row] + red2[192 + row]);
    }
  }

  // column sums of A over this chunk's 64 rows -> cbufg
#pragma unroll
  for (int s = 0; s < 6; ++s) {
    float v = 0.f;
#pragma unroll
    for (int mt = 0; mt < 4; ++mt)
#pragma unroll
      for (int r = 0; r < 4; ++r)
        v += sc[mt][s][r] * rinv[mt][r];
    v += __shfl_xor(v, 16);
    v += __shfl_xor(v, 32);
    if (lane < 16)
      atomicAdd(&cbufg[p * NEPI + s * 64 + wv * 16 + lane], v);
  }
}

// ---------------- output kernel ----------------
// out[p] = (ftri[p] + (c^T Z_p) @ wv + 384*bv) / 384

__global__ __launch_bounds__(256) void out_kernel(
    const unsigned short* __restrict__ Zg, const float* __restrict__ ftri,
    const float* __restrict__ cbufg, const float* __restrict__ wvw,
    const float* __restrict__ wvb, float* __restrict__ out) {
  __shared__ float cb[NEPI];
  __shared__ float u[DD];
  const int p = blockIdx.x, t = threadIdx.x;
  for (int i = t; i < NEPI; i += 256) cb[i] = cbufg[p * NEPI + i];
  __syncthreads();
  const unsigned short* Zp = Zg + (size_t)p * NEPI * DD;
  float a0 = 0.f, a1 = 0.f, a2 = 0.f, a3 = 0.f;
  for (int f = 0; f < NEPI; f += 4) {
    a0 = fmaf(cb[f + 0], bf2f(Zp[(f + 0) * DD + t]), a0);
    a1 = fmaf(cb[f + 1], bf2f(Zp[(f + 1) * DD + t]), a1);
    a2 = fmaf(cb[f + 2], bf2f(Zp[(f + 2) * DD + t]), a2);
    a3 = fmaf(cb[f + 3], bf2f(Zp[(f + 3) * DD + t]), a3);
  }
  u[t] = a0 + a1 + a2 + a3;
  __syncthreads();
  float acc = ftri[p * DD + t] + 384.0f * wvb[t];
  for (int d = 0; d < DD; ++d)
    acc = fmaf(u[d], wvw[d * DD + t], acc);
  out[p * DD + t] = acc * (1.0f / 384.0f);
}

// ---------------- launch ----------------

extern "C" void kernel_launch(void* const* d_in, const int* in_sizes, int n_in,
                              void* d_out, int out_size, void* d_ws, size_t ws_size,
                              hipStream_t stream) {
  (void)in_sizes; (void)n_in; (void)out_size; (void)ws_size;
  const float* H = (const float*)d_in[0];
  const float* X = (const float*)d_in[1];
  const float* res_w1 = (const float*)d_in[4];
  const float* res_b1 = (const float*)d_in[5];
  const float* res_w2 = (const float*)d_in[6];
  const float* res_b2 = (const float*)d_in[7];
  const float* atom_w1 = (const float*)d_in[8];
  const float* atom_b1 = (const float*)d_in[9];
  const float* atom_w2 = (const float*)d_in[10];
  const float* atom_b2 = (const float*)d_in[11];
  const float* simw = (const float*)d_in[12];
  const float* int_w1 = (const float*)d_in[13];
  const float* int_b1 = (const float*)d_in[14];
  const float* int_w2 = (const float*)d_in[15];
  const float* int_b2 = (const float*)d_in[16];
  const float* wl = (const float*)d_in[17];
  const float* wr = (const float*)d_in[18];
  const float* wg_w = (const float*)d_in[19];
  const float* wg_b = (const float*)d_in[20];
  const float* wq_w = (const float*)d_in[21];
  const float* wq_b = (const float*)d_in[22];
  const float* wk_w = (const float*)d_in[23];
  const float* wk_b = (const float*)d_in[24];
  const float* wv_w = (const float*)d_in[25];
  const float* wv_b = (const float*)d_in[26];
  (void)wk_b;

  char* ws = (char*)d_ws;
  unsigned short* wpack = (unsigned short*)(ws + 0);      //  655360 B (5 slots)
  float* MrF   = (float*)(ws + 655360);
  float* MaF   = (float*)(ws + 917504);
  float* WqkF  = (float*)(ws + 1179648);
  float* wkT   = (float*)(ws + 1441792);
  float* cvec  = (float*)(ws + 1703936);
  float* gv    = (float*)(ws + 1704960);
  float* P1    = (float*)(ws + 1705984);
  float* P2    = (float*)(ws + 2099200);
  float* Hpl   = (float*)(ws + 2492416);
  float* Her   = (float*)(ws + 2885632);
  float* ftri  = (float*)(ws + 3278848);
  float* vbuf  = (float*)(ws + 3672064);                  //  589824 B
  float* cbufg = (float*)(ws + 4261888);                  //  589824 B
  unsigned short* Zg = (unsigned short*)(ws + 4851712);   // 75497472 B

  hipMemsetAsync(ftri, 0, NPAR * DD * sizeof(float), stream);
  hipMemsetAsync(cbufg, 0, NPAR * NEPI * sizeof(float), stream);
  transpose_k<<<64, 256, 0, stream>>>(wk_w, wkT);
  fold_kernel<<<512, 256, 0, stream>>>(res_w2, atom_w2, int_w1, simw, MrF, MaF);
  cvec_kernel<<<1, 256, 0, stream>>>(res_b2, atom_b2, int_b1, int_w1, simw, cvec);
  mm_rows<<<256, 256, 0, stream>>>(wq_w, wkT, WqkF);        // Wqk = wq @ wk^T
  gvec_kernel<<<1, 256, 0, stream>>>(wk_w, wq_b, gv);       // g = wk @ bq
  pack_kernel<<<1280, 256, 0, stream>>>(MrF, MaF, int_w2, wg_w, WqkF, wpack);
  mm_rows<<<384, 256, 0, stream>>>(H, wl, Hpl);
  mm_rows<<<384, 256, 0, stream>>>(H + NPAR * DD, wr, Her);
  mm_rows<<<384, 256, 0, stream>>>(H, int_w1, P1);
  mm_rows<<<384, 256, 0, stream>>>(H + NPAR * DD, int_w1 + DD * DD, P2);
  pair_kernel<<<1152, 256, 0, stream>>>(X, res_w1, res_b1, atom_w1, atom_b1,
                                        int_b2, wg_b, wpack, cvec, gv,
                                        P1, P2, Hpl, Her, ftri, vbuf, Zg);
  attn_kernel<<<2304, 256, 0, stream>>>(Zg, vbuf, wpack, cbufg);
  out_kernel<<<384, 256, 0, stream>>>(Zg, ftri, cbufg, wv_w, wv_b, (float*)d_out);
  hipMemcpyAsync((float*)d_out + NPAR * DD, H + NPAR * DD,
                 (1024 - NPAR) * DD * sizeof(float), hipMemcpyDeviceToDevice, stream);
}

// Round 5
// 461.768 us; speedup vs baseline: 2.1896x; 1.1992x over previous
//
#include <hip/hip_runtime.h>

#define NPAR 384
#define NEPI 384
#define DD   256

using bf16x8 = __bf16 __attribute__((ext_vector_type(8)));
using f32x4  = float __attribute__((ext_vector_type(4)));

__device__ __forceinline__ float sigm(float x) { return 1.0f / (1.0f + __expf(-x)); }
__device__ __forceinline__ float silu(float x) { return x / (1.0f + __expf(-x)); }
__device__ __forceinline__ unsigned short f2bf(float f) {
  unsigned u = __float_as_uint(f);
  u += 0x7fffu + ((u >> 16) & 1u);
  return (unsigned short)(u >> 16);
}
__device__ __forceinline__ float bf2f(unsigned short h) {
  return __uint_as_float(((unsigned)h) << 16);
}
__device__ __forceinline__ uint2 pack4(float a, float b, float c, float d) {
  uint2 r;
  r.x = (unsigned)f2bf(a) | ((unsigned)f2bf(b) << 16);
  r.y = (unsigned)f2bf(c) | ((unsigned)f2bf(d) << 16);
  return r;
}

// ---------------- precompute kernels ----------------

__global__ void fold_kernel(const float* __restrict__ res_w2, const float* __restrict__ atom_w2,
                            const float* __restrict__ int_w1, const float* __restrict__ simw,
                            float* __restrict__ MrF, float* __restrict__ MaF) {
  const int i = blockIdx.x & 255;
  const bool isMa = blockIdx.x >= 256;
  const float wmix = 1.0f / (1.0f + __expf(-simw[0]));
  const float sc = isMa ? (1.0f - wmix) : wmix;
  const float* W2 = isMa ? atom_w2 : res_w2;
  const int j = threadIdx.x;
  float acc = 0.f;
  for (int k = 0; k < 256; ++k)
    acc += W2[i * 256 + k] * int_w1[(512 + k) * 256 + j];
  (isMa ? MaF : MrF)[i * 256 + j] = acc * sc;
}

__global__ void cvec_kernel(const float* __restrict__ res_b2, const float* __restrict__ atom_b2,
                            const float* __restrict__ int_b1, const float* __restrict__ int_w1,
                            const float* __restrict__ simw, float* __restrict__ cvec) {
  const int j = threadIdx.x;
  const float wmix = 1.0f / (1.0f + __expf(-simw[0]));
  float acc = int_b1[j];
  for (int k = 0; k < 256; ++k) {
    float bm = wmix * res_b2[k] + (1.0f - wmix) * atom_b2[k];
    acc += bm * int_w1[(512 + k) * 256 + j];
  }
  cvec[j] = acc;
}

// 32x32-tiled transpose: AT[i][j] = A[j][i], 256x256
__global__ void transpose_k(const float* __restrict__ A, float* __restrict__ AT) {
  __shared__ float tile[32][33];
  const int bx = blockIdx.x & 7, by = blockIdx.x >> 3;
  const int tx = threadIdx.x & 31, ty = threadIdx.x >> 5;
  for (int r = 0; r < 32; r += 8)
    tile[ty + r][tx] = A[(by * 32 + ty + r) * 256 + bx * 32 + tx];
  __syncthreads();
  for (int r = 0; r < 32; r += 8)
    AT[(bx * 32 + ty + r) * 256 + by * 32 + tx] = tile[tx][ty + r];
}

// g[d] = sum_c wk[d,c] * bq[c]
__global__ void gvec_kernel(const float* __restrict__ wk, const float* __restrict__ bq,
                            float* __restrict__ gv) {
  const int d = threadIdx.x;
  float acc = 0.f;
  for (int c = 0; c < 256; ++c) acc += wk[d * 256 + c] * bq[c];
  gv[d] = acc;
}

// pack 5 [256,256] matrices into MFMA fragment order:
// wpack[m][((ks*16+tile)*64 + lane)*8 + j] = W[k = ks*32 + (lane>>4)*8 + j][n = tile*16 + (lane&15)]
// slots: 0=Mr 1=Ma 2=int_w2 3=wg 4=Wqk
__global__ void pack_kernel(const float* __restrict__ MrF, const float* __restrict__ MaF,
                            const float* __restrict__ w2, const float* __restrict__ wg,
                            const float* __restrict__ WqkF, unsigned short* __restrict__ wpack) {
  const int idx = blockIdx.x * 256 + threadIdx.x;
  const int m = idx >> 16;
  const int r = idx & 65535;
  const int chunk = r >> 9;
  const int lane = (r >> 3) & 63;
  const int j = r & 7;
  const int k = (chunk >> 4) * 32 + (lane >> 4) * 8 + j;
  const int n = (chunk & 15) * 16 + (lane & 15);
  const float* src;
  switch (m) {
    case 0: src = MrF; break;
    case 1: src = MaF; break;
    case 2: src = w2; break;
    case 3: src = wg; break;
    default: src = WqkF; break;
  }
  wpack[idx] = f2bf(src[k * 256 + n]);
}

// fused 4x: Hpl = Hp@wl, Her = He@wr, P1 = Hp@W1a, P2 = He@W1b
__global__ void mm_rows4(const float* __restrict__ H, const float* __restrict__ wl,
                         const float* __restrict__ wr, const float* __restrict__ int_w1,
                         float* __restrict__ Hpl, float* __restrict__ Her,
                         float* __restrict__ P1, float* __restrict__ P2) {
  const int seg = blockIdx.x / 384, r = blockIdx.x % 384;
  const float* A;
  const float* B;
  float* C;
  switch (seg) {
    case 0:  A = H + r * 256;            B = wl;              C = Hpl + r * 256; break;
    case 1:  A = H + (NPAR + r) * 256;   B = wr;              C = Her + r * 256; break;
    case 2:  A = H + r * 256;            B = int_w1;          C = P1 + r * 256;  break;
    default: A = H + (NPAR + r) * 256;   B = int_w1 + 65536;  C = P2 + r * 256;  break;
  }
  const int j = threadIdx.x;
  float acc = 0.f;
#pragma unroll 8
  for (int k = 0; k < 256; ++k)
    acc += A[k] * B[k * 256 + j];
  C[j] = acc;
}

// C[r][j] = sum_k A[r][k] * B[k][j]  (grid = #rows) — for Wqk
__global__ void mm_rows(const float* __restrict__ A, const float* __restrict__ B,
                        float* __restrict__ C) {
  const int r = blockIdx.x, j = threadIdx.x;
  float acc = 0.f;
#pragma unroll 8
  for (int k = 0; k < 256; ++k)
    acc += A[r * 256 + k] * B[k * 256 + j];
  C[r * 256 + j] = acc;
}

// ---------------- pairwise GEMM-chain kernel (64-row tiles) ----------------

__device__ __forceinline__ void zero_acc4(f32x4 (&acc)[4][4]) {
#pragma unroll
  for (int mt = 0; mt < 4; ++mt)
#pragma unroll
    for (int nt = 0; nt < 4; ++nt)
      acc[mt][nt] = (f32x4){0.f, 0.f, 0.f, 0.f};
}

// transposed-acc: mfma(Wfrag, ActFrag) -> acc^T[d][e]
// d = wv*64 + mt*16 + l4*4 + r, e = nt*16 + l15
__device__ __forceinline__ void gemm4(f32x4 (&acc)[4][4],
                                      const unsigned short* __restrict__ wp,
                                      const unsigned short* ub, int lane, int wv) {
  const int l15 = lane & 15, l4 = lane >> 4;
#pragma unroll
  for (int ks = 0; ks < 8; ++ks) {
    bf16x8 a[4];
#pragma unroll
    for (int mt = 0; mt < 4; ++mt)
      a[mt] = *reinterpret_cast<const bf16x8*>(wp + ((ks * 16 + wv * 4 + mt) * 64 + lane) * 8);
#pragma unroll
    for (int nt = 0; nt < 4; ++nt) {
      bf16x8 b = *reinterpret_cast<const bf16x8*>(ub + (nt * 16 + l15) * 264 + ks * 32 + l4 * 8);
#pragma unroll
      for (int mt = 0; mt < 4; ++mt)
        acc[mt][nt] = __builtin_amdgcn_mfma_f32_16x16x32_bf16(a[mt], b, acc[mt][nt], 0, 0, 0);
    }
  }
}

__global__ __launch_bounds__(256, 3) void pair_kernel(
    const float* __restrict__ Xg,
    const float* __restrict__ res_w1, const float* __restrict__ res_b1,
    const float* __restrict__ atom_w1, const float* __restrict__ atom_b1,
    const float* __restrict__ int_b2, const float* __restrict__ wg_b,
    const unsigned short* __restrict__ wpack, const float* __restrict__ cvec,
    const float* __restrict__ gv,
    const float* __restrict__ P1, const float* __restrict__ P2,
    const float* __restrict__ Hpl, const float* __restrict__ Her,
    float* __restrict__ ftri, float* __restrict__ vbuf,
    unsigned short* __restrict__ Zg) {
  __shared__ __align__(16) unsigned short ubuf[64 * 264];
  __shared__ float Sv[64];
  __shared__ float pc[DD];
  __shared__ float vred[256];
  const int t = threadIdx.x, lane = t & 63, wv = t >> 6;
  const int l15 = lane & 15, l4 = lane >> 4;
  const int p = blockIdx.x / 6, e0 = (blockIdx.x % 6) * 64;
  const int d0 = wv * 64;

  if (t < 64) {
    const int e = e0 + t;
    float dx = Xg[p * 42 + 3] - Xg[(NPAR + e) * 42 + 3];
    float dy = Xg[p * 42 + 4] - Xg[(NPAR + e) * 42 + 4];
    float dz = Xg[p * 42 + 5] - Xg[(NPAR + e) * 42 + 5];
    Sv[t] = dx * dx + dy * dy + dz * dz;
  }
  pc[t] = P1[p * DD + t] + cvec[t];
  __syncthreads();

  f32x4 acc[4][4];
  zero_acc4(acc);

  // fill u_r: wave wv owns rows {wv, wv+4, ...}; lane owns d-quad lane*4
  {
    const f32x4 w1q = *reinterpret_cast<const f32x4*>(&res_w1[lane * 4]);
    const f32x4 b1q = *reinterpret_cast<const f32x4*>(&res_b1[lane * 4]);
#pragma unroll
    for (int i = 0; i < 16; ++i) {
      const int e = wv + i * 4;
      const float s = Sv[e];
      uint2 pk = pack4(silu(fmaf(s, w1q[0], b1q[0])), silu(fmaf(s, w1q[1], b1q[1])),
                       silu(fmaf(s, w1q[2], b1q[2])), silu(fmaf(s, w1q[3], b1q[3])));
      *reinterpret_cast<uint2*>(&ubuf[e * 264 + lane * 4]) = pk;
    }
  }
  __syncthreads();
  gemm4(acc, wpack + 0 * 65536, ubuf, lane, wv);
  __syncthreads();
  // fill u_a
  {
    const f32x4 w1q = *reinterpret_cast<const f32x4*>(&atom_w1[lane * 4]);
    const f32x4 b1q = *reinterpret_cast<const f32x4*>(&atom_b1[lane * 4]);
#pragma unroll
    for (int i = 0; i < 16; ++i) {
      const int e = wv + i * 4;
      const float s = Sv[e];
      uint2 pk = pack4(silu(fmaf(s, w1q[0], b1q[0])), silu(fmaf(s, w1q[1], b1q[1])),
                       silu(fmaf(s, w1q[2], b1q[2])), silu(fmaf(s, w1q[3], b1q[3])));
      *reinterpret_cast<uint2*>(&ubuf[e * 264 + lane * 4]) = pk;
    }
  }
  __syncthreads();
  gemm4(acc, wpack + 1 * 65536, ubuf, lane, wv);
  __syncthreads();

  // epilogue: h = silu(zpre^T + pc[d] + P2[e][d]) -> ubuf[e][d]
#pragma unroll
  for (int mt = 0; mt < 4; ++mt) {
    const int d = d0 + mt * 16 + l4 * 4;
    const f32x4 pcv = *reinterpret_cast<const f32x4*>(&pc[d]);
#pragma unroll
    for (int nt = 0; nt < 4; ++nt) {
      const int e = nt * 16 + l15;
      const f32x4 p2v = *reinterpret_cast<const f32x4*>(&P2[(e0 + e) * DD + d]);
      uint2 pk = pack4(silu(acc[mt][nt][0] + pcv[0] + p2v[0]),
                       silu(acc[mt][nt][1] + pcv[1] + p2v[1]),
                       silu(acc[mt][nt][2] + pcv[2] + p2v[2]),
                       silu(acc[mt][nt][3] + pcv[3] + p2v[3]));
      *reinterpret_cast<uint2*>(&ubuf[e * 264 + d]) = pk;
    }
  }
  __syncthreads();

  // Z = h @ int_w2 + int_b2 -> ubuf; v[e] = Z[e,:] . gv
  zero_acc4(acc);
  gemm4(acc, wpack + 2 * 65536, ubuf, lane, wv);
  __syncthreads();
  {
    float vp[4] = {0.f, 0.f, 0.f, 0.f};
#pragma unroll
    for (int mt = 0; mt < 4; ++mt) {
      const int d = d0 + mt * 16 + l4 * 4;
      const f32x4 bb = *reinterpret_cast<const f32x4*>(&int_b2[d]);
      const f32x4 gq = *reinterpret_cast<const f32x4*>(&gv[d]);
#pragma unroll
      for (int nt = 0; nt < 4; ++nt) {
        const int e = nt * 16 + l15;
        float z0 = acc[mt][nt][0] + bb[0];
        float z1 = acc[mt][nt][1] + bb[1];
        float z2 = acc[mt][nt][2] + bb[2];
        float z3 = acc[mt][nt][3] + bb[3];
        *reinterpret_cast<uint2*>(&ubuf[e * 264 + d]) = pack4(z0, z1, z2, z3);
        vp[nt] += z0 * gq[0] + z1 * gq[1] + z2 * gq[2] + z3 * gq[3];
      }
    }
#pragma unroll
    for (int nt = 0; nt < 4; ++nt) {
      float v = vp[nt];
      v += __shfl_xor(v, 16);
      v += __shfl_xor(v, 32);
      if (lane < 16) vred[wv * 64 + nt * 16 + lane] = v;
    }
  }
  __syncthreads();
  if (t < 64)
    vbuf[p * NEPI + e0 + t] = vred[t] + vred[64 + t] + vred[128 + t] + vred[192 + t];

  // coalesced Z store: ubuf -> Zg, 1 KB/wave-instruction contiguous
#pragma unroll
  for (int i = 0; i < 8; ++i) {
    const int idx = i * 256 + t;
    const int row = idx >> 5, c16 = idx & 31;
    *reinterpret_cast<uint4*>(&Zg[((size_t)(p * NEPI) + e0 + row) * DD + c16 * 8]) =
        *reinterpret_cast<const uint4*>(&ubuf[row * 264 + c16 * 8]);
  }

  // gate: f_tri[d] += sum_e sigm(Zg^T + b) * Hpl[p][d] * Her[e][d]
  zero_acc4(acc);
  gemm4(acc, wpack + 3 * 65536, ubuf, lane, wv);
#pragma unroll
  for (int mt = 0; mt < 4; ++mt) {
    const int d = d0 + mt * 16 + l4 * 4;
    const f32x4 bb = *reinterpret_cast<const f32x4*>(&wg_b[d]);
    const f32x4 hl = *reinterpret_cast<const f32x4*>(&Hpl[p * DD + d]);
    f32x4 fs = (f32x4){0.f, 0.f, 0.f, 0.f};
#pragma unroll
    for (int nt = 0; nt < 4; ++nt) {
      const int e = e0 + nt * 16 + l15;
      const f32x4 hr = *reinterpret_cast<const f32x4*>(&Her[e * DD + d]);
#pragma unroll
      for (int r = 0; r < 4; ++r)
        fs[r] += sigm(acc[mt][nt][r] + bb[r]) * hl[r] * hr[r];
    }
#pragma unroll
    for (int r = 0; r < 4; ++r) {
      float v = fs[r];
      v += __shfl_xor(v, 1);
      v += __shfl_xor(v, 2);
      v += __shfl_xor(v, 4);
      v += __shfl_xor(v, 8);
      if (l15 == 0) atomicAdd(&ftri[p * DD + d + r], v);
    }
  }
}

// ---------------- fused attention kernel: block = (p, 64-row chunk) ----------------
// scores = (Z_c Wqk Z^T + 1 v^T) / 16 ; col-sums of softmax -> cbufg[p]
// r5: B-fragments read directly from global (L2/L3-resident Zg, XCD-swizzled);
// only Tc stays in LDS; 2 barriers total.

__global__ __launch_bounds__(256, 2) void attn_kernel(
    const unsigned short* __restrict__ Zg, const float* __restrict__ vbuf,
    const unsigned short* __restrict__ wpack, float* __restrict__ cbufg) {
  __shared__ __align__(16) unsigned short Tc[64 * 264];
  __shared__ float vb[NEPI];
  __shared__ float red[256];
  __shared__ float red2[256];
  const int t = threadIdx.x, lane = t & 63, wv = t >> 6;
  const int l15 = lane & 15, l4 = lane >> 4;
  // XCD swizzle: all 6 chunks of one p land on the same XCD (xcd = blk % 8)
  const int xcd = blockIdx.x & 7, inner = blockIdx.x >> 3;
  const int p = (inner / 6) * 8 + xcd, c = inner % 6;
  const unsigned short* Zp = Zg + (size_t)p * NEPI * DD;
  const unsigned short* wqk = wpack + 4 * 65536;

  for (int i = t; i < NEPI; i += 256) vb[i] = vbuf[p * NEPI + i];

  // T = Zc @ Wqk (transposed acc), B-frags straight from global
  {
    f32x4 ta[4][4];
#pragma unroll
    for (int mt = 0; mt < 4; ++mt)
#pragma unroll
      for (int nt = 0; nt < 4; ++nt) ta[mt][nt] = (f32x4){0.f, 0.f, 0.f, 0.f};
#pragma unroll
    for (int ks = 0; ks < 8; ++ks) {
      bf16x8 a[4];
#pragma unroll
      for (int mt = 0; mt < 4; ++mt)
        a[mt] = *reinterpret_cast<const bf16x8*>(wqk + ((ks * 16 + wv * 4 + mt) * 64 + lane) * 8);
#pragma unroll
      for (int nt = 0; nt < 4; ++nt) {
        bf16x8 b = *reinterpret_cast<const bf16x8*>(
            Zp + (c * 64 + nt * 16 + l15) * DD + ks * 32 + l4 * 8);
#pragma unroll
        for (int mt = 0; mt < 4; ++mt)
          ta[mt][nt] = __builtin_amdgcn_mfma_f32_16x16x32_bf16(a[mt], b, ta[mt][nt], 0, 0, 0);
      }
    }
#pragma unroll
    for (int mt = 0; mt < 4; ++mt) {
      const int d = wv * 64 + mt * 16 + l4 * 4;
#pragma unroll
      for (int nt = 0; nt < 4; ++nt) {
        const int e = nt * 16 + l15;
        *reinterpret_cast<uint2*>(&Tc[e * 264 + d]) =
            pack4(ta[mt][nt][0], ta[mt][nt][1], ta[mt][nt][2], ta[mt][nt][3]);
      }
    }
  }
  __syncthreads();

  // S = Tc @ Z^T; a-frags hoisted per-ks, b-frags from global; no barriers
  f32x4 sc[4][6];
#pragma unroll
  for (int mt = 0; mt < 4; ++mt)
#pragma unroll
    for (int s = 0; s < 6; ++s) sc[mt][s] = (f32x4){0.f, 0.f, 0.f, 0.f};

#pragma unroll
  for (int ks = 0; ks < 8; ++ks) {
    bf16x8 a[4];
#pragma unroll
    for (int mt = 0; mt < 4; ++mt)
      a[mt] = *reinterpret_cast<const bf16x8*>(&Tc[(mt * 16 + l15) * 264 + ks * 32 + l4 * 8]);
#pragma unroll
    for (int s = 0; s < 6; ++s) {
      bf16x8 b = *reinterpret_cast<const bf16x8*>(
          Zp + (s * 64 + wv * 16 + l15) * DD + ks * 32 + l4 * 8);
#pragma unroll
      for (int mt = 0; mt < 4; ++mt)
        sc[mt][s] = __builtin_amdgcn_mfma_f32_16x16x32_bf16(a[mt], b, sc[mt][s], 0, 0, 0);
    }
  }

  // softmax over f (384 cols), rows e = mt*16 + l4*4 + r
  const float scl = 0.0625f;
  float fv[6];
#pragma unroll
  for (int s = 0; s < 6; ++s)
    fv[s] = vb[s * 64 + wv * 16 + l15];

  float rmax[4][4];
#pragma unroll
  for (int mt = 0; mt < 4; ++mt) {
#pragma unroll
    for (int r = 0; r < 4; ++r) {
      float m = -1e30f;
#pragma unroll
      for (int s = 0; s < 6; ++s) {
        sc[mt][s][r] = (sc[mt][s][r] + fv[s]) * scl;
        m = fmaxf(m, sc[mt][s][r]);
      }
      m = fmaxf(m, __shfl_xor(m, 1));
      m = fmaxf(m, __shfl_xor(m, 2));
      m = fmaxf(m, __shfl_xor(m, 4));
      m = fmaxf(m, __shfl_xor(m, 8));
      rmax[mt][r] = m;
    }
  }
  if (l15 == 0) {
#pragma unroll
    for (int mt = 0; mt < 4; ++mt)
#pragma unroll
      for (int r = 0; r < 4; ++r)
        red[wv * 64 + mt * 16 + l4 * 4 + r] = rmax[mt][r];
  }
  __syncthreads();
#pragma unroll
  for (int mt = 0; mt < 4; ++mt) {
#pragma unroll
    for (int r = 0; r < 4; ++r) {
      const int row = mt * 16 + l4 * 4 + r;
      rmax[mt][r] = fmaxf(fmaxf(red[row], red[64 + row]), fmaxf(red[128 + row], red[192 + row]));
    }
  }

  float rsum[4][4];
#pragma unroll
  for (int mt = 0; mt < 4; ++mt) {
#pragma unroll
    for (int r = 0; r < 4; ++r) {
      float sSum = 0.f;
#pragma unroll
      for (int s = 0; s < 6; ++s) {
        float e = __expf(sc[mt][s][r] - rmax[mt][r]);
        sc[mt][s][r] = e;
        sSum += e;
      }
      sSum += __shfl_xor(sSum, 1);
      sSum += __shfl_xor(sSum, 2);
      sSum += __shfl_xor(sSum, 4);
      sSum += __shfl_xor(sSum, 8);
      rsum[mt][r] = sSum;
    }
  }
  if (l15 == 0) {
#pragma unroll
    for (int mt = 0; mt < 4; ++mt)
#pragma unroll
      for (int r = 0; r < 4; ++r)
        red2[wv * 64 + mt * 16 + l4 * 4 + r] = rsum[mt][r];
  }
  __syncthreads();
  float rinv[4][4];
#pragma unroll
  for (int mt = 0; mt < 4; ++mt) {
#pragma unroll
    for (int r = 0; r < 4; ++r) {
      const int row = mt * 16 + l4 * 4 + r;
      rinv[mt][r] = 1.0f / (red2[row] + red2[64 + row] + red2[128 + row] + red2[192 + row]);
    }
  }

  // column sums of A over this chunk's 64 rows -> cbufg
#pragma unroll
  for (int s = 0; s < 6; ++s) {
    float v = 0.f;
#pragma unroll
    for (int mt = 0; mt < 4; ++mt)
#pragma unroll
      for (int r = 0; r < 4; ++r)
        v += sc[mt][s][r] * rinv[mt][r];
    v += __shfl_xor(v, 16);
    v += __shfl_xor(v, 32);
    if (lane < 16)
      atomicAdd(&cbufg[p * NEPI + s * 64 + wv * 16 + lane], v);
  }
}

// ---------------- output kernel ----------------
// out[p] = (ftri[p] + (c^T Z_p) @ wv + 384*bv) / 384

__global__ __launch_bounds__(256) void out_kernel(
    const unsigned short* __restrict__ Zg, const float* __restrict__ ftri,
    const float* __restrict__ cbufg, const float* __restrict__ wvw,
    const float* __restrict__ wvb, float* __restrict__ out) {
  __shared__ float cb[NEPI];
  __shared__ float u[DD];
  const int p = blockIdx.x, t = threadIdx.x;
  for (int i = t; i < NEPI; i += 256) cb[i] = cbufg[p * NEPI + i];
  __syncthreads();
  const unsigned short* Zp = Zg + (size_t)p * NEPI * DD;
  float a0 = 0.f, a1 = 0.f, a2 = 0.f, a3 = 0.f;
  for (int f = 0; f < NEPI; f += 4) {
    a0 = fmaf(cb[f + 0], bf2f(Zp[(f + 0) * DD + t]), a0);
    a1 = fmaf(cb[f + 1], bf2f(Zp[(f + 1) * DD + t]), a1);
    a2 = fmaf(cb[f + 2], bf2f(Zp[(f + 2) * DD + t]), a2);
    a3 = fmaf(cb[f + 3], bf2f(Zp[(f + 3) * DD + t]), a3);
  }
  u[t] = a0 + a1 + a2 + a3;
  __syncthreads();
  float acc = ftri[p * DD + t] + 384.0f * wvb[t];
#pragma unroll 8
  for (int d = 0; d < DD; ++d)
    acc = fmaf(u[d], wvw[d * DD + t], acc);
  out[p * DD + t] = acc * (1.0f / 384.0f);
}

// ---------------- launch ----------------

extern "C" void kernel_launch(void* const* d_in, const int* in_sizes, int n_in,
                              void* d_out, int out_size, void* d_ws, size_t ws_size,
                              hipStream_t stream) {
  (void)in_sizes; (void)n_in; (void)out_size; (void)ws_size;
  const float* H = (const float*)d_in[0];
  const float* X = (const float*)d_in[1];
  const float* res_w1 = (const float*)d_in[4];
  const float* res_b1 = (const float*)d_in[5];
  const float* res_w2 = (const float*)d_in[6];
  const float* res_b2 = (const float*)d_in[7];
  const float* atom_w1 = (const float*)d_in[8];
  const float* atom_b1 = (const float*)d_in[9];
  const float* atom_w2 = (const float*)d_in[10];
  const float* atom_b2 = (const float*)d_in[11];
  const float* simw = (const float*)d_in[12];
  const float* int_w1 = (const float*)d_in[13];
  const float* int_b1 = (const float*)d_in[14];
  const float* int_w2 = (const float*)d_in[15];
  const float* int_b2 = (const float*)d_in[16];
  const float* wl = (const float*)d_in[17];
  const float* wr = (const float*)d_in[18];
  const float* wg_w = (const float*)d_in[19];
  const float* wg_b = (const float*)d_in[20];
  const float* wq_w = (const float*)d_in[21];
  const float* wq_b = (const float*)d_in[22];
  const float* wk_w = (const float*)d_in[23];
  const float* wv_w = (const float*)d_in[25];
  const float* wv_b = (const float*)d_in[26];

  char* ws = (char*)d_ws;
  unsigned short* wpack = (unsigned short*)(ws + 0);      //  655360 B (5 slots)
  float* MrF   = (float*)(ws + 655360);
  float* MaF   = (float*)(ws + 917504);
  float* WqkF  = (float*)(ws + 1179648);
  float* wkT   = (float*)(ws + 1441792);
  float* cvec  = (float*)(ws + 1703936);
  float* gv    = (float*)(ws + 1704960);
  float* P1    = (float*)(ws + 1705984);
  float* P2    = (float*)(ws + 2099200);
  float* Hpl   = (float*)(ws + 2492416);
  float* Her   = (float*)(ws + 2885632);
  float* ftri  = (float*)(ws + 3278848);
  float* vbuf  = (float*)(ws + 3672064);                  //  589824 B
  float* cbufg = (float*)(ws + 4261888);                  //  589824 B
  unsigned short* Zg = (unsigned short*)(ws + 4851712);   // 75497472 B

  hipMemsetAsync(ftri, 0, NPAR * DD * sizeof(float), stream);
  hipMemsetAsync(cbufg, 0, NPAR * NEPI * sizeof(float), stream);
  transpose_k<<<64, 256, 0, stream>>>(wk_w, wkT);
  fold_kernel<<<512, 256, 0, stream>>>(res_w2, atom_w2, int_w1, simw, MrF, MaF);
  cvec_kernel<<<1, 256, 0, stream>>>(res_b2, atom_b2, int_b1, int_w1, simw, cvec);
  mm_rows<<<256, 256, 0, stream>>>(wq_w, wkT, WqkF);        // Wqk = wq @ wk^T
  gvec_kernel<<<1, 256, 0, stream>>>(wk_w, wq_b, gv);       // g = wk @ bq
  pack_kernel<<<1280, 256, 0, stream>>>(MrF, MaF, int_w2, wg_w, WqkF, wpack);
  mm_rows4<<<1536, 256, 0, stream>>>(H, wl, wr, int_w1, Hpl, Her, P1, P2);
  pair_kernel<<<2304, 256, 0, stream>>>(X, res_w1, res_b1, atom_w1, atom_b1,
                                        int_b2, wg_b, wpack, cvec, gv,
                                        P1, P2, Hpl, Her, ftri, vbuf, Zg);
  attn_kernel<<<2304, 256, 0, stream>>>(Zg, vbuf, wpack, cbufg);
  out_kernel<<<384, 256, 0, stream>>>(Zg, ftri, cbufg, wv_w, wv_b, (float*)d_out);
  hipMemcpyAsync((float*)d_out + NPAR * DD, H + NPAR * DD,
                 (1024 - NPAR) * DD * sizeof(float), hipMemcpyDeviceToDevice, stream);
}

// Round 6
// 456.018 us; speedup vs baseline: 2.2172x; 1.0126x over previous
//
#include <hip/hip_runtime.h>

#define NPAR 384
#define NEPI 384
#define DD   256

using bf16x8 = __bf16 __attribute__((ext_vector_type(8)));
using bf16x2 = __bf16 __attribute__((ext_vector_type(2)));
using f32x4  = float __attribute__((ext_vector_type(4)));

#if defined(__has_builtin)
#if __has_builtin(__builtin_amdgcn_cvt_pk_bf16_f32)
#define HAVE_PK_BF16 1
#endif
#endif

__device__ __forceinline__ float sigm(float x) { return 1.0f / (1.0f + __expf(-x)); }
__device__ __forceinline__ float silu(float x) { return x / (1.0f + __expf(-x)); }
__device__ __forceinline__ unsigned short f2bf(float f) {
  unsigned u = __float_as_uint(f);
  u += 0x7fffu + ((u >> 16) & 1u);
  return (unsigned short)(u >> 16);
}
__device__ __forceinline__ float bf2f(unsigned u16) {
  return __uint_as_float(u16 << 16);
}
__device__ __forceinline__ uint2 pack4(float a, float b, float c, float d) {
  uint2 r;
#ifdef HAVE_PK_BF16
  bf16x2 lo = __builtin_amdgcn_cvt_pk_bf16_f32(a, b);
  bf16x2 hi = __builtin_amdgcn_cvt_pk_bf16_f32(c, d);
  r.x = __builtin_bit_cast(unsigned, lo);
  r.y = __builtin_bit_cast(unsigned, hi);
#else
  r.x = (unsigned)f2bf(a) | ((unsigned)f2bf(b) << 16);
  r.y = (unsigned)f2bf(c) | ((unsigned)f2bf(d) << 16);
#endif
  return r;
}

// ---------------- precompute kernels ----------------

__global__ void fold_kernel(const float* __restrict__ res_w2, const float* __restrict__ atom_w2,
                            const float* __restrict__ int_w1, const float* __restrict__ simw,
                            float* __restrict__ MrF, float* __restrict__ MaF) {
  const int i = blockIdx.x & 255;
  const bool isMa = blockIdx.x >= 256;
  const float wmix = 1.0f / (1.0f + __expf(-simw[0]));
  const float sc = isMa ? (1.0f - wmix) : wmix;
  const float* W2 = isMa ? atom_w2 : res_w2;
  const int j = threadIdx.x;
  float acc = 0.f;
#pragma unroll 8
  for (int k = 0; k < 256; ++k)
    acc += W2[i * 256 + k] * int_w1[(512 + k) * 256 + j];
  (isMa ? MaF : MrF)[i * 256 + j] = acc * sc;
}

// cvec partials: 8 blocks, block b covers k in [b*32, b*32+32); cvec pre-zeroed
__global__ void cvec_kernel(const float* __restrict__ res_b2, const float* __restrict__ atom_b2,
                            const float* __restrict__ int_b1, const float* __restrict__ int_w1,
                            const float* __restrict__ simw, float* __restrict__ cvec) {
  const int j = threadIdx.x, b = blockIdx.x;
  const float wmix = 1.0f / (1.0f + __expf(-simw[0]));
  float acc = (b == 0) ? int_b1[j] : 0.f;
#pragma unroll
  for (int k = b * 32; k < b * 32 + 32; ++k) {
    float bm = wmix * res_b2[k] + (1.0f - wmix) * atom_b2[k];
    acc += bm * int_w1[(512 + k) * 256 + j];
  }
  atomicAdd(&cvec[j], acc);
}

// 32x32-tiled transpose: AT[i][j] = A[j][i], 256x256
__global__ void transpose_k(const float* __restrict__ A, float* __restrict__ AT) {
  __shared__ float tile[32][33];
  const int bx = blockIdx.x & 7, by = blockIdx.x >> 3;
  const int tx = threadIdx.x & 31, ty = threadIdx.x >> 5;
  for (int r = 0; r < 32; r += 8)
    tile[ty + r][tx] = A[(by * 32 + ty + r) * 256 + bx * 32 + tx];
  __syncthreads();
  for (int r = 0; r < 32; r += 8)
    AT[(bx * 32 + ty + r) * 256 + by * 32 + tx] = tile[tx][ty + r];
}

// g[d] = sum_c wk[d,c] * bq[c] ; 64 blocks x 4 waves, one d per wave
__global__ void gvec_kernel(const float* __restrict__ wk, const float* __restrict__ bq,
                            float* __restrict__ gv) {
  const int lane = threadIdx.x & 63, w = threadIdx.x >> 6;
  const int d = blockIdx.x * 4 + w;
  float acc = 0.f;
#pragma unroll
  for (int i = 0; i < 4; ++i) {
    const int c = i * 64 + lane;
    acc += wk[d * 256 + c] * bq[c];
  }
  acc += __shfl_xor(acc, 1);
  acc += __shfl_xor(acc, 2);
  acc += __shfl_xor(acc, 4);
  acc += __shfl_xor(acc, 8);
  acc += __shfl_xor(acc, 16);
  acc += __shfl_xor(acc, 32);
  if (lane == 0) gv[d] = acc;
}

// pack 5 [256,256] matrices into MFMA fragment order:
// wpack[m][((ks*16+tile)*64 + lane)*8 + j] = W[k = ks*32 + (lane>>4)*8 + j][n = tile*16 + (lane&15)]
// slots: 0=Mr 1=Ma 2=int_w2 3=wg 4=Wqk
__global__ void pack_kernel(const float* __restrict__ MrF, const float* __restrict__ MaF,
                            const float* __restrict__ w2, const float* __restrict__ wg,
                            const float* __restrict__ WqkF, unsigned short* __restrict__ wpack) {
  const int idx = blockIdx.x * 256 + threadIdx.x;
  const int m = idx >> 16;
  const int r = idx & 65535;
  const int chunk = r >> 9;
  const int lane = (r >> 3) & 63;
  const int j = r & 7;
  const int k = (chunk >> 4) * 32 + (lane >> 4) * 8 + j;
  const int n = (chunk & 15) * 16 + (lane & 15);
  const float* src;
  switch (m) {
    case 0: src = MrF; break;
    case 1: src = MaF; break;
    case 2: src = w2; break;
    case 3: src = wg; break;
    default: src = WqkF; break;
  }
  wpack[idx] = f2bf(src[k * 256 + n]);
}

// fused 4x: Hpl = Hp@wl, Her = He@wr, P1 = Hp@W1a, P2 = He@W1b
__global__ void mm_rows4(const float* __restrict__ H, const float* __restrict__ wl,
                         const float* __restrict__ wr, const float* __restrict__ int_w1,
                         float* __restrict__ Hpl, float* __restrict__ Her,
                         float* __restrict__ P1, float* __restrict__ P2) {
  const int seg = blockIdx.x / 384, r = blockIdx.x % 384;
  const float* A;
  const float* B;
  float* C;
  switch (seg) {
    case 0:  A = H + r * 256;            B = wl;              C = Hpl + r * 256; break;
    case 1:  A = H + (NPAR + r) * 256;   B = wr;              C = Her + r * 256; break;
    case 2:  A = H + r * 256;            B = int_w1;          C = P1 + r * 256;  break;
    default: A = H + (NPAR + r) * 256;   B = int_w1 + 65536;  C = P2 + r * 256;  break;
  }
  const int j = threadIdx.x;
  float acc = 0.f;
#pragma unroll 8
  for (int k = 0; k < 256; ++k)
    acc += A[k] * B[k * 256 + j];
  C[j] = acc;
}

// C[r][j] = sum_k A[r][k] * B[k][j]  (grid = #rows) — for Wqk
__global__ void mm_rows(const float* __restrict__ A, const float* __restrict__ B,
                        float* __restrict__ C) {
  const int r = blockIdx.x, j = threadIdx.x;
  float acc = 0.f;
#pragma unroll 8
  for (int k = 0; k < 256; ++k)
    acc += A[r * 256 + k] * B[k * 256 + j];
  C[r * 256 + j] = acc;
}

// ---------------- pairwise GEMM-chain kernel (64-row tiles) ----------------

__device__ __forceinline__ void zero_acc4(f32x4 (&acc)[4][4]) {
#pragma unroll
  for (int mt = 0; mt < 4; ++mt)
#pragma unroll
    for (int nt = 0; nt < 4; ++nt)
      acc[mt][nt] = (f32x4){0.f, 0.f, 0.f, 0.f};
}

// transposed-acc: mfma(Wfrag, ActFrag) -> acc^T[d][e]
// d = wv*64 + mt*16 + l4*4 + r, e = nt*16 + l15
__device__ __forceinline__ void gemm4(f32x4 (&acc)[4][4],
                                      const unsigned short* __restrict__ wp,
                                      const unsigned short* ub, int lane, int wv) {
  const int l15 = lane & 15, l4 = lane >> 4;
#pragma unroll
  for (int ks = 0; ks < 8; ++ks) {
    bf16x8 a[4];
#pragma unroll
    for (int mt = 0; mt < 4; ++mt)
      a[mt] = *reinterpret_cast<const bf16x8*>(wp + ((ks * 16 + wv * 4 + mt) * 64 + lane) * 8);
#pragma unroll
    for (int nt = 0; nt < 4; ++nt) {
      bf16x8 b = *reinterpret_cast<const bf16x8*>(ub + (nt * 16 + l15) * 264 + ks * 32 + l4 * 8);
#pragma unroll
      for (int mt = 0; mt < 4; ++mt)
        acc[mt][nt] = __builtin_amdgcn_mfma_f32_16x16x32_bf16(a[mt], b, acc[mt][nt], 0, 0, 0);
    }
  }
}

// fill ubuf[e][d] = silu(Sv[e]*w1[d] + b1[d]) ; thread owns 8 contiguous d, b128 writes
__device__ __forceinline__ void fill_u(unsigned short* ub, const float* Sv,
                                       const float* __restrict__ w1,
                                       const float* __restrict__ b1, int t) {
  const int dg = t & 31, rb = t >> 5;
  const f32x4 w1a = *reinterpret_cast<const f32x4*>(&w1[dg * 8]);
  const f32x4 w1b = *reinterpret_cast<const f32x4*>(&w1[dg * 8 + 4]);
  const f32x4 b1a = *reinterpret_cast<const f32x4*>(&b1[dg * 8]);
  const f32x4 b1b = *reinterpret_cast<const f32x4*>(&b1[dg * 8 + 4]);
#pragma unroll
  for (int i = 0; i < 8; ++i) {
    const int e = rb + i * 8;
    const float s = Sv[e];
    uint2 lo = pack4(silu(fmaf(s, w1a[0], b1a[0])), silu(fmaf(s, w1a[1], b1a[1])),
                     silu(fmaf(s, w1a[2], b1a[2])), silu(fmaf(s, w1a[3], b1a[3])));
    uint2 hi = pack4(silu(fmaf(s, w1b[0], b1b[0])), silu(fmaf(s, w1b[1], b1b[1])),
                     silu(fmaf(s, w1b[2], b1b[2])), silu(fmaf(s, w1b[3], b1b[3])));
    uint4 pk = {lo.x, lo.y, hi.x, hi.y};
    *reinterpret_cast<uint4*>(&ub[e * 264 + dg * 8]) = pk;
  }
}

__global__ __launch_bounds__(256, 4) void pair_kernel(
    const float* __restrict__ Xg,
    const float* __restrict__ res_w1, const float* __restrict__ res_b1,
    const float* __restrict__ atom_w1, const float* __restrict__ atom_b1,
    const float* __restrict__ int_b2, const float* __restrict__ wg_b,
    const unsigned short* __restrict__ wpack, const float* __restrict__ cvec,
    const float* __restrict__ gv,
    const float* __restrict__ P1, const float* __restrict__ P2,
    const float* __restrict__ Hpl, const float* __restrict__ Her,
    float* __restrict__ ftri, float* __restrict__ vbuf,
    unsigned short* __restrict__ Zg) {
  __shared__ __align__(16) unsigned short ubuf[64 * 264];
  __shared__ float Sv[64];
  __shared__ float pc[DD];
  __shared__ float vred[256];
  const int t = threadIdx.x, lane = t & 63, wv = t >> 6;
  const int l15 = lane & 15, l4 = lane >> 4;
  const int p = blockIdx.x / 6, e0 = (blockIdx.x % 6) * 64;
  const int d0 = wv * 64;

  if (t < 64) {
    const int e = e0 + t;
    float dx = Xg[p * 42 + 3] - Xg[(NPAR + e) * 42 + 3];
    float dy = Xg[p * 42 + 4] - Xg[(NPAR + e) * 42 + 4];
    float dz = Xg[p * 42 + 5] - Xg[(NPAR + e) * 42 + 5];
    Sv[t] = dx * dx + dy * dy + dz * dz;
  }
  pc[t] = P1[p * DD + t] + cvec[t];
  __syncthreads();

  f32x4 acc[4][4];
  zero_acc4(acc);

  fill_u(ubuf, Sv, res_w1, res_b1, t);
  __syncthreads();
  gemm4(acc, wpack + 0 * 65536, ubuf, lane, wv);
  __syncthreads();
  fill_u(ubuf, Sv, atom_w1, atom_b1, t);
  __syncthreads();
  gemm4(acc, wpack + 1 * 65536, ubuf, lane, wv);
  __syncthreads();

  // epilogue: h = silu(zpre^T + pc[d] + P2[e][d]) -> ubuf[e][d]
#pragma unroll
  for (int mt = 0; mt < 4; ++mt) {
    const int d = d0 + mt * 16 + l4 * 4;
    const f32x4 pcv = *reinterpret_cast<const f32x4*>(&pc[d]);
#pragma unroll
    for (int nt = 0; nt < 4; ++nt) {
      const int e = nt * 16 + l15;
      const f32x4 p2v = *reinterpret_cast<const f32x4*>(&P2[(e0 + e) * DD + d]);
      uint2 pk = pack4(silu(acc[mt][nt][0] + pcv[0] + p2v[0]),
                       silu(acc[mt][nt][1] + pcv[1] + p2v[1]),
                       silu(acc[mt][nt][2] + pcv[2] + p2v[2]),
                       silu(acc[mt][nt][3] + pcv[3] + p2v[3]));
      *reinterpret_cast<uint2*>(&ubuf[e * 264 + d]) = pk;
    }
  }
  __syncthreads();

  // Z = h @ int_w2 + int_b2 -> ubuf; v[e] = Z[e,:] . gv
  zero_acc4(acc);
  gemm4(acc, wpack + 2 * 65536, ubuf, lane, wv);
  __syncthreads();
  {
    float vp[4] = {0.f, 0.f, 0.f, 0.f};
#pragma unroll
    for (int mt = 0; mt < 4; ++mt) {
      const int d = d0 + mt * 16 + l4 * 4;
      const f32x4 bb = *reinterpret_cast<const f32x4*>(&int_b2[d]);
      const f32x4 gq = *reinterpret_cast<const f32x4*>(&gv[d]);
#pragma unroll
      for (int nt = 0; nt < 4; ++nt) {
        const int e = nt * 16 + l15;
        float z0 = acc[mt][nt][0] + bb[0];
        float z1 = acc[mt][nt][1] + bb[1];
        float z2 = acc[mt][nt][2] + bb[2];
        float z3 = acc[mt][nt][3] + bb[3];
        *reinterpret_cast<uint2*>(&ubuf[e * 264 + d]) = pack4(z0, z1, z2, z3);
        vp[nt] += z0 * gq[0] + z1 * gq[1] + z2 * gq[2] + z3 * gq[3];
      }
    }
#pragma unroll
    for (int nt = 0; nt < 4; ++nt) {
      float v = vp[nt];
      v += __shfl_xor(v, 16);
      v += __shfl_xor(v, 32);
      if (lane < 16) vred[wv * 64 + nt * 16 + lane] = v;
    }
  }
  __syncthreads();
  if (t < 64)
    vbuf[p * NEPI + e0 + t] = vred[t] + vred[64 + t] + vred[128 + t] + vred[192 + t];

  // coalesced Z store: ubuf -> Zg
#pragma unroll
  for (int i = 0; i < 8; ++i) {
    const int idx = i * 256 + t;
    const int row = idx >> 5, c16 = idx & 31;
    *reinterpret_cast<uint4*>(&Zg[((size_t)(p * NEPI) + e0 + row) * DD + c16 * 8]) =
        *reinterpret_cast<const uint4*>(&ubuf[row * 264 + c16 * 8]);
  }

  // gate: f_tri[d] += Hpl[p][d] * sum_e sigm(Zg^T + b) * Her[e][d]
  zero_acc4(acc);
  gemm4(acc, wpack + 3 * 65536, ubuf, lane, wv);
#pragma unroll
  for (int mt = 0; mt < 4; ++mt) {
    const int d = d0 + mt * 16 + l4 * 4;
    const f32x4 bb = *reinterpret_cast<const f32x4*>(&wg_b[d]);
    const f32x4 hl = *reinterpret_cast<const f32x4*>(&Hpl[p * DD + d]);
    f32x4 fs = (f32x4){0.f, 0.f, 0.f, 0.f};
#pragma unroll
    for (int nt = 0; nt < 4; ++nt) {
      const int e = e0 + nt * 16 + l15;
      const f32x4 hr = *reinterpret_cast<const f32x4*>(&Her[e * DD + d]);
#pragma unroll
      for (int r = 0; r < 4; ++r)
        fs[r] += sigm(acc[mt][nt][r] + bb[r]) * hr[r];
    }
#pragma unroll
    for (int r = 0; r < 4; ++r) {
      float v = fs[r] * hl[r];
      v += __shfl_xor(v, 1);
      v += __shfl_xor(v, 2);
      v += __shfl_xor(v, 4);
      v += __shfl_xor(v, 8);
      if (l15 == 0) atomicAdd(&ftri[p * DD + d + r], v);
    }
  }
}

// ---------------- fused attention kernel: block = (p, 64-row chunk) ----------------
// scores = (Z_c Wqk Z^T + 1 v^T) / 16 ; col-sums of softmax -> cbufg[p]
// r6: double-buffered global b-frag prefetch in T and S phases.

__global__ __launch_bounds__(256, 2) void attn_kernel(
    const unsigned short* __restrict__ Zg, const float* __restrict__ vbuf,
    const unsigned short* __restrict__ wpack, float* __restrict__ cbufg) {
  __shared__ __align__(16) unsigned short Tc[64 * 264];
  __shared__ float vb[NEPI];
  __shared__ float red[256];
  __shared__ float red2[256];
  const int t = threadIdx.x, lane = t & 63, wv = t >> 6;
  const int l15 = lane & 15, l4 = lane >> 4;
  // XCD swizzle: all 6 chunks of one p land on the same XCD (xcd = blk % 8)
  const int xcd = blockIdx.x & 7, inner = blockIdx.x >> 3;
  const int p = (inner / 6) * 8 + xcd, c = inner % 6;
  const unsigned short* Zp = Zg + (size_t)p * NEPI * DD;
  const unsigned short* wqk = wpack + 4 * 65536;

  for (int i = t; i < NEPI; i += 256) vb[i] = vbuf[p * NEPI + i];

  // T = Zc @ Wqk (transposed acc), b-frags double-buffered from global
  {
    f32x4 ta[4][4];
#pragma unroll
    for (int mt = 0; mt < 4; ++mt)
#pragma unroll
      for (int nt = 0; nt < 4; ++nt) ta[mt][nt] = (f32x4){0.f, 0.f, 0.f, 0.f};
    const unsigned short* Zb = Zp + (size_t)(c * 64 + l15) * DD + l4 * 8;
    bf16x8 bcur[4], bnxt[4];
#pragma unroll
    for (int nt = 0; nt < 4; ++nt)
      bcur[nt] = *reinterpret_cast<const bf16x8*>(Zb + nt * 16 * DD);
#pragma unroll
    for (int ks = 0; ks < 8; ++ks) {
      if (ks < 7) {
#pragma unroll
        for (int nt = 0; nt < 4; ++nt)
          bnxt[nt] = *reinterpret_cast<const bf16x8*>(Zb + nt * 16 * DD + (ks + 1) * 32);
      }
      bf16x8 a[4];
#pragma unroll
      for (int mt = 0; mt < 4; ++mt)
        a[mt] = *reinterpret_cast<const bf16x8*>(wqk + ((ks * 16 + wv * 4 + mt) * 64 + lane) * 8);
#pragma unroll
      for (int nt = 0; nt < 4; ++nt)
#pragma unroll
        for (int mt = 0; mt < 4; ++mt)
          ta[mt][nt] = __builtin_amdgcn_mfma_f32_16x16x32_bf16(a[mt], bcur[nt], ta[mt][nt], 0, 0, 0);
      if (ks < 7) {
#pragma unroll
        for (int nt = 0; nt < 4; ++nt) bcur[nt] = bnxt[nt];
      }
    }
#pragma unroll
    for (int mt = 0; mt < 4; ++mt) {
      const int d = wv * 64 + mt * 16 + l4 * 4;
#pragma unroll
      for (int nt = 0; nt < 4; ++nt) {
        const int e = nt * 16 + l15;
        *reinterpret_cast<uint2*>(&Tc[e * 264 + d]) =
            pack4(ta[mt][nt][0], ta[mt][nt][1], ta[mt][nt][2], ta[mt][nt][3]);
      }
    }
  }
  __syncthreads();

  // S = Tc @ Z^T; a-frags from LDS, b-frags double-buffered from global
  f32x4 sc[4][6];
#pragma unroll
  for (int mt = 0; mt < 4; ++mt)
#pragma unroll
    for (int s = 0; s < 6; ++s) sc[mt][s] = (f32x4){0.f, 0.f, 0.f, 0.f};

  {
    const unsigned short* Zb = Zp + (size_t)(wv * 16 + l15) * DD + l4 * 8;
    bf16x8 bcur[6], bnxt[6];
#pragma unroll
    for (int s = 0; s < 6; ++s)
      bcur[s] = *reinterpret_cast<const bf16x8*>(Zb + (size_t)s * 64 * DD);
#pragma unroll
    for (int ks = 0; ks < 8; ++ks) {
      if (ks < 7) {
#pragma unroll
        for (int s = 0; s < 6; ++s)
          bnxt[s] = *reinterpret_cast<const bf16x8*>(Zb + (size_t)s * 64 * DD + (ks + 1) * 32);
      }
      bf16x8 a[4];
#pragma unroll
      for (int mt = 0; mt < 4; ++mt)
        a[mt] = *reinterpret_cast<const bf16x8*>(&Tc[(mt * 16 + l15) * 264 + ks * 32 + l4 * 8]);
#pragma unroll
      for (int s = 0; s < 6; ++s)
#pragma unroll
        for (int mt = 0; mt < 4; ++mt)
          sc[mt][s] = __builtin_amdgcn_mfma_f32_16x16x32_bf16(a[mt], bcur[s], sc[mt][s], 0, 0, 0);
      if (ks < 7) {
#pragma unroll
        for (int s = 0; s < 6; ++s) bcur[s] = bnxt[s];
      }
    }
  }

  // softmax over f (384 cols), rows e = mt*16 + l4*4 + r
  const float scl = 0.0625f;
  float fv[6];
#pragma unroll
  for (int s = 0; s < 6; ++s)
    fv[s] = vb[s * 64 + wv * 16 + l15];

  float rmax[4][4];
#pragma unroll
  for (int mt = 0; mt < 4; ++mt) {
#pragma unroll
    for (int r = 0; r < 4; ++r) {
      float m = -1e30f;
#pragma unroll
      for (int s = 0; s < 6; ++s) {
        sc[mt][s][r] = (sc[mt][s][r] + fv[s]) * scl;
        m = fmaxf(m, sc[mt][s][r]);
      }
      m = fmaxf(m, __shfl_xor(m, 1));
      m = fmaxf(m, __shfl_xor(m, 2));
      m = fmaxf(m, __shfl_xor(m, 4));
      m = fmaxf(m, __shfl_xor(m, 8));
      rmax[mt][r] = m;
    }
  }
  if (l15 == 0) {
#pragma unroll
    for (int mt = 0; mt < 4; ++mt)
#pragma unroll
      for (int r = 0; r < 4; ++r)
        red[wv * 64 + mt * 16 + l4 * 4 + r] = rmax[mt][r];
  }
  __syncthreads();
#pragma unroll
  for (int mt = 0; mt < 4; ++mt) {
#pragma unroll
    for (int r = 0; r < 4; ++r) {
      const int row = mt * 16 + l4 * 4 + r;
      rmax[mt][r] = fmaxf(fmaxf(red[row], red[64 + row]), fmaxf(red[128 + row], red[192 + row]));
    }
  }

  float rsum[4][4];
#pragma unroll
  for (int mt = 0; mt < 4; ++mt) {
#pragma unroll
    for (int r = 0; r < 4; ++r) {
      float sSum = 0.f;
#pragma unroll
      for (int s = 0; s < 6; ++s) {
        float e = __expf(sc[mt][s][r] - rmax[mt][r]);
        sc[mt][s][r] = e;
        sSum += e;
      }
      sSum += __shfl_xor(sSum, 1);
      sSum += __shfl_xor(sSum, 2);
      sSum += __shfl_xor(sSum, 4);
      sSum += __shfl_xor(sSum, 8);
      rsum[mt][r] = sSum;
    }
  }
  if (l15 == 0) {
#pragma unroll
    for (int mt = 0; mt < 4; ++mt)
#pragma unroll
      for (int r = 0; r < 4; ++r)
        red2[wv * 64 + mt * 16 + l4 * 4 + r] = rsum[mt][r];
  }
  __syncthreads();
  float rinv[4][4];
#pragma unroll
  for (int mt = 0; mt < 4; ++mt) {
#pragma unroll
    for (int r = 0; r < 4; ++r) {
      const int row = mt * 16 + l4 * 4 + r;
      rinv[mt][r] = 1.0f / (red2[row] + red2[64 + row] + red2[128 + row] + red2[192 + row]);
    }
  }

  // column sums of A over this chunk's 64 rows -> cbufg
#pragma unroll
  for (int s = 0; s < 6; ++s) {
    float v = 0.f;
#pragma unroll
    for (int mt = 0; mt < 4; ++mt)
#pragma unroll
      for (int r = 0; r < 4; ++r)
        v += sc[mt][s][r] * rinv[mt][r];
    v += __shfl_xor(v, 16);
    v += __shfl_xor(v, 32);
    if (lane < 16)
      atomicAdd(&cbufg[p * NEPI + s * 64 + wv * 16 + lane], v);
  }
}

// ---------------- output kernel ----------------
// out[p] = (ftri[p] + (c^T Z_p) @ wv + 384*bv) / 384
// r6: b128 Z loads via (fg,dg) split + LDS partial reduce

__global__ __launch_bounds__(256) void out_kernel(
    const unsigned short* __restrict__ Zg, const float* __restrict__ ftri,
    const float* __restrict__ cbufg, const float* __restrict__ wvw,
    const float* __restrict__ wvb, float* __restrict__ out) {
  __shared__ float cb[NEPI];
  __shared__ float part[8][257];
  __shared__ float u[DD];
  const int p = blockIdx.x, t = threadIdx.x;
  const int fg = t >> 5, dg = t & 31;
  for (int i = t; i < NEPI; i += 256) cb[i] = cbufg[p * NEPI + i];
  __syncthreads();
  const unsigned short* Zp = Zg + (size_t)p * NEPI * DD;
  float a8[8] = {0.f, 0.f, 0.f, 0.f, 0.f, 0.f, 0.f, 0.f};
#pragma unroll 4
  for (int i = 0; i < 48; ++i) {
    const int f = fg + i * 8;
    const uint4 zz = *reinterpret_cast<const uint4*>(&Zp[f * DD + dg * 8]);
    const float w = cb[f];
    a8[0] = fmaf(w, bf2f(zz.x & 0xffffu), a8[0]);
    a8[1] = fmaf(w, bf2f(zz.x >> 16), a8[1]);
    a8[2] = fmaf(w, bf2f(zz.y & 0xffffu), a8[2]);
    a8[3] = fmaf(w, bf2f(zz.y >> 16), a8[3]);
    a8[4] = fmaf(w, bf2f(zz.z & 0xffffu), a8[4]);
    a8[5] = fmaf(w, bf2f(zz.z >> 16), a8[5]);
    a8[6] = fmaf(w, bf2f(zz.w & 0xffffu), a8[6]);
    a8[7] = fmaf(w, bf2f(zz.w >> 16), a8[7]);
  }
#pragma unroll
  for (int j = 0; j < 8; ++j) part[fg][dg * 8 + j] = a8[j];
  __syncthreads();
  float uu = 0.f;
#pragma unroll
  for (int g = 0; g < 8; ++g) uu += part[g][t];
  u[t] = uu;
  __syncthreads();
  float acc = ftri[p * DD + t] + 384.0f * wvb[t];
#pragma unroll 8
  for (int d = 0; d < DD; ++d)
    acc = fmaf(u[d], wvw[d * DD + t], acc);
  out[p * DD + t] = acc * (1.0f / 384.0f);
}

// ---------------- launch ----------------

extern "C" void kernel_launch(void* const* d_in, const int* in_sizes, int n_in,
                              void* d_out, int out_size, void* d_ws, size_t ws_size,
                              hipStream_t stream) {
  (void)in_sizes; (void)n_in; (void)out_size; (void)ws_size;
  const float* H = (const float*)d_in[0];
  const float* X = (const float*)d_in[1];
  const float* res_w1 = (const float*)d_in[4];
  const float* res_b1 = (const float*)d_in[5];
  const float* res_w2 = (const float*)d_in[6];
  const float* res_b2 = (const float*)d_in[7];
  const float* atom_w1 = (const float*)d_in[8];
  const float* atom_b1 = (const float*)d_in[9];
  const float* atom_w2 = (const float*)d_in[10];
  const float* atom_b2 = (const float*)d_in[11];
  const float* simw = (const float*)d_in[12];
  const float* int_w1 = (const float*)d_in[13];
  const float* int_b1 = (const float*)d_in[14];
  const float* int_w2 = (const float*)d_in[15];
  const float* int_b2 = (const float*)d_in[16];
  const float* wl = (const float*)d_in[17];
  const float* wr = (const float*)d_in[18];
  const float* wg_w = (const float*)d_in[19];
  const float* wg_b = (const float*)d_in[20];
  const float* wq_w = (const float*)d_in[21];
  const float* wq_b = (const float*)d_in[22];
  const float* wk_w = (const float*)d_in[23];
  const float* wv_w = (const float*)d_in[25];
  const float* wv_b = (const float*)d_in[26];

  char* ws = (char*)d_ws;
  unsigned short* wpack = (unsigned short*)(ws + 0);      //  655360 B (5 slots)
  float* MrF   = (float*)(ws + 655360);
  float* MaF   = (float*)(ws + 917504);
  float* WqkF  = (float*)(ws + 1179648);
  float* wkT   = (float*)(ws + 1441792);
  float* cvec  = (float*)(ws + 1703936);
  float* gv    = (float*)(ws + 1704960);
  float* P1    = (float*)(ws + 1705984);
  float* P2    = (float*)(ws + 2099200);
  float* Hpl   = (float*)(ws + 2492416);
  float* Her   = (float*)(ws + 2885632);
  float* ftri  = (float*)(ws + 3278848);
  float* vbuf  = (float*)(ws + 3672064);                  //  589824 B
  float* cbufg = (float*)(ws + 4261888);                  //  589824 B
  unsigned short* Zg = (unsigned short*)(ws + 4851712);   // 75497472 B

  hipMemsetAsync(ftri, 0, NPAR * DD * sizeof(float), stream);
  hipMemsetAsync(cbufg, 0, NPAR * NEPI * sizeof(float), stream);
  hipMemsetAsync(cvec, 0, DD * sizeof(float), stream);
  transpose_k<<<64, 256, 0, stream>>>(wk_w, wkT);
  fold_kernel<<<512, 256, 0, stream>>>(res_w2, atom_w2, int_w1, simw, MrF, MaF);
  cvec_kernel<<<8, 256, 0, stream>>>(res_b2, atom_b2, int_b1, int_w1, simw, cvec);
  mm_rows<<<256, 256, 0, stream>>>(wq_w, wkT, WqkF);        // Wqk = wq @ wk^T
  gvec_kernel<<<64, 256, 0, stream>>>(wk_w, wq_b, gv);      // g = wk @ bq
  pack_kernel<<<1280, 256, 0, stream>>>(MrF, MaF, int_w2, wg_w, WqkF, wpack);
  mm_rows4<<<1536, 256, 0, stream>>>(H, wl, wr, int_w1, Hpl, Her, P1, P2);
  pair_kernel<<<2304, 256, 0, stream>>>(X, res_w1, res_b1, atom_w1, atom_b1,
                                        int_b2, wg_b, wpack, cvec, gv,
                                        P1, P2, Hpl, Her, ftri, vbuf, Zg);
  attn_kernel<<<2304, 256, 0, stream>>>(Zg, vbuf, wpack, cbufg);
  out_kernel<<<384, 256, 0, stream>>>(Zg, ftri, cbufg, wv_w, wv_b, (float*)d_out);
  hipMemcpyAsync((float*)d_out + NPAR * DD, H + NPAR * DD,
                 (1024 - NPAR) * DD * sizeof(float), hipMemcpyDeviceToDevice, stream);
}

// Round 7
// 398.968 us; speedup vs baseline: 2.5343x; 1.1430x over previous
//
#include <hip/hip_runtime.h>

#define NPAR 384
#define NEPI 384
#define DD   256

using bf16x8 = __bf16 __attribute__((ext_vector_type(8)));
using bf16x2 = __bf16 __attribute__((ext_vector_type(2)));
using f32x4  = float __attribute__((ext_vector_type(4)));

#if defined(__has_builtin)
#if __has_builtin(__builtin_amdgcn_cvt_pk_bf16_f32)
#define HAVE_PK_BF16 1
#endif
#endif

__device__ __forceinline__ float sigm(float x) { return 1.0f / (1.0f + __expf(-x)); }
__device__ __forceinline__ float silu(float x) { return x / (1.0f + __expf(-x)); }
__device__ __forceinline__ unsigned short f2bf(float f) {
  unsigned u = __float_as_uint(f);
  u += 0x7fffu + ((u >> 16) & 1u);
  return (unsigned short)(u >> 16);
}
__device__ __forceinline__ float bf2f(unsigned u16) {
  return __uint_as_float(u16 << 16);
}
__device__ __forceinline__ uint2 pack4(float a, float b, float c, float d) {
  uint2 r;
#ifdef HAVE_PK_BF16
  bf16x2 lo = __builtin_amdgcn_cvt_pk_bf16_f32(a, b);
  bf16x2 hi = __builtin_amdgcn_cvt_pk_bf16_f32(c, d);
  r.x = __builtin_bit_cast(unsigned, lo);
  r.y = __builtin_bit_cast(unsigned, hi);
#else
  r.x = (unsigned)f2bf(a) | ((unsigned)f2bf(b) << 16);
  r.y = (unsigned)f2bf(c) | ((unsigned)f2bf(d) << 16);
#endif
  return r;
}

// ---------------- fused precompute kernel ----------------
// block ranges: [0,64) transpose wk->wkT ; [64,576) fold Mr/Ma ; [576,584) cvec ;
// [584,648) gvec ; [648,2184) mm_rows4 (Hpl/Her/P1/P2)

__global__ void prep_kernel(
    const float* __restrict__ H, const float* __restrict__ wl,
    const float* __restrict__ wr, const float* __restrict__ int_w1,
    const float* __restrict__ res_w2, const float* __restrict__ atom_w2,
    const float* __restrict__ res_b2, const float* __restrict__ atom_b2,
    const float* __restrict__ int_b1, const float* __restrict__ simw,
    const float* __restrict__ wq_b, const float* __restrict__ wk_w,
    float* __restrict__ Hpl, float* __restrict__ Her,
    float* __restrict__ P1, float* __restrict__ P2,
    float* __restrict__ MrF, float* __restrict__ MaF,
    float* __restrict__ cvec, float* __restrict__ gv,
    float* __restrict__ wkT) {
  __shared__ float tile[32][33];
  const int b = blockIdx.x, t = threadIdx.x;
  if (b < 64) {
    const int bx = b & 7, by = b >> 3;
    const int tx = t & 31, ty = t >> 5;
    for (int r = 0; r < 32; r += 8)
      tile[ty + r][tx] = wk_w[(by * 32 + ty + r) * 256 + bx * 32 + tx];
    __syncthreads();
    for (int r = 0; r < 32; r += 8)
      wkT[(bx * 32 + ty + r) * 256 + by * 32 + tx] = tile[tx][ty + r];
  } else if (b < 576) {
    const int bb = b - 64;
    const int i = bb & 255;
    const bool isMa = bb >= 256;
    const float wmix = 1.0f / (1.0f + __expf(-simw[0]));
    const float sc = isMa ? (1.0f - wmix) : wmix;
    const float* W2 = isMa ? atom_w2 : res_w2;
    float acc = 0.f;
#pragma unroll 8
    for (int k = 0; k < 256; ++k)
      acc += W2[i * 256 + k] * int_w1[(512 + k) * 256 + t];
    (isMa ? MaF : MrF)[i * 256 + t] = acc * sc;
  } else if (b < 584) {
    const int bb = b - 576;
    const float wmix = 1.0f / (1.0f + __expf(-simw[0]));
    float acc = (bb == 0) ? int_b1[t] : 0.f;
#pragma unroll
    for (int k = bb * 32; k < bb * 32 + 32; ++k) {
      float bm = wmix * res_b2[k] + (1.0f - wmix) * atom_b2[k];
      acc += bm * int_w1[(512 + k) * 256 + t];
    }
    atomicAdd(&cvec[t], acc);
  } else if (b < 648) {
    const int lane = t & 63, w = t >> 6;
    const int d = (b - 584) * 4 + w;
    float acc = 0.f;
#pragma unroll
    for (int i = 0; i < 4; ++i) {
      const int c = i * 64 + lane;
      acc += wk_w[d * 256 + c] * wq_b[c];
    }
    acc += __shfl_xor(acc, 1);
    acc += __shfl_xor(acc, 2);
    acc += __shfl_xor(acc, 4);
    acc += __shfl_xor(acc, 8);
    acc += __shfl_xor(acc, 16);
    acc += __shfl_xor(acc, 32);
    if (lane == 0) gv[d] = acc;
  } else {
    const int idx = b - 648;
    const int seg = idx / 384, r = idx % 384;
    const float* A;
    const float* B;
    float* C;
    switch (seg) {
      case 0:  A = H + r * 256;            B = wl;              C = Hpl + r * 256; break;
      case 1:  A = H + (NPAR + r) * 256;   B = wr;              C = Her + r * 256; break;
      case 2:  A = H + r * 256;            B = int_w1;          C = P1 + r * 256;  break;
      default: A = H + (NPAR + r) * 256;   B = int_w1 + 65536;  C = P2 + r * 256;  break;
    }
    float acc = 0.f;
#pragma unroll 8
    for (int k = 0; k < 256; ++k)
      acc += A[k] * B[k * 256 + t];
    C[t] = acc;
  }
}

// C[r][j] = sum_k A[r][k] * B[k][j]  (grid = #rows) — for Wqk = wq @ wkT
__global__ void mm_rows(const float* __restrict__ A, const float* __restrict__ B,
                        float* __restrict__ C) {
  const int r = blockIdx.x, j = threadIdx.x;
  float acc = 0.f;
#pragma unroll 8
  for (int k = 0; k < 256; ++k)
    acc += A[r * 256 + k] * B[k * 256 + j];
  C[r * 256 + j] = acc;
}

// pack 5 [256,256] matrices into MFMA fragment order:
// wpack[m][((ks*16+tile)*64 + lane)*8 + j] = W[k = ks*32 + (lane>>4)*8 + j][n = tile*16 + (lane&15)]
// slots: 0=Mr 1=Ma 2=int_w2 3=wg 4=Wqk
__global__ void pack_kernel(const float* __restrict__ MrF, const float* __restrict__ MaF,
                            const float* __restrict__ w2, const float* __restrict__ wg,
                            const float* __restrict__ WqkF, unsigned short* __restrict__ wpack) {
  const int idx = blockIdx.x * 256 + threadIdx.x;
  const int m = idx >> 16;
  const int r = idx & 65535;
  const int chunk = r >> 9;
  const int lane = (r >> 3) & 63;
  const int j = r & 7;
  const int k = (chunk >> 4) * 32 + (lane >> 4) * 8 + j;
  const int n = (chunk & 15) * 16 + (lane & 15);
  const float* src;
  switch (m) {
    case 0: src = MrF; break;
    case 1: src = MaF; break;
    case 2: src = w2; break;
    case 3: src = wg; break;
    default: src = WqkF; break;
  }
  wpack[idx] = f2bf(src[k * 256 + n]);
}

// ---------------- pairwise GEMM-chain kernel (64-row tiles) ----------------

__device__ __forceinline__ void zero_acc4(f32x4 (&acc)[4][4]) {
#pragma unroll
  for (int mt = 0; mt < 4; ++mt)
#pragma unroll
    for (int nt = 0; nt < 4; ++nt)
      acc[mt][nt] = (f32x4){0.f, 0.f, 0.f, 0.f};
}

// transposed-acc: mfma(Wfrag, ActFrag) -> acc^T[d][e]
// d = wv*64 + mt*16 + l4*4 + r, e = nt*16 + l15
__device__ __forceinline__ void gemm4(f32x4 (&acc)[4][4],
                                      const unsigned short* __restrict__ wp,
                                      const unsigned short* ub, int lane, int wv) {
  const int l15 = lane & 15, l4 = lane >> 4;
#pragma unroll
  for (int ks = 0; ks < 8; ++ks) {
    bf16x8 a[4];
#pragma unroll
    for (int mt = 0; mt < 4; ++mt)
      a[mt] = *reinterpret_cast<const bf16x8*>(wp + ((ks * 16 + wv * 4 + mt) * 64 + lane) * 8);
#pragma unroll
    for (int nt = 0; nt < 4; ++nt) {
      bf16x8 b = *reinterpret_cast<const bf16x8*>(ub + (nt * 16 + l15) * 264 + ks * 32 + l4 * 8);
#pragma unroll
      for (int mt = 0; mt < 4; ++mt)
        acc[mt][nt] = __builtin_amdgcn_mfma_f32_16x16x32_bf16(a[mt], b, acc[mt][nt], 0, 0, 0);
    }
  }
}

// fill ubuf[e][d] = silu(Sv[e]*w1[d] + b1[d]) ; thread owns 8 contiguous d, b128 writes
__device__ __forceinline__ void fill_u(unsigned short* ub, const float* Sv,
                                       const float* __restrict__ w1,
                                       const float* __restrict__ b1, int t) {
  const int dg = t & 31, rb = t >> 5;
  const f32x4 w1a = *reinterpret_cast<const f32x4*>(&w1[dg * 8]);
  const f32x4 w1b = *reinterpret_cast<const f32x4*>(&w1[dg * 8 + 4]);
  const f32x4 b1a = *reinterpret_cast<const f32x4*>(&b1[dg * 8]);
  const f32x4 b1b = *reinterpret_cast<const f32x4*>(&b1[dg * 8 + 4]);
#pragma unroll
  for (int i = 0; i < 8; ++i) {
    const int e = rb + i * 8;
    const float s = Sv[e];
    uint2 lo = pack4(silu(fmaf(s, w1a[0], b1a[0])), silu(fmaf(s, w1a[1], b1a[1])),
                     silu(fmaf(s, w1a[2], b1a[2])), silu(fmaf(s, w1a[3], b1a[3])));
    uint2 hi = pack4(silu(fmaf(s, w1b[0], b1b[0])), silu(fmaf(s, w1b[1], b1b[1])),
                     silu(fmaf(s, w1b[2], b1b[2])), silu(fmaf(s, w1b[3], b1b[3])));
    uint4 pk = {lo.x, lo.y, hi.x, hi.y};
    *reinterpret_cast<uint4*>(&ub[e * 264 + dg * 8]) = pk;
  }
}

__global__ __launch_bounds__(256, 3) void pair_kernel(
    const float* __restrict__ Xg,
    const float* __restrict__ res_w1, const float* __restrict__ res_b1,
    const float* __restrict__ atom_w1, const float* __restrict__ atom_b1,
    const float* __restrict__ int_b2, const float* __restrict__ wg_b,
    const unsigned short* __restrict__ wpack, const float* __restrict__ cvec,
    const float* __restrict__ gv,
    const float* __restrict__ P1, const float* __restrict__ P2,
    const float* __restrict__ Hpl, const float* __restrict__ Her,
    float* __restrict__ ftri, float* __restrict__ vbuf,
    unsigned short* __restrict__ Zg, unsigned short* __restrict__ Zsw) {
  __shared__ __align__(16) unsigned short ubuf[64 * 264];
  __shared__ float Sv[64];
  __shared__ float pc[DD];
  __shared__ float vred[256];
  const int t = threadIdx.x, lane = t & 63, wv = t >> 6;
  const int l15 = lane & 15, l4 = lane >> 4;
  const int p = blockIdx.x / 6, cc = blockIdx.x % 6, e0 = cc * 64;
  const int d0 = wv * 64;

  if (t < 64) {
    const int e = e0 + t;
    float dx = Xg[p * 42 + 3] - Xg[(NPAR + e) * 42 + 3];
    float dy = Xg[p * 42 + 4] - Xg[(NPAR + e) * 42 + 4];
    float dz = Xg[p * 42 + 5] - Xg[(NPAR + e) * 42 + 5];
    Sv[t] = dx * dx + dy * dy + dz * dz;
  }
  pc[t] = P1[p * DD + t] + cvec[t];
  __syncthreads();

  f32x4 acc[4][4];
  zero_acc4(acc);

  fill_u(ubuf, Sv, res_w1, res_b1, t);
  __syncthreads();
  gemm4(acc, wpack + 0 * 65536, ubuf, lane, wv);
  __syncthreads();
  fill_u(ubuf, Sv, atom_w1, atom_b1, t);
  __syncthreads();
  gemm4(acc, wpack + 1 * 65536, ubuf, lane, wv);
  __syncthreads();

  // epilogue: h = silu(zpre^T + pc[d] + P2[e][d]) -> ubuf[e][d]
#pragma unroll
  for (int mt = 0; mt < 4; ++mt) {
    const int d = d0 + mt * 16 + l4 * 4;
    const f32x4 pcv = *reinterpret_cast<const f32x4*>(&pc[d]);
#pragma unroll
    for (int nt = 0; nt < 4; ++nt) {
      const int e = nt * 16 + l15;
      const f32x4 p2v = *reinterpret_cast<const f32x4*>(&P2[(e0 + e) * DD + d]);
      uint2 pk = pack4(silu(acc[mt][nt][0] + pcv[0] + p2v[0]),
                       silu(acc[mt][nt][1] + pcv[1] + p2v[1]),
                       silu(acc[mt][nt][2] + pcv[2] + p2v[2]),
                       silu(acc[mt][nt][3] + pcv[3] + p2v[3]));
      *reinterpret_cast<uint2*>(&ubuf[e * 264 + d]) = pk;
    }
  }
  __syncthreads();

  // Z = h @ int_w2 + int_b2 -> ubuf; v[e] = Z[e,:] . gv
  zero_acc4(acc);
  gemm4(acc, wpack + 2 * 65536, ubuf, lane, wv);
  __syncthreads();
  {
    float vp[4] = {0.f, 0.f, 0.f, 0.f};
#pragma unroll
    for (int mt = 0; mt < 4; ++mt) {
      const int d = d0 + mt * 16 + l4 * 4;
      const f32x4 bb = *reinterpret_cast<const f32x4*>(&int_b2[d]);
      const f32x4 gq = *reinterpret_cast<const f32x4*>(&gv[d]);
#pragma unroll
      for (int nt = 0; nt < 4; ++nt) {
        const int e = nt * 16 + l15;
        float z0 = acc[mt][nt][0] + bb[0];
        float z1 = acc[mt][nt][1] + bb[1];
        float z2 = acc[mt][nt][2] + bb[2];
        float z3 = acc[mt][nt][3] + bb[3];
        *reinterpret_cast<uint2*>(&ubuf[e * 264 + d]) = pack4(z0, z1, z2, z3);
        vp[nt] += z0 * gq[0] + z1 * gq[1] + z2 * gq[2] + z3 * gq[3];
      }
    }
#pragma unroll
    for (int nt = 0; nt < 4; ++nt) {
      float v = vp[nt];
      v += __shfl_xor(v, 16);
      v += __shfl_xor(v, 32);
      if (lane < 16) vred[wv * 64 + nt * 16 + lane] = v;
    }
  }
  __syncthreads();
  if (t < 64)
    vbuf[p * NEPI + e0 + t] = vred[t] + vred[64 + t] + vred[128 + t] + vred[192 + t];

  // coalesced row-major Z store: ubuf -> Zg (for out_kernel)
#pragma unroll
  for (int i = 0; i < 8; ++i) {
    const int idx = i * 256 + t;
    const int row = idx >> 5, c16 = idx & 31;
    *reinterpret_cast<uint4*>(&Zg[((size_t)(p * NEPI) + e0 + row) * DD + c16 * 8]) =
        *reinterpret_cast<const uint4*>(&ubuf[row * 264 + c16 * 8]);
  }
  // swizzled MFMA-fragment-order store: grp = (cc*4 + wv)*8 + ks, 1 KB/wave coalesced
  {
    unsigned short* Zd = Zsw + (size_t)p * 98304 + (size_t)(cc * 4 + wv) * 4096 + lane * 8;
#pragma unroll
    for (int ks = 0; ks < 8; ++ks) {
      *reinterpret_cast<uint4*>(Zd + ks * 512) =
          *reinterpret_cast<const uint4*>(&ubuf[(wv * 16 + l15) * 264 + ks * 32 + l4 * 8]);
    }
  }

  // gate: f_tri[d] += Hpl[p][d] * sum_e sigm(Zg^T + b) * Her[e][d]
  zero_acc4(acc);
  gemm4(acc, wpack + 3 * 65536, ubuf, lane, wv);
#pragma unroll
  for (int mt = 0; mt < 4; ++mt) {
    const int d = d0 + mt * 16 + l4 * 4;
    const f32x4 bb = *reinterpret_cast<const f32x4*>(&wg_b[d]);
    const f32x4 hl = *reinterpret_cast<const f32x4*>(&Hpl[p * DD + d]);
    f32x4 fs = (f32x4){0.f, 0.f, 0.f, 0.f};
#pragma unroll
    for (int nt = 0; nt < 4; ++nt) {
      const int e = e0 + nt * 16 + l15;
      const f32x4 hr = *reinterpret_cast<const f32x4*>(&Her[e * DD + d]);
#pragma unroll
      for (int r = 0; r < 4; ++r)
        fs[r] += sigm(acc[mt][nt][r] + bb[r]) * hr[r];
    }
#pragma unroll
    for (int r = 0; r < 4; ++r) {
      float v = fs[r] * hl[r];
      v += __shfl_xor(v, 1);
      v += __shfl_xor(v, 2);
      v += __shfl_xor(v, 4);
      v += __shfl_xor(v, 8);
      if (l15 == 0) atomicAdd(&ftri[p * DD + d + r], v);
    }
  }
}

// ---------------- fused attention kernel: block = (p, 64-row chunk) ----------------
// scores = (Z_c Wqk Z^T + 1 v^T) / 16 ; col-sums of softmax -> cbufg[p]
// r7: all Z b-fragments from swizzled Zsw — one contiguous 1 KB load per wave.

__global__ __launch_bounds__(256, 2) void attn_kernel(
    const unsigned short* __restrict__ Zsw, const float* __restrict__ vbuf,
    const unsigned short* __restrict__ wpack, float* __restrict__ cbufg) {
  __shared__ __align__(16) unsigned short Tc[64 * 264];
  __shared__ float vb[NEPI];
  __shared__ float red[256];
  __shared__ float red2[256];
  const int t = threadIdx.x, lane = t & 63, wv = t >> 6;
  const int l15 = lane & 15, l4 = lane >> 4;
  // XCD swizzle: all 6 chunks of one p land on the same XCD (xcd = blk % 8)
  const int xcd = blockIdx.x & 7, inner = blockIdx.x >> 3;
  const int p = (inner / 6) * 8 + xcd, c = inner % 6;
  const unsigned short* Zsp = Zsw + (size_t)p * 98304;
  const unsigned short* wqk = wpack + 4 * 65536;

  for (int i = t; i < NEPI; i += 256) vb[i] = vbuf[p * NEPI + i];

  // T = Zc @ Wqk (transposed acc), b-frags double-buffered from Zsw
  {
    f32x4 ta[4][4];
#pragma unroll
    for (int mt = 0; mt < 4; ++mt)
#pragma unroll
      for (int nt = 0; nt < 4; ++nt) ta[mt][nt] = (f32x4){0.f, 0.f, 0.f, 0.f};
    const unsigned short* Tb = Zsp + (size_t)(c * 4) * 4096 + lane * 8;
    bf16x8 bcur[4], bnxt[4];
#pragma unroll
    for (int nt = 0; nt < 4; ++nt)
      bcur[nt] = *reinterpret_cast<const bf16x8*>(Tb + nt * 4096);
#pragma unroll
    for (int ks = 0; ks < 8; ++ks) {
      if (ks < 7) {
#pragma unroll
        for (int nt = 0; nt < 4; ++nt)
          bnxt[nt] = *reinterpret_cast<const bf16x8*>(Tb + nt * 4096 + (ks + 1) * 512);
      }
      bf16x8 a[4];
#pragma unroll
      for (int mt = 0; mt < 4; ++mt)
        a[mt] = *reinterpret_cast<const bf16x8*>(wqk + ((ks * 16 + wv * 4 + mt) * 64 + lane) * 8);
#pragma unroll
      for (int nt = 0; nt < 4; ++nt)
#pragma unroll
        for (int mt = 0; mt < 4; ++mt)
          ta[mt][nt] = __builtin_amdgcn_mfma_f32_16x16x32_bf16(a[mt], bcur[nt], ta[mt][nt], 0, 0, 0);
      if (ks < 7) {
#pragma unroll
        for (int nt = 0; nt < 4; ++nt) bcur[nt] = bnxt[nt];
      }
    }
#pragma unroll
    for (int mt = 0; mt < 4; ++mt) {
      const int d = wv * 64 + mt * 16 + l4 * 4;
#pragma unroll
      for (int nt = 0; nt < 4; ++nt) {
        const int e = nt * 16 + l15;
        *reinterpret_cast<uint2*>(&Tc[e * 264 + d]) =
            pack4(ta[mt][nt][0], ta[mt][nt][1], ta[mt][nt][2], ta[mt][nt][3]);
      }
    }
  }
  __syncthreads();

  // S = Tc @ Z^T; a-frags from LDS, b-frags double-buffered from Zsw
  f32x4 sc[4][6];
#pragma unroll
  for (int mt = 0; mt < 4; ++mt)
#pragma unroll
    for (int s = 0; s < 6; ++s) sc[mt][s] = (f32x4){0.f, 0.f, 0.f, 0.f};

  {
    const unsigned short* Sb = Zsp + (size_t)wv * 4096 + lane * 8;
    bf16x8 bcur[6], bnxt[6];
#pragma unroll
    for (int s = 0; s < 6; ++s)
      bcur[s] = *reinterpret_cast<const bf16x8*>(Sb + s * 16384);
#pragma unroll
    for (int ks = 0; ks < 8; ++ks) {
      if (ks < 7) {
#pragma unroll
        for (int s = 0; s < 6; ++s)
          bnxt[s] = *reinterpret_cast<const bf16x8*>(Sb + s * 16384 + (ks + 1) * 512);
      }
      bf16x8 a[4];
#pragma unroll
      for (int mt = 0; mt < 4; ++mt)
        a[mt] = *reinterpret_cast<const bf16x8*>(&Tc[(mt * 16 + l15) * 264 + ks * 32 + l4 * 8]);
#pragma unroll
      for (int s = 0; s < 6; ++s)
#pragma unroll
        for (int mt = 0; mt < 4; ++mt)
          sc[mt][s] = __builtin_amdgcn_mfma_f32_16x16x32_bf16(a[mt], bcur[s], sc[mt][s], 0, 0, 0);
      if (ks < 7) {
#pragma unroll
        for (int s = 0; s < 6; ++s) bcur[s] = bnxt[s];
      }
    }
  }

  // softmax over f (384 cols), rows e = mt*16 + l4*4 + r
  const float scl = 0.0625f;
  float fv[6];
#pragma unroll
  for (int s = 0; s < 6; ++s)
    fv[s] = vb[s * 64 + wv * 16 + l15];

  float rmax[4][4];
#pragma unroll
  for (int mt = 0; mt < 4; ++mt) {
#pragma unroll
    for (int r = 0; r < 4; ++r) {
      float m = -1e30f;
#pragma unroll
      for (int s = 0; s < 6; ++s) {
        sc[mt][s][r] = (sc[mt][s][r] + fv[s]) * scl;
        m = fmaxf(m, sc[mt][s][r]);
      }
      m = fmaxf(m, __shfl_xor(m, 1));
      m = fmaxf(m, __shfl_xor(m, 2));
      m = fmaxf(m, __shfl_xor(m, 4));
      m = fmaxf(m, __shfl_xor(m, 8));
      rmax[mt][r] = m;
    }
  }
  if (l15 == 0) {
#pragma unroll
    for (int mt = 0; mt < 4; ++mt)
#pragma unroll
      for (int r = 0; r < 4; ++r)
        red[wv * 64 + mt * 16 + l4 * 4 + r] = rmax[mt][r];
  }
  __syncthreads();
#pragma unroll
  for (int mt = 0; mt < 4; ++mt) {
#pragma unroll
    for (int r = 0; r < 4; ++r) {
      const int row = mt * 16 + l4 * 4 + r;
      rmax[mt][r] = fmaxf(fmaxf(red[row], red[64 + row]), fmaxf(red[128 + row], red[192 + row]));
    }
  }

  float rsum[4][4];
#pragma unroll
  for (int mt = 0; mt < 4; ++mt) {
#pragma unroll
    for (int r = 0; r < 4; ++r) {
      float sSum = 0.f;
#pragma unroll
      for (int s = 0; s < 6; ++s) {
        float e = __expf(sc[mt][s][r] - rmax[mt][r]);
        sc[mt][s][r] = e;
        sSum += e;
      }
      sSum += __shfl_xor(sSum, 1);
      sSum += __shfl_xor(sSum, 2);
      sSum += __shfl_xor(sSum, 4);
      sSum += __shfl_xor(sSum, 8);
      rsum[mt][r] = sSum;
    }
  }
  if (l15 == 0) {
#pragma unroll
    for (int mt = 0; mt < 4; ++mt)
#pragma unroll
      for (int r = 0; r < 4; ++r)
        red2[wv * 64 + mt * 16 + l4 * 4 + r] = rsum[mt][r];
  }
  __syncthreads();
  float rinv[4][4];
#pragma unroll
  for (int mt = 0; mt < 4; ++mt) {
#pragma unroll
    for (int r = 0; r < 4; ++r) {
      const int row = mt * 16 + l4 * 4 + r;
      rinv[mt][r] = 1.0f / (red2[row] + red2[64 + row] + red2[128 + row] + red2[192 + row]);
    }
  }

  // column sums of A over this chunk's 64 rows -> cbufg
#pragma unroll
  for (int s = 0; s < 6; ++s) {
    float v = 0.f;
#pragma unroll
    for (int mt = 0; mt < 4; ++mt)
#pragma unroll
      for (int r = 0; r < 4; ++r)
        v += sc[mt][s][r] * rinv[mt][r];
    v += __shfl_xor(v, 16);
    v += __shfl_xor(v, 32);
    if (lane < 16)
      atomicAdd(&cbufg[p * NEPI + s * 64 + wv * 16 + lane], v);
  }
}

// ---------------- output kernel ----------------
// out[p] = (ftri[p] + (c^T Z_p) @ wv + 384*bv) / 384

__global__ __launch_bounds__(256) void out_kernel(
    const unsigned short* __restrict__ Zg, const float* __restrict__ ftri,
    const float* __restrict__ cbufg, const float* __restrict__ wvw,
    const float* __restrict__ wvb, float* __restrict__ out) {
  __shared__ float cb[NEPI];
  __shared__ float part[8][257];
  __shared__ float u[DD];
  const int p = blockIdx.x, t = threadIdx.x;
  const int fg = t >> 5, dg = t & 31;
  for (int i = t; i < NEPI; i += 256) cb[i] = cbufg[p * NEPI + i];
  __syncthreads();
  const unsigned short* Zp = Zg + (size_t)p * NEPI * DD;
  float a8[8] = {0.f, 0.f, 0.f, 0.f, 0.f, 0.f, 0.f, 0.f};
#pragma unroll 4
  for (int i = 0; i < 48; ++i) {
    const int f = fg + i * 8;
    const uint4 zz = *reinterpret_cast<const uint4*>(&Zp[f * DD + dg * 8]);
    const float w = cb[f];
    a8[0] = fmaf(w, bf2f(zz.x & 0xffffu), a8[0]);
    a8[1] = fmaf(w, bf2f(zz.x >> 16), a8[1]);
    a8[2] = fmaf(w, bf2f(zz.y & 0xffffu), a8[2]);
    a8[3] = fmaf(w, bf2f(zz.y >> 16), a8[3]);
    a8[4] = fmaf(w, bf2f(zz.z & 0xffffu), a8[4]);
    a8[5] = fmaf(w, bf2f(zz.z >> 16), a8[5]);
    a8[6] = fmaf(w, bf2f(zz.w & 0xffffu), a8[6]);
    a8[7] = fmaf(w, bf2f(zz.w >> 16), a8[7]);
  }
#pragma unroll
  for (int j = 0; j < 8; ++j) part[fg][dg * 8 + j] = a8[j];
  __syncthreads();
  float uu = 0.f;
#pragma unroll
  for (int g = 0; g < 8; ++g) uu += part[g][t];
  u[t] = uu;
  __syncthreads();
  float acc = ftri[p * DD + t] + 384.0f * wvb[t];
#pragma unroll 8
  for (int d = 0; d < DD; ++d)
    acc = fmaf(u[d], wvw[d * DD + t], acc);
  out[p * DD + t] = acc * (1.0f / 384.0f);
}

// ---------------- launch ----------------

extern "C" void kernel_launch(void* const* d_in, const int* in_sizes, int n_in,
                              void* d_out, int out_size, void* d_ws, size_t ws_size,
                              hipStream_t stream) {
  (void)in_sizes; (void)n_in; (void)out_size; (void)ws_size;
  const float* H = (const float*)d_in[0];
  const float* X = (const float*)d_in[1];
  const float* res_w1 = (const float*)d_in[4];
  const float* res_b1 = (const float*)d_in[5];
  const float* res_w2 = (const float*)d_in[6];
  const float* res_b2 = (const float*)d_in[7];
  const float* atom_w1 = (const float*)d_in[8];
  const float* atom_b1 = (const float*)d_in[9];
  const float* atom_w2 = (const float*)d_in[10];
  const float* atom_b2 = (const float*)d_in[11];
  const float* simw = (const float*)d_in[12];
  const float* int_w1 = (const float*)d_in[13];
  const float* int_b1 = (const float*)d_in[14];
  const float* int_w2 = (const float*)d_in[15];
  const float* int_b2 = (const float*)d_in[16];
  const float* wl = (const float*)d_in[17];
  const float* wr = (const float*)d_in[18];
  const float* wg_w = (const float*)d_in[19];
  const float* wg_b = (const float*)d_in[20];
  const float* wq_w = (const float*)d_in[21];
  const float* wq_b = (const float*)d_in[22];
  const float* wk_w = (const float*)d_in[23];
  const float* wv_w = (const float*)d_in[25];
  const float* wv_b = (const float*)d_in[26];

  char* ws = (char*)d_ws;
  unsigned short* wpack = (unsigned short*)(ws + 0);      //  655360 B (5 slots)
  float* MrF   = (float*)(ws + 655360);
  float* MaF   = (float*)(ws + 917504);
  float* WqkF  = (float*)(ws + 1179648);
  float* wkT   = (float*)(ws + 1441792);
  float* cvec  = (float*)(ws + 1703936);
  float* gv    = (float*)(ws + 1704960);
  float* P1    = (float*)(ws + 1705984);
  float* P2    = (float*)(ws + 2099200);
  float* Hpl   = (float*)(ws + 2492416);
  float* Her   = (float*)(ws + 2885632);
  float* ftri  = (float*)(ws + 3278848);                  //  393216 B
  float* vbuf  = (float*)(ws + 3672064);                  //  589824 B
  float* cbufg = (float*)(ws + 4261888);                  //  589824 B
  unsigned short* Zg  = (unsigned short*)(ws + 4851712);  // 75497472 B (row-major)
  unsigned short* Zsw = (unsigned short*)(ws + 80349184); // 75497472 B (MFMA frag order)

  // one span: ftri + vbuf + cbufg (vbuf zeroing is harmless)
  hipMemsetAsync(ftri, 0, 393216 + 589824 + 589824, stream);
  hipMemsetAsync(cvec, 0, DD * sizeof(float), stream);
  prep_kernel<<<2184, 256, 0, stream>>>(H, wl, wr, int_w1, res_w2, atom_w2,
                                        res_b2, atom_b2, int_b1, simw, wq_b, wk_w,
                                        Hpl, Her, P1, P2, MrF, MaF, cvec, gv, wkT);
  mm_rows<<<256, 256, 0, stream>>>(wq_w, wkT, WqkF);        // Wqk = wq @ wk^T
  pack_kernel<<<1280, 256, 0, stream>>>(MrF, MaF, int_w2, wg_w, WqkF, wpack);
  pair_kernel<<<2304, 256, 0, stream>>>(X, res_w1, res_b1, atom_w1, atom_b1,
                                        int_b2, wg_b, wpack, cvec, gv,
                                        P1, P2, Hpl, Her, ftri, vbuf, Zg, Zsw);
  attn_kernel<<<2304, 256, 0, stream>>>(Zsw, vbuf, wpack, cbufg);
  out_kernel<<<384, 256, 0, stream>>>(Zg, ftri, cbufg, wv_w, wv_b, (float*)d_out);
  hipMemcpyAsync((float*)d_out + NPAR * DD, H + NPAR * DD,
                 (1024 - NPAR) * DD * sizeof(float), hipMemcpyDeviceToDevice, stream);
}

// Round 8
// 391.395 us; speedup vs baseline: 2.5833x; 1.0193x over previous
//
#include <hip/hip_runtime.h>

#define NPAR 384
#define NEPI 384
#define DD   256

using bf16x8 = __bf16 __attribute__((ext_vector_type(8)));
using bf16x2 = __bf16 __attribute__((ext_vector_type(2)));
using f32x4  = float __attribute__((ext_vector_type(4)));

#if defined(__has_builtin)
#if __has_builtin(__builtin_amdgcn_cvt_pk_bf16_f32)
#define HAVE_PK_BF16 1
#endif
#endif

__device__ __forceinline__ float sigm(float x) { return 1.0f / (1.0f + __expf(-x)); }
__device__ __forceinline__ float silu(float x) { return x / (1.0f + __expf(-x)); }
__device__ __forceinline__ unsigned short f2bf(float f) {
  unsigned u = __float_as_uint(f);
  u += 0x7fffu + ((u >> 16) & 1u);
  return (unsigned short)(u >> 16);
}
__device__ __forceinline__ float bf2f(unsigned u16) {
  return __uint_as_float(u16 << 16);
}
__device__ __forceinline__ uint2 pack4(float a, float b, float c, float d) {
  uint2 r;
#ifdef HAVE_PK_BF16
  bf16x2 lo = __builtin_amdgcn_cvt_pk_bf16_f32(a, b);
  bf16x2 hi = __builtin_amdgcn_cvt_pk_bf16_f32(c, d);
  r.x = __builtin_bit_cast(unsigned, lo);
  r.y = __builtin_bit_cast(unsigned, hi);
#else
  r.x = (unsigned)f2bf(a) | ((unsigned)f2bf(b) << 16);
  r.y = (unsigned)f2bf(c) | ((unsigned)f2bf(d) << 16);
#endif
  return r;
}

// ---------------- fused precompute kernel ----------------
// block ranges: [0,64) transpose wk->wkT ; [64,576) fold Mr/Ma ; [576,584) cvec ;
// [584,648) gvec ; [648,2184) mm_rows4 (Hpl/Her/P1/P2)

__global__ void prep_kernel(
    const float* __restrict__ H, const float* __restrict__ wl,
    const float* __restrict__ wr, const float* __restrict__ int_w1,
    const float* __restrict__ res_w2, const float* __restrict__ atom_w2,
    const float* __restrict__ res_b2, const float* __restrict__ atom_b2,
    const float* __restrict__ int_b1, const float* __restrict__ simw,
    const float* __restrict__ wq_b, const float* __restrict__ wk_w,
    float* __restrict__ Hpl, float* __restrict__ Her,
    float* __restrict__ P1, float* __restrict__ P2,
    float* __restrict__ MrF, float* __restrict__ MaF,
    float* __restrict__ cvec, float* __restrict__ gv,
    float* __restrict__ wkT) {
  __shared__ float tile[32][33];
  const int b = blockIdx.x, t = threadIdx.x;
  if (b < 64) {
    const int bx = b & 7, by = b >> 3;
    const int tx = t & 31, ty = t >> 5;
    for (int r = 0; r < 32; r += 8)
      tile[ty + r][tx] = wk_w[(by * 32 + ty + r) * 256 + bx * 32 + tx];
    __syncthreads();
    for (int r = 0; r < 32; r += 8)
      wkT[(bx * 32 + ty + r) * 256 + by * 32 + tx] = tile[tx][ty + r];
  } else if (b < 576) {
    const int bb = b - 64;
    const int i = bb & 255;
    const bool isMa = bb >= 256;
    const float wmix = 1.0f / (1.0f + __expf(-simw[0]));
    const float sc = isMa ? (1.0f - wmix) : wmix;
    const float* W2 = isMa ? atom_w2 : res_w2;
    float acc = 0.f;
#pragma unroll 8
    for (int k = 0; k < 256; ++k)
      acc += W2[i * 256 + k] * int_w1[(512 + k) * 256 + t];
    (isMa ? MaF : MrF)[i * 256 + t] = acc * sc;
  } else if (b < 584) {
    const int bb = b - 576;
    const float wmix = 1.0f / (1.0f + __expf(-simw[0]));
    float acc = (bb == 0) ? int_b1[t] : 0.f;
#pragma unroll
    for (int k = bb * 32; k < bb * 32 + 32; ++k) {
      float bm = wmix * res_b2[k] + (1.0f - wmix) * atom_b2[k];
      acc += bm * int_w1[(512 + k) * 256 + t];
    }
    atomicAdd(&cvec[t], acc);
  } else if (b < 648) {
    const int lane = t & 63, w = t >> 6;
    const int d = (b - 584) * 4 + w;
    float acc = 0.f;
#pragma unroll
    for (int i = 0; i < 4; ++i) {
      const int c = i * 64 + lane;
      acc += wk_w[d * 256 + c] * wq_b[c];
    }
    acc += __shfl_xor(acc, 1);
    acc += __shfl_xor(acc, 2);
    acc += __shfl_xor(acc, 4);
    acc += __shfl_xor(acc, 8);
    acc += __shfl_xor(acc, 16);
    acc += __shfl_xor(acc, 32);
    if (lane == 0) gv[d] = acc;
  } else {
    const int idx = b - 648;
    const int seg = idx / 384, r = idx % 384;
    const float* A;
    const float* B;
    float* C;
    switch (seg) {
      case 0:  A = H + r * 256;            B = wl;              C = Hpl + r * 256; break;
      case 1:  A = H + (NPAR + r) * 256;   B = wr;              C = Her + r * 256; break;
      case 2:  A = H + r * 256;            B = int_w1;          C = P1 + r * 256;  break;
      default: A = H + (NPAR + r) * 256;   B = int_w1 + 65536;  C = P2 + r * 256;  break;
    }
    float acc = 0.f;
#pragma unroll 8
    for (int k = 0; k < 256; ++k)
      acc += A[k] * B[k * 256 + t];
    C[t] = acc;
  }
}

// C[r][j] = sum_k A[r][k] * B[k][j]  (grid = #rows) — for Wqk = wq @ wkT
__global__ void mm_rows(const float* __restrict__ A, const float* __restrict__ B,
                        float* __restrict__ C) {
  const int r = blockIdx.x, j = threadIdx.x;
  float acc = 0.f;
#pragma unroll 8
  for (int k = 0; k < 256; ++k)
    acc += A[r * 256 + k] * B[k * 256 + j];
  C[r * 256 + j] = acc;
}

// pack 5 [256,256] matrices into MFMA fragment order:
// wpack[m][((ks*16+tile)*64 + lane)*8 + j] = W[k = ks*32 + (lane>>4)*8 + j][n = tile*16 + (lane&15)]
// slots: 0=Mr 1=Ma 2=int_w2 3=wg 4=Wqk
__global__ void pack_kernel(const float* __restrict__ MrF, const float* __restrict__ MaF,
                            const float* __restrict__ w2, const float* __restrict__ wg,
                            const float* __restrict__ WqkF, unsigned short* __restrict__ wpack) {
  const int idx = blockIdx.x * 256 + threadIdx.x;
  const int m = idx >> 16;
  const int r = idx & 65535;
  const int chunk = r >> 9;
  const int lane = (r >> 3) & 63;
  const int j = r & 7;
  const int k = (chunk >> 4) * 32 + (lane >> 4) * 8 + j;
  const int n = (chunk & 15) * 16 + (lane & 15);
  const float* src;
  switch (m) {
    case 0: src = MrF; break;
    case 1: src = MaF; break;
    case 2: src = w2; break;
    case 3: src = wg; break;
    default: src = WqkF; break;
  }
  wpack[idx] = f2bf(src[k * 256 + n]);
}

// ---------------- pairwise GEMM-chain kernel (64-row tiles) ----------------

__device__ __forceinline__ void zero_acc4(f32x4 (&acc)[4][4]) {
#pragma unroll
  for (int mt = 0; mt < 4; ++mt)
#pragma unroll
    for (int nt = 0; nt < 4; ++nt)
      acc[mt][nt] = (f32x4){0.f, 0.f, 0.f, 0.f};
}

// transposed-acc: mfma(Wfrag, ActFrag) -> acc^T[d][e]
// d = wv*64 + mt*16 + l4*4 + r, e = nt*16 + l15
__device__ __forceinline__ void gemm4(f32x4 (&acc)[4][4],
                                      const unsigned short* __restrict__ wp,
                                      const unsigned short* ub, int lane, int wv) {
  const int l15 = lane & 15, l4 = lane >> 4;
#pragma unroll
  for (int ks = 0; ks < 8; ++ks) {
    bf16x8 a[4];
#pragma unroll
    for (int mt = 0; mt < 4; ++mt)
      a[mt] = *reinterpret_cast<const bf16x8*>(wp + ((ks * 16 + wv * 4 + mt) * 64 + lane) * 8);
#pragma unroll
    for (int nt = 0; nt < 4; ++nt) {
      bf16x8 b = *reinterpret_cast<const bf16x8*>(ub + (nt * 16 + l15) * 264 + ks * 32 + l4 * 8);
#pragma unroll
      for (int mt = 0; mt < 4; ++mt)
        acc[mt][nt] = __builtin_amdgcn_mfma_f32_16x16x32_bf16(a[mt], b, acc[mt][nt], 0, 0, 0);
    }
  }
}

// fill ubuf[e][d] = silu(Sv[e]*w1[d] + b1[d]) ; thread owns 8 contiguous d, b128 writes
__device__ __forceinline__ void fill_u(unsigned short* ub, const float* Sv,
                                       const float* __restrict__ w1,
                                       const float* __restrict__ b1, int t) {
  const int dg = t & 31, rb = t >> 5;
  const f32x4 w1a = *reinterpret_cast<const f32x4*>(&w1[dg * 8]);
  const f32x4 w1b = *reinterpret_cast<const f32x4*>(&w1[dg * 8 + 4]);
  const f32x4 b1a = *reinterpret_cast<const f32x4*>(&b1[dg * 8]);
  const f32x4 b1b = *reinterpret_cast<const f32x4*>(&b1[dg * 8 + 4]);
#pragma unroll
  for (int i = 0; i < 8; ++i) {
    const int e = rb + i * 8;
    const float s = Sv[e];
    uint2 lo = pack4(silu(fmaf(s, w1a[0], b1a[0])), silu(fmaf(s, w1a[1], b1a[1])),
                     silu(fmaf(s, w1a[2], b1a[2])), silu(fmaf(s, w1a[3], b1a[3])));
    uint2 hi = pack4(silu(fmaf(s, w1b[0], b1b[0])), silu(fmaf(s, w1b[1], b1b[1])),
                     silu(fmaf(s, w1b[2], b1b[2])), silu(fmaf(s, w1b[3], b1b[3])));
    uint4 pk = {lo.x, lo.y, hi.x, hi.y};
    *reinterpret_cast<uint4*>(&ub[e * 264 + dg * 8]) = pk;
  }
}

__global__ __launch_bounds__(256, 3) void pair_kernel(
    const float* __restrict__ Xg,
    const float* __restrict__ res_w1, const float* __restrict__ res_b1,
    const float* __restrict__ atom_w1, const float* __restrict__ atom_b1,
    const float* __restrict__ int_b2, const float* __restrict__ wg_b,
    const unsigned short* __restrict__ wpack, const float* __restrict__ cvec,
    const float* __restrict__ gv,
    const float* __restrict__ P1, const float* __restrict__ P2,
    const float* __restrict__ Hpl, const float* __restrict__ Her,
    float* __restrict__ ftri, float* __restrict__ vbuf,
    unsigned short* __restrict__ Zsw) {
  __shared__ __align__(16) unsigned short ubuf[64 * 264];
  __shared__ float Sv[64];
  __shared__ float pc[DD];
  __shared__ float vred[256];
  const int t = threadIdx.x, lane = t & 63, wv = t >> 6;
  const int l15 = lane & 15, l4 = lane >> 4;
  const int p = blockIdx.x / 6, cc = blockIdx.x % 6, e0 = cc * 64;
  const int d0 = wv * 64;

  if (t < 64) {
    const int e = e0 + t;
    float dx = Xg[p * 42 + 3] - Xg[(NPAR + e) * 42 + 3];
    float dy = Xg[p * 42 + 4] - Xg[(NPAR + e) * 42 + 4];
    float dz = Xg[p * 42 + 5] - Xg[(NPAR + e) * 42 + 5];
    Sv[t] = dx * dx + dy * dy + dz * dz;
  }
  pc[t] = P1[p * DD + t] + cvec[t];
  __syncthreads();

  f32x4 acc[4][4];
  zero_acc4(acc);

  fill_u(ubuf, Sv, res_w1, res_b1, t);
  __syncthreads();
  gemm4(acc, wpack + 0 * 65536, ubuf, lane, wv);
  __syncthreads();
  fill_u(ubuf, Sv, atom_w1, atom_b1, t);
  __syncthreads();
  gemm4(acc, wpack + 1 * 65536, ubuf, lane, wv);
  __syncthreads();

  // epilogue: h = silu(zpre^T + pc[d] + P2[e][d]) -> ubuf[e][d]
#pragma unroll
  for (int mt = 0; mt < 4; ++mt) {
    const int d = d0 + mt * 16 + l4 * 4;
    const f32x4 pcv = *reinterpret_cast<const f32x4*>(&pc[d]);
#pragma unroll
    for (int nt = 0; nt < 4; ++nt) {
      const int e = nt * 16 + l15;
      const f32x4 p2v = *reinterpret_cast<const f32x4*>(&P2[(e0 + e) * DD + d]);
      uint2 pk = pack4(silu(acc[mt][nt][0] + pcv[0] + p2v[0]),
                       silu(acc[mt][nt][1] + pcv[1] + p2v[1]),
                       silu(acc[mt][nt][2] + pcv[2] + p2v[2]),
                       silu(acc[mt][nt][3] + pcv[3] + p2v[3]));
      *reinterpret_cast<uint2*>(&ubuf[e * 264 + d]) = pk;
    }
  }
  __syncthreads();

  // Z = h @ int_w2 + int_b2 -> ubuf; v[e] = Z[e,:] . gv
  zero_acc4(acc);
  gemm4(acc, wpack + 2 * 65536, ubuf, lane, wv);
  __syncthreads();
  {
    float vp[4] = {0.f, 0.f, 0.f, 0.f};
#pragma unroll
    for (int mt = 0; mt < 4; ++mt) {
      const int d = d0 + mt * 16 + l4 * 4;
      const f32x4 bb = *reinterpret_cast<const f32x4*>(&int_b2[d]);
      const f32x4 gq = *reinterpret_cast<const f32x4*>(&gv[d]);
#pragma unroll
      for (int nt = 0; nt < 4; ++nt) {
        const int e = nt * 16 + l15;
        float z0 = acc[mt][nt][0] + bb[0];
        float z1 = acc[mt][nt][1] + bb[1];
        float z2 = acc[mt][nt][2] + bb[2];
        float z3 = acc[mt][nt][3] + bb[3];
        *reinterpret_cast<uint2*>(&ubuf[e * 264 + d]) = pack4(z0, z1, z2, z3);
        vp[nt] += z0 * gq[0] + z1 * gq[1] + z2 * gq[2] + z3 * gq[3];
      }
    }
#pragma unroll
    for (int nt = 0; nt < 4; ++nt) {
      float v = vp[nt];
      v += __shfl_xor(v, 16);
      v += __shfl_xor(v, 32);
      if (lane < 16) vred[wv * 64 + nt * 16 + lane] = v;
    }
  }
  __syncthreads();
  if (t < 64)
    vbuf[p * NEPI + e0 + t] = vred[t] + vred[64 + t] + vred[128 + t] + vred[192 + t];

  // swizzled MFMA-fragment-order store: grp = cc*4 + wv, e = grp*16 + l15
  {
    unsigned short* Zd = Zsw + (size_t)p * 98304 + (size_t)(cc * 4 + wv) * 4096 + lane * 8;
#pragma unroll
    for (int ks = 0; ks < 8; ++ks) {
      *reinterpret_cast<uint4*>(Zd + ks * 512) =
          *reinterpret_cast<const uint4*>(&ubuf[(wv * 16 + l15) * 264 + ks * 32 + l4 * 8]);
    }
  }

  // gate: f_tri[d] += Hpl[p][d] * sum_e sigm(Z@wg + b) * Her[e][d]
  zero_acc4(acc);
  gemm4(acc, wpack + 3 * 65536, ubuf, lane, wv);
#pragma unroll
  for (int mt = 0; mt < 4; ++mt) {
    const int d = d0 + mt * 16 + l4 * 4;
    const f32x4 bb = *reinterpret_cast<const f32x4*>(&wg_b[d]);
    const f32x4 hl = *reinterpret_cast<const f32x4*>(&Hpl[p * DD + d]);
    f32x4 fs = (f32x4){0.f, 0.f, 0.f, 0.f};
#pragma unroll
    for (int nt = 0; nt < 4; ++nt) {
      const int e = e0 + nt * 16 + l15;
      const f32x4 hr = *reinterpret_cast<const f32x4*>(&Her[e * DD + d]);
#pragma unroll
      for (int r = 0; r < 4; ++r)
        fs[r] += sigm(acc[mt][nt][r] + bb[r]) * hr[r];
    }
#pragma unroll
    for (int r = 0; r < 4; ++r) {
      float v = fs[r] * hl[r];
      v += __shfl_xor(v, 1);
      v += __shfl_xor(v, 2);
      v += __shfl_xor(v, 4);
      v += __shfl_xor(v, 8);
      if (l15 == 0) atomicAdd(&ftri[p * DD + d + r], v);
    }
  }
}

// ---------------- fused attention kernel: block = (p, 64-row chunk) ----------------
// scores = (Z_c Wqk Z^T + 1 v^T) / 16 ; col-sums of softmax -> cbufg[p]
// b-fragments from swizzled Zsw — one contiguous 1 KB load per wave.

__global__ __launch_bounds__(256, 2) void attn_kernel(
    const unsigned short* __restrict__ Zsw, const float* __restrict__ vbuf,
    const unsigned short* __restrict__ wpack, float* __restrict__ cbufg) {
  __shared__ __align__(16) unsigned short Tc[64 * 264];
  __shared__ float vb[NEPI];
  __shared__ float red[256];
  __shared__ float red2[256];
  const int t = threadIdx.x, lane = t & 63, wv = t >> 6;
  const int l15 = lane & 15, l4 = lane >> 4;
  // XCD swizzle: all 6 chunks of one p land on the same XCD (xcd = blk % 8)
  const int xcd = blockIdx.x & 7, inner = blockIdx.x >> 3;
  const int p = (inner / 6) * 8 + xcd, c = inner % 6;
  const unsigned short* Zsp = Zsw + (size_t)p * 98304;
  const unsigned short* wqk = wpack + 4 * 65536;

  for (int i = t; i < NEPI; i += 256) vb[i] = vbuf[p * NEPI + i];

  // T = Zc @ Wqk (transposed acc), b-frags double-buffered from Zsw
  {
    f32x4 ta[4][4];
#pragma unroll
    for (int mt = 0; mt < 4; ++mt)
#pragma unroll
      for (int nt = 0; nt < 4; ++nt) ta[mt][nt] = (f32x4){0.f, 0.f, 0.f, 0.f};
    const unsigned short* Tb = Zsp + (size_t)(c * 4) * 4096 + lane * 8;
    bf16x8 bcur[4], bnxt[4];
#pragma unroll
    for (int nt = 0; nt < 4; ++nt)
      bcur[nt] = *reinterpret_cast<const bf16x8*>(Tb + nt * 4096);
#pragma unroll
    for (int ks = 0; ks < 8; ++ks) {
      if (ks < 7) {
#pragma unroll
        for (int nt = 0; nt < 4; ++nt)
          bnxt[nt] = *reinterpret_cast<const bf16x8*>(Tb + nt * 4096 + (ks + 1) * 512);
      }
      bf16x8 a[4];
#pragma unroll
      for (int mt = 0; mt < 4; ++mt)
        a[mt] = *reinterpret_cast<const bf16x8*>(wqk + ((ks * 16 + wv * 4 + mt) * 64 + lane) * 8);
#pragma unroll
      for (int nt = 0; nt < 4; ++nt)
#pragma unroll
        for (int mt = 0; mt < 4; ++mt)
          ta[mt][nt] = __builtin_amdgcn_mfma_f32_16x16x32_bf16(a[mt], bcur[nt], ta[mt][nt], 0, 0, 0);
      if (ks < 7) {
#pragma unroll
        for (int nt = 0; nt < 4; ++nt) bcur[nt] = bnxt[nt];
      }
    }
#pragma unroll
    for (int mt = 0; mt < 4; ++mt) {
      const int d = wv * 64 + mt * 16 + l4 * 4;
#pragma unroll
      for (int nt = 0; nt < 4; ++nt) {
        const int e = nt * 16 + l15;
        *reinterpret_cast<uint2*>(&Tc[e * 264 + d]) =
            pack4(ta[mt][nt][0], ta[mt][nt][1], ta[mt][nt][2], ta[mt][nt][3]);
      }
    }
  }
  __syncthreads();

  // S = Tc @ Z^T; a-frags from LDS, b-frags double-buffered from Zsw
  f32x4 sc[4][6];
#pragma unroll
  for (int mt = 0; mt < 4; ++mt)
#pragma unroll
    for (int s = 0; s < 6; ++s) sc[mt][s] = (f32x4){0.f, 0.f, 0.f, 0.f};

  {
    const unsigned short* Sb = Zsp + (size_t)wv * 4096 + lane * 8;
    bf16x8 bcur[6], bnxt[6];
#pragma unroll
    for (int s = 0; s < 6; ++s)
      bcur[s] = *reinterpret_cast<const bf16x8*>(Sb + s * 16384);
#pragma unroll
    for (int ks = 0; ks < 8; ++ks) {
      if (ks < 7) {
#pragma unroll
        for (int s = 0; s < 6; ++s)
          bnxt[s] = *reinterpret_cast<const bf16x8*>(Sb + s * 16384 + (ks + 1) * 512);
      }
      bf16x8 a[4];
#pragma unroll
      for (int mt = 0; mt < 4; ++mt)
        a[mt] = *reinterpret_cast<const bf16x8*>(&Tc[(mt * 16 + l15) * 264 + ks * 32 + l4 * 8]);
#pragma unroll
      for (int s = 0; s < 6; ++s)
#pragma unroll
        for (int mt = 0; mt < 4; ++mt)
          sc[mt][s] = __builtin_amdgcn_mfma_f32_16x16x32_bf16(a[mt], bcur[s], sc[mt][s], 0, 0, 0);
      if (ks < 7) {
#pragma unroll
        for (int s = 0; s < 6; ++s) bcur[s] = bnxt[s];
      }
    }
  }

  // softmax over f (384 cols), rows e = mt*16 + l4*4 + r
  const float scl = 0.0625f;
  float fv[6];
#pragma unroll
  for (int s = 0; s < 6; ++s)
    fv[s] = vb[s * 64 + wv * 16 + l15];

  float rmax[4][4];
#pragma unroll
  for (int mt = 0; mt < 4; ++mt) {
#pragma unroll
    for (int r = 0; r < 4; ++r) {
      float m = -1e30f;
#pragma unroll
      for (int s = 0; s < 6; ++s) {
        sc[mt][s][r] = (sc[mt][s][r] + fv[s]) * scl;
        m = fmaxf(m, sc[mt][s][r]);
      }
      m = fmaxf(m, __shfl_xor(m, 1));
      m = fmaxf(m, __shfl_xor(m, 2));
      m = fmaxf(m, __shfl_xor(m, 4));
      m = fmaxf(m, __shfl_xor(m, 8));
      rmax[mt][r] = m;
    }
  }
  if (l15 == 0) {
#pragma unroll
    for (int mt = 0; mt < 4; ++mt)
#pragma unroll
      for (int r = 0; r < 4; ++r)
        red[wv * 64 + mt * 16 + l4 * 4 + r] = rmax[mt][r];
  }
  __syncthreads();
#pragma unroll
  for (int mt = 0; mt < 4; ++mt) {
#pragma unroll
    for (int r = 0; r < 4; ++r) {
      const int row = mt * 16 + l4 * 4 + r;
      rmax[mt][r] = fmaxf(fmaxf(red[row], red[64 + row]), fmaxf(red[128 + row], red[192 + row]));
    }
  }

  float rsum[4][4];
#pragma unroll
  for (int mt = 0; mt < 4; ++mt) {
#pragma unroll
    for (int r = 0; r < 4; ++r) {
      float sSum = 0.f;
#pragma unroll
      for (int s = 0; s < 6; ++s) {
        float e = __expf(sc[mt][s][r] - rmax[mt][r]);
        sc[mt][s][r] = e;
        sSum += e;
      }
      sSum += __shfl_xor(sSum, 1);
      sSum += __shfl_xor(sSum, 2);
      sSum += __shfl_xor(sSum, 4);
      sSum += __shfl_xor(sSum, 8);
      rsum[mt][r] = sSum;
    }
  }
  if (l15 == 0) {
#pragma unroll
    for (int mt = 0; mt < 4; ++mt)
#pragma unroll
      for (int r = 0; r < 4; ++r)
        red2[wv * 64 + mt * 16 + l4 * 4 + r] = rsum[mt][r];
  }
  __syncthreads();
  float rinv[4][4];
#pragma unroll
  for (int mt = 0; mt < 4; ++mt) {
#pragma unroll
    for (int r = 0; r < 4; ++r) {
      const int row = mt * 16 + l4 * 4 + r;
      rinv[mt][r] = 1.0f / (red2[row] + red2[64 + row] + red2[128 + row] + red2[192 + row]);
    }
  }

  // column sums of A over this chunk's 64 rows -> cbufg
#pragma unroll
  for (int s = 0; s < 6; ++s) {
    float v = 0.f;
#pragma unroll
    for (int mt = 0; mt < 4; ++mt)
#pragma unroll
      for (int r = 0; r < 4; ++r)
        v += sc[mt][s][r] * rinv[mt][r];
    v += __shfl_xor(v, 16);
    v += __shfl_xor(v, 32);
    if (lane < 16)
      atomicAdd(&cbufg[p * NEPI + s * 64 + wv * 16 + lane], v);
  }
}

// ---------------- output kernel ----------------
// out[p] = (ftri[p] + (c^T Z_p) @ wv + 384*bv) / 384
// r8: Z read from swizzled Zsw — 1 KB contiguous per wave-load;
// thread (wv,l4,l15) covers ks in {wv, wv+4}, e = grp*16 + l15.

__global__ __launch_bounds__(256) void out_kernel(
    const unsigned short* __restrict__ Zsw, const float* __restrict__ ftri,
    const float* __restrict__ cbufg, const float* __restrict__ wvw,
    const float* __restrict__ wvb, float* __restrict__ out) {
  __shared__ float cb[NEPI];
  __shared__ float part[16][257];
  __shared__ float u[DD];
  const int p = blockIdx.x, t = threadIdx.x;
  const int lane = t & 63, wv = t >> 6;
  const int l15 = lane & 15, l4 = lane >> 4;
  for (int i = t; i < NEPI; i += 256) cb[i] = cbufg[p * NEPI + i];
  __syncthreads();
  const unsigned short* Zsp = Zsw + (size_t)p * 98304;
  float a16[16];
#pragma unroll
  for (int j = 0; j < 16; ++j) a16[j] = 0.f;
#pragma unroll 4
  for (int grp = 0; grp < 24; ++grp) {
    const float w = cb[grp * 16 + l15];
    const uint4 z0 = *reinterpret_cast<const uint4*>(Zsp + grp * 4096 + wv * 512 + lane * 8);
    const uint4 z1 = *reinterpret_cast<const uint4*>(Zsp + grp * 4096 + (wv + 4) * 512 + lane * 8);
    a16[0] = fmaf(w, bf2f(z0.x & 0xffffu), a16[0]);
    a16[1] = fmaf(w, bf2f(z0.x >> 16), a16[1]);
    a16[2] = fmaf(w, bf2f(z0.y & 0xffffu), a16[2]);
    a16[3] = fmaf(w, bf2f(z0.y >> 16), a16[3]);
    a16[4] = fmaf(w, bf2f(z0.z & 0xffffu), a16[4]);
    a16[5] = fmaf(w, bf2f(z0.z >> 16), a16[5]);
    a16[6] = fmaf(w, bf2f(z0.w & 0xffffu), a16[6]);
    a16[7] = fmaf(w, bf2f(z0.w >> 16), a16[7]);
    a16[8]  = fmaf(w, bf2f(z1.x & 0xffffu), a16[8]);
    a16[9]  = fmaf(w, bf2f(z1.x >> 16), a16[9]);
    a16[10] = fmaf(w, bf2f(z1.y & 0xffffu), a16[10]);
    a16[11] = fmaf(w, bf2f(z1.y >> 16), a16[11]);
    a16[12] = fmaf(w, bf2f(z1.z & 0xffffu), a16[12]);
    a16[13] = fmaf(w, bf2f(z1.z >> 16), a16[13]);
    a16[14] = fmaf(w, bf2f(z1.w & 0xffffu), a16[14]);
    a16[15] = fmaf(w, bf2f(z1.w >> 16), a16[15]);
  }
  // partial u: d = ks*32 + l4*8 + j, ks = wv (first 8) and wv+4 (second 8)
#pragma unroll
  for (int j = 0; j < 8; ++j) part[l15][wv * 32 + l4 * 8 + j] = a16[j];
#pragma unroll
  for (int j = 0; j < 8; ++j) part[l15][128 + wv * 32 + l4 * 8 + j] = a16[8 + j];
  __syncthreads();
  float uu = 0.f;
#pragma unroll
  for (int g = 0; g < 16; ++g) uu += part[g][t];
  u[t] = uu;
  __syncthreads();
  float acc = ftri[p * DD + t] + 384.0f * wvb[t];
#pragma unroll 8
  for (int d = 0; d < DD; ++d)
    acc = fmaf(u[d], wvw[d * DD + t], acc);
  out[p * DD + t] = acc * (1.0f / 384.0f);
}

// ---------------- launch ----------------

extern "C" void kernel_launch(void* const* d_in, const int* in_sizes, int n_in,
                              void* d_out, int out_size, void* d_ws, size_t ws_size,
                              hipStream_t stream) {
  (void)in_sizes; (void)n_in; (void)out_size; (void)ws_size;
  const float* H = (const float*)d_in[0];
  const float* X = (const float*)d_in[1];
  const float* res_w1 = (const float*)d_in[4];
  const float* res_b1 = (const float*)d_in[5];
  const float* res_w2 = (const float*)d_in[6];
  const float* res_b2 = (const float*)d_in[7];
  const float* atom_w1 = (const float*)d_in[8];
  const float* atom_b1 = (const float*)d_in[9];
  const float* atom_w2 = (const float*)d_in[10];
  const float* atom_b2 = (const float*)d_in[11];
  const float* simw = (const float*)d_in[12];
  const float* int_w1 = (const float*)d_in[13];
  const float* int_b1 = (const float*)d_in[14];
  const float* int_w2 = (const float*)d_in[15];
  const float* int_b2 = (const float*)d_in[16];
  const float* wl = (const float*)d_in[17];
  const float* wr = (const float*)d_in[18];
  const float* wg_w = (const float*)d_in[19];
  const float* wg_b = (const float*)d_in[20];
  const float* wq_w = (const float*)d_in[21];
  const float* wq_b = (const float*)d_in[22];
  const float* wk_w = (const float*)d_in[23];
  const float* wv_w = (const float*)d_in[25];
  const float* wv_b = (const float*)d_in[26];

  char* ws = (char*)d_ws;
  unsigned short* wpack = (unsigned short*)(ws + 0);      //  655360 B (5 slots)
  float* MrF   = (float*)(ws + 655360);
  float* MaF   = (float*)(ws + 917504);
  float* WqkF  = (float*)(ws + 1179648);
  float* wkT   = (float*)(ws + 1441792);
  float* cvec  = (float*)(ws + 1703936);
  float* gv    = (float*)(ws + 1704960);
  float* P1    = (float*)(ws + 1705984);
  float* P2    = (float*)(ws + 2099200);
  float* Hpl   = (float*)(ws + 2492416);
  float* Her   = (float*)(ws + 2885632);
  float* ftri  = (float*)(ws + 3278848);                  //  393216 B
  float* vbuf  = (float*)(ws + 3672064);                  //  589824 B
  float* cbufg = (float*)(ws + 4261888);                  //  589824 B
  unsigned short* Zsw = (unsigned short*)(ws + 4851712);  // 75497472 B (MFMA frag order)

  // one span: ftri + vbuf + cbufg (vbuf zeroing is harmless)
  hipMemsetAsync(ftri, 0, 393216 + 589824 + 589824, stream);
  hipMemsetAsync(cvec, 0, DD * sizeof(float), stream);
  prep_kernel<<<2184, 256, 0, stream>>>(H, wl, wr, int_w1, res_w2, atom_w2,
                                        res_b2, atom_b2, int_b1, simw, wq_b, wk_w,
                                        Hpl, Her, P1, P2, MrF, MaF, cvec, gv, wkT);
  mm_rows<<<256, 256, 0, stream>>>(wq_w, wkT, WqkF);        // Wqk = wq @ wk^T
  pack_kernel<<<1280, 256, 0, stream>>>(MrF, MaF, int_w2, wg_w, WqkF, wpack);
  pair_kernel<<<2304, 256, 0, stream>>>(X, res_w1, res_b1, atom_w1, atom_b1,
                                        int_b2, wg_b, wpack, cvec, gv,
                                        P1, P2, Hpl, Her, ftri, vbuf, Zsw);
  attn_kernel<<<2304, 256, 0, stream>>>(Zsw, vbuf, wpack, cbufg);
  out_kernel<<<384, 256, 0, stream>>>(Zsw, ftri, cbufg, wv_w, wv_b, (float*)d_out);
  hipMemcpyAsync((float*)d_out + NPAR * DD, H + NPAR * DD,
                 (1024 - NPAR) * DD * sizeof(float), hipMemcpyDeviceToDevice, stream);
}

// Round 9
// 370.354 us; speedup vs baseline: 2.7301x; 1.0568x over previous
//
#include <hip/hip_runtime.h>

#define NPAR 384
#define NEPI 384
#define DD   256

using bf16x8 = __bf16 __attribute__((ext_vector_type(8)));
using bf16x2 = __bf16 __attribute__((ext_vector_type(2)));
using f32x4  = float __attribute__((ext_vector_type(4)));

#if defined(__has_builtin)
#if __has_builtin(__builtin_amdgcn_cvt_pk_bf16_f32)
#define HAVE_PK_BF16 1
#endif
#endif

__device__ __forceinline__ float sigm(float x) { return 1.0f / (1.0f + __expf(-x)); }
__device__ __forceinline__ float silu(float x) { return x / (1.0f + __expf(-x)); }
__device__ __forceinline__ unsigned short f2bf(float f) {
  unsigned u = __float_as_uint(f);
  u += 0x7fffu + ((u >> 16) & 1u);
  return (unsigned short)(u >> 16);
}
__device__ __forceinline__ float bf2f(unsigned u16) {
  return __uint_as_float(u16 << 16);
}
__device__ __forceinline__ uint2 pack4(float a, float b, float c, float d) {
  uint2 r;
#ifdef HAVE_PK_BF16
  bf16x2 lo = __builtin_amdgcn_cvt_pk_bf16_f32(a, b);
  bf16x2 hi = __builtin_amdgcn_cvt_pk_bf16_f32(c, d);
  r.x = __builtin_bit_cast(unsigned, lo);
  r.y = __builtin_bit_cast(unsigned, hi);
#else
  r.x = (unsigned)f2bf(a) | ((unsigned)f2bf(b) << 16);
  r.y = (unsigned)f2bf(c) | ((unsigned)f2bf(d) << 16);
#endif
  return r;
}

// ---------------- fused precompute kernel ----------------
// block ranges: [0,64) transpose wk->wkT ; [64,576) fold Mr/Ma ; [576,584) cvec ;
// [584,648) gvec ; [648,2184) mm_rows4 (Hpl/Her/P1/P2)

__global__ void prep_kernel(
    const float* __restrict__ H, const float* __restrict__ wl,
    const float* __restrict__ wr, const float* __restrict__ int_w1,
    const float* __restrict__ res_w2, const float* __restrict__ atom_w2,
    const float* __restrict__ res_b2, const float* __restrict__ atom_b2,
    const float* __restrict__ int_b1, const float* __restrict__ simw,
    const float* __restrict__ wq_b, const float* __restrict__ wk_w,
    float* __restrict__ Hpl, float* __restrict__ Her,
    float* __restrict__ P1, float* __restrict__ P2,
    float* __restrict__ MrF, float* __restrict__ MaF,
    float* __restrict__ cvec, float* __restrict__ gv,
    float* __restrict__ wkT) {
  __shared__ float tile[32][33];
  const int b = blockIdx.x, t = threadIdx.x;
  if (b < 64) {
    const int bx = b & 7, by = b >> 3;
    const int tx = t & 31, ty = t >> 5;
    for (int r = 0; r < 32; r += 8)
      tile[ty + r][tx] = wk_w[(by * 32 + ty + r) * 256 + bx * 32 + tx];
    __syncthreads();
    for (int r = 0; r < 32; r += 8)
      wkT[(bx * 32 + ty + r) * 256 + by * 32 + tx] = tile[tx][ty + r];
  } else if (b < 576) {
    const int bb = b - 64;
    const int i = bb & 255;
    const bool isMa = bb >= 256;
    const float wmix = 1.0f / (1.0f + __expf(-simw[0]));
    const float sc = isMa ? (1.0f - wmix) : wmix;
    const float* W2 = isMa ? atom_w2 : res_w2;
    float acc = 0.f;
#pragma unroll 8
    for (int k = 0; k < 256; ++k)
      acc += W2[i * 256 + k] * int_w1[(512 + k) * 256 + t];
    (isMa ? MaF : MrF)[i * 256 + t] = acc * sc;
  } else if (b < 584) {
    const int bb = b - 576;
    const float wmix = 1.0f / (1.0f + __expf(-simw[0]));
    float acc = (bb == 0) ? int_b1[t] : 0.f;
#pragma unroll
    for (int k = bb * 32; k < bb * 32 + 32; ++k) {
      float bm = wmix * res_b2[k] + (1.0f - wmix) * atom_b2[k];
      acc += bm * int_w1[(512 + k) * 256 + t];
    }
    atomicAdd(&cvec[t], acc);
  } else if (b < 648) {
    const int lane = t & 63, w = t >> 6;
    const int d = (b - 584) * 4 + w;
    float acc = 0.f;
#pragma unroll
    for (int i = 0; i < 4; ++i) {
      const int c = i * 64 + lane;
      acc += wk_w[d * 256 + c] * wq_b[c];
    }
    acc += __shfl_xor(acc, 1);
    acc += __shfl_xor(acc, 2);
    acc += __shfl_xor(acc, 4);
    acc += __shfl_xor(acc, 8);
    acc += __shfl_xor(acc, 16);
    acc += __shfl_xor(acc, 32);
    if (lane == 0) gv[d] = acc;
  } else {
    const int idx = b - 648;
    const int seg = idx / 384, r = idx % 384;
    const float* A;
    const float* B;
    float* C;
    switch (seg) {
      case 0:  A = H + r * 256;            B = wl;              C = Hpl + r * 256; break;
      case 1:  A = H + (NPAR + r) * 256;   B = wr;              C = Her + r * 256; break;
      case 2:  A = H + r * 256;            B = int_w1;          C = P1 + r * 256;  break;
      default: A = H + (NPAR + r) * 256;   B = int_w1 + 65536;  C = P2 + r * 256;  break;
    }
    float acc = 0.f;
#pragma unroll 8
    for (int k = 0; k < 256; ++k)
      acc += A[k] * B[k * 256 + t];
    C[t] = acc;
  }
}

// C[r][j] = sum_k A[r][k] * B[k][j]  (grid = #rows) — for Wqk = wq @ wkT
__global__ void mm_rows(const float* __restrict__ A, const float* __restrict__ B,
                        float* __restrict__ C) {
  const int r = blockIdx.x, j = threadIdx.x;
  float acc = 0.f;
#pragma unroll 8
  for (int k = 0; k < 256; ++k)
    acc += A[r * 256 + k] * B[k * 256 + j];
  C[r * 256 + j] = acc;
}

// pack 5 [256,256] matrices into MFMA fragment order:
// wpack[m][((ks*16+tile)*64 + lane)*8 + j] = W[k = ks*32 + (lane>>4)*8 + j][n = tile*16 + (lane&15)]
// slots: 0=Mr 1=Ma 2=int_w2 3=wg 4=Wqk
__global__ void pack_kernel(const float* __restrict__ MrF, const float* __restrict__ MaF,
                            const float* __restrict__ w2, const float* __restrict__ wg,
                            const float* __restrict__ WqkF, unsigned short* __restrict__ wpack) {
  const int idx = blockIdx.x * 256 + threadIdx.x;
  const int m = idx >> 16;
  const int r = idx & 65535;
  const int chunk = r >> 9;
  const int lane = (r >> 3) & 63;
  const int j = r & 7;
  const int k = (chunk >> 4) * 32 + (lane >> 4) * 8 + j;
  const int n = (chunk & 15) * 16 + (lane & 15);
  const float* src;
  switch (m) {
    case 0: src = MrF; break;
    case 1: src = MaF; break;
    case 2: src = w2; break;
    case 3: src = wg; break;
    default: src = WqkF; break;
  }
  wpack[idx] = f2bf(src[k * 256 + n]);
}

// ---------------- pairwise GEMM-chain kernel (64-row tiles) ----------------

__device__ __forceinline__ void zero_acc4(f32x4 (&acc)[4][4]) {
#pragma unroll
  for (int mt = 0; mt < 4; ++mt)
#pragma unroll
    for (int nt = 0; nt < 4; ++nt)
      acc[mt][nt] = (f32x4){0.f, 0.f, 0.f, 0.f};
}

// transposed-acc: mfma(Wfrag, ActFrag) -> acc^T[d][e]
// d = wv*64 + mt*16 + l4*4 + r, e = nt*16 + l15
__device__ __forceinline__ void gemm4(f32x4 (&acc)[4][4],
                                      const unsigned short* __restrict__ wp,
                                      const unsigned short* ub, int lane, int wv) {
  const int l15 = lane & 15, l4 = lane >> 4;
#pragma unroll
  for (int ks = 0; ks < 8; ++ks) {
    bf16x8 a[4];
#pragma unroll
    for (int mt = 0; mt < 4; ++mt)
      a[mt] = *reinterpret_cast<const bf16x8*>(wp + ((ks * 16 + wv * 4 + mt) * 64 + lane) * 8);
#pragma unroll
    for (int nt = 0; nt < 4; ++nt) {
      bf16x8 b = *reinterpret_cast<const bf16x8*>(ub + (nt * 16 + l15) * 264 + ks * 32 + l4 * 8);
#pragma unroll
      for (int mt = 0; mt < 4; ++mt)
        acc[mt][nt] = __builtin_amdgcn_mfma_f32_16x16x32_bf16(a[mt], b, acc[mt][nt], 0, 0, 0);
    }
  }
}

// fill ubuf[e][d] = silu(Sv[e]*w1[d] + b1[d]) ; thread owns 8 contiguous d, b128 writes
__device__ __forceinline__ void fill_u(unsigned short* ub, const float* Sv,
                                       const float* __restrict__ w1,
                                       const float* __restrict__ b1, int t) {
  const int dg = t & 31, rb = t >> 5;
  const f32x4 w1a = *reinterpret_cast<const f32x4*>(&w1[dg * 8]);
  const f32x4 w1b = *reinterpret_cast<const f32x4*>(&w1[dg * 8 + 4]);
  const f32x4 b1a = *reinterpret_cast<const f32x4*>(&b1[dg * 8]);
  const f32x4 b1b = *reinterpret_cast<const f32x4*>(&b1[dg * 8 + 4]);
#pragma unroll
  for (int i = 0; i < 8; ++i) {
    const int e = rb + i * 8;
    const float s = Sv[e];
    uint2 lo = pack4(silu(fmaf(s, w1a[0], b1a[0])), silu(fmaf(s, w1a[1], b1a[1])),
                     silu(fmaf(s, w1a[2], b1a[2])), silu(fmaf(s, w1a[3], b1a[3])));
    uint2 hi = pack4(silu(fmaf(s, w1b[0], b1b[0])), silu(fmaf(s, w1b[1], b1b[1])),
                     silu(fmaf(s, w1b[2], b1b[2])), silu(fmaf(s, w1b[3], b1b[3])));
    uint4 pk = {lo.x, lo.y, hi.x, hi.y};
    *reinterpret_cast<uint4*>(&ub[e * 264 + dg * 8]) = pk;
  }
}

__global__ __launch_bounds__(256, 3) void pair_kernel(
    const float* __restrict__ Xg,
    const float* __restrict__ res_w1, const float* __restrict__ res_b1,
    const float* __restrict__ atom_w1, const float* __restrict__ atom_b1,
    const float* __restrict__ int_b2, const float* __restrict__ wg_b,
    const unsigned short* __restrict__ wpack, const float* __restrict__ cvec,
    const float* __restrict__ P1, const float* __restrict__ P2,
    const float* __restrict__ Hpl, const float* __restrict__ Her,
    float* __restrict__ ftri, unsigned short* __restrict__ Zsw) {
  __shared__ __align__(16) unsigned short ubuf[64 * 264];
  __shared__ float Sv[64];
  __shared__ float pc[DD];
  const int t = threadIdx.x, lane = t & 63, wv = t >> 6;
  const int l15 = lane & 15, l4 = lane >> 4;
  const int p = blockIdx.x / 6, cc = blockIdx.x % 6, e0 = cc * 64;
  const int d0 = wv * 64;

  if (t < 64) {
    const int e = e0 + t;
    float dx = Xg[p * 42 + 3] - Xg[(NPAR + e) * 42 + 3];
    float dy = Xg[p * 42 + 4] - Xg[(NPAR + e) * 42 + 4];
    float dz = Xg[p * 42 + 5] - Xg[(NPAR + e) * 42 + 5];
    Sv[t] = dx * dx + dy * dy + dz * dz;
  }
  pc[t] = P1[p * DD + t] + cvec[t];
  __syncthreads();

  f32x4 acc[4][4];
  zero_acc4(acc);

  fill_u(ubuf, Sv, res_w1, res_b1, t);
  __syncthreads();
  gemm4(acc, wpack + 0 * 65536, ubuf, lane, wv);
  __syncthreads();
  fill_u(ubuf, Sv, atom_w1, atom_b1, t);
  __syncthreads();
  gemm4(acc, wpack + 1 * 65536, ubuf, lane, wv);
  __syncthreads();

  // epilogue: h = silu(zpre^T + pc[d] + P2[e][d]) -> ubuf[e][d]
#pragma unroll
  for (int mt = 0; mt < 4; ++mt) {
    const int d = d0 + mt * 16 + l4 * 4;
    const f32x4 pcv = *reinterpret_cast<const f32x4*>(&pc[d]);
#pragma unroll
    for (int nt = 0; nt < 4; ++nt) {
      const int e = nt * 16 + l15;
      const f32x4 p2v = *reinterpret_cast<const f32x4*>(&P2[(e0 + e) * DD + d]);
      uint2 pk = pack4(silu(acc[mt][nt][0] + pcv[0] + p2v[0]),
                       silu(acc[mt][nt][1] + pcv[1] + p2v[1]),
                       silu(acc[mt][nt][2] + pcv[2] + p2v[2]),
                       silu(acc[mt][nt][3] + pcv[3] + p2v[3]));
      *reinterpret_cast<uint2*>(&ubuf[e * 264 + d]) = pk;
    }
  }
  __syncthreads();

  // Z = h @ int_w2 + int_b2 -> ubuf
  zero_acc4(acc);
  gemm4(acc, wpack + 2 * 65536, ubuf, lane, wv);
  __syncthreads();
#pragma unroll
  for (int mt = 0; mt < 4; ++mt) {
    const int d = d0 + mt * 16 + l4 * 4;
    const f32x4 bb = *reinterpret_cast<const f32x4*>(&int_b2[d]);
#pragma unroll
    for (int nt = 0; nt < 4; ++nt) {
      const int e = nt * 16 + l15;
      *reinterpret_cast<uint2*>(&ubuf[e * 264 + d]) =
          pack4(acc[mt][nt][0] + bb[0], acc[mt][nt][1] + bb[1],
                acc[mt][nt][2] + bb[2], acc[mt][nt][3] + bb[3]);
    }
  }
  __syncthreads();

  // swizzled MFMA-fragment-order store: grp = cc*4 + wv, e = grp*16 + l15
  {
    unsigned short* Zd = Zsw + (size_t)p * 98304 + (size_t)(cc * 4 + wv) * 4096 + lane * 8;
#pragma unroll
    for (int ks = 0; ks < 8; ++ks) {
      *reinterpret_cast<uint4*>(Zd + ks * 512) =
          *reinterpret_cast<const uint4*>(&ubuf[(wv * 16 + l15) * 264 + ks * 32 + l4 * 8]);
    }
  }

  // gate: f_tri[d] += Hpl[p][d] * sum_e sigm(Z@wg + b) * Her[e][d]
  zero_acc4(acc);
  gemm4(acc, wpack + 3 * 65536, ubuf, lane, wv);
#pragma unroll
  for (int mt = 0; mt < 4; ++mt) {
    const int d = d0 + mt * 16 + l4 * 4;
    const f32x4 bb = *reinterpret_cast<const f32x4*>(&wg_b[d]);
    const f32x4 hl = *reinterpret_cast<const f32x4*>(&Hpl[p * DD + d]);
    f32x4 fs = (f32x4){0.f, 0.f, 0.f, 0.f};
#pragma unroll
    for (int nt = 0; nt < 4; ++nt) {
      const int e = e0 + nt * 16 + l15;
      const f32x4 hr = *reinterpret_cast<const f32x4*>(&Her[e * DD + d]);
#pragma unroll
      for (int r = 0; r < 4; ++r)
        fs[r] += sigm(acc[mt][nt][r] + bb[r]) * hr[r];
    }
#pragma unroll
    for (int r = 0; r < 4; ++r) {
      float v = fs[r] * hl[r];
      v += __shfl_xor(v, 1);
      v += __shfl_xor(v, 2);
      v += __shfl_xor(v, 4);
      v += __shfl_xor(v, 8);
      if (l15 == 0) atomicAdd(&ftri[p * DD + d + r], v);
    }
  }
}

// ---------------- fused attention kernel: block = (p, 64-row chunk) ----------------
// scores = (Z_c Wqk + 1*gv^T) Z^T / 16 — gv and 1/16 folded into T.
// col-sums of softmax -> cbufg[p].

__global__ __launch_bounds__(256, 3) void attn_kernel(
    const unsigned short* __restrict__ Zsw, const float* __restrict__ gv,
    const unsigned short* __restrict__ wpack, float* __restrict__ cbufg) {
  __shared__ __align__(16) unsigned short Tc[64 * 264];
  __shared__ float red[256];
  __shared__ float red2[256];
  const int t = threadIdx.x, lane = t & 63, wv = t >> 6;
  const int l15 = lane & 15, l4 = lane >> 4;
  // XCD swizzle: all 6 chunks of one p land on the same XCD (xcd = blk % 8)
  const int xcd = blockIdx.x & 7, inner = blockIdx.x >> 3;
  const int p = (inner / 6) * 8 + xcd, c = inner % 6;
  const unsigned short* Zsp = Zsw + (size_t)p * 98304;
  const unsigned short* wqk = wpack + 4 * 65536;

  // T' = (Zc @ Wqk + gv) / 16, b-frags double-buffered from Zsw
  {
    f32x4 ta[4][4];
#pragma unroll
    for (int mt = 0; mt < 4; ++mt)
#pragma unroll
      for (int nt = 0; nt < 4; ++nt) ta[mt][nt] = (f32x4){0.f, 0.f, 0.f, 0.f};
    const unsigned short* Tb = Zsp + (size_t)(c * 4) * 4096 + lane * 8;
    bf16x8 bcur[4], bnxt[4];
#pragma unroll
    for (int nt = 0; nt < 4; ++nt)
      bcur[nt] = *reinterpret_cast<const bf16x8*>(Tb + nt * 4096);
#pragma unroll
    for (int ks = 0; ks < 8; ++ks) {
      if (ks < 7) {
#pragma unroll
        for (int nt = 0; nt < 4; ++nt)
          bnxt[nt] = *reinterpret_cast<const bf16x8*>(Tb + nt * 4096 + (ks + 1) * 512);
      }
      bf16x8 a[4];
#pragma unroll
      for (int mt = 0; mt < 4; ++mt)
        a[mt] = *reinterpret_cast<const bf16x8*>(wqk + ((ks * 16 + wv * 4 + mt) * 64 + lane) * 8);
#pragma unroll
      for (int nt = 0; nt < 4; ++nt)
#pragma unroll
        for (int mt = 0; mt < 4; ++mt)
          ta[mt][nt] = __builtin_amdgcn_mfma_f32_16x16x32_bf16(a[mt], bcur[nt], ta[mt][nt], 0, 0, 0);
      if (ks < 7) {
#pragma unroll
        for (int nt = 0; nt < 4; ++nt) bcur[nt] = bnxt[nt];
      }
    }
#pragma unroll
    for (int mt = 0; mt < 4; ++mt) {
      const int d = wv * 64 + mt * 16 + l4 * 4;
      const f32x4 gq = *reinterpret_cast<const f32x4*>(&gv[d]);
#pragma unroll
      for (int nt = 0; nt < 4; ++nt) {
        const int e = nt * 16 + l15;
        *reinterpret_cast<uint2*>(&Tc[e * 264 + d]) =
            pack4((ta[mt][nt][0] + gq[0]) * 0.0625f, (ta[mt][nt][1] + gq[1]) * 0.0625f,
                  (ta[mt][nt][2] + gq[2]) * 0.0625f, (ta[mt][nt][3] + gq[3]) * 0.0625f);
      }
    }
  }
  __syncthreads();

  // S = Tc @ Z^T; a-frags from LDS, b-frags rolling 3+3 prefetch from Zsw
  f32x4 sc[4][6];
#pragma unroll
  for (int mt = 0; mt < 4; ++mt)
#pragma unroll
    for (int s = 0; s < 6; ++s) sc[mt][s] = (f32x4){0.f, 0.f, 0.f, 0.f};

  {
    const unsigned short* Sb = Zsp + (size_t)wv * 4096 + lane * 8;
    bf16x8 b0[3], b1[3];
#pragma unroll
    for (int j = 0; j < 3; ++j)
      b0[j] = *reinterpret_cast<const bf16x8*>(Sb + j * 16384);
#pragma unroll
    for (int ks = 0; ks < 8; ++ks) {
#pragma unroll
      for (int j = 0; j < 3; ++j)
        b1[j] = *reinterpret_cast<const bf16x8*>(Sb + (3 + j) * 16384 + ks * 512);
      bf16x8 a[4];
#pragma unroll
      for (int mt = 0; mt < 4; ++mt)
        a[mt] = *reinterpret_cast<const bf16x8*>(&Tc[(mt * 16 + l15) * 264 + ks * 32 + l4 * 8]);
#pragma unroll
      for (int j = 0; j < 3; ++j)
#pragma unroll
        for (int mt = 0; mt < 4; ++mt)
          sc[mt][j] = __builtin_amdgcn_mfma_f32_16x16x32_bf16(a[mt], b0[j], sc[mt][j], 0, 0, 0);
      if (ks < 7) {
#pragma unroll
        for (int j = 0; j < 3; ++j)
          b0[j] = *reinterpret_cast<const bf16x8*>(Sb + j * 16384 + (ks + 1) * 512);
      }
#pragma unroll
      for (int j = 0; j < 3; ++j)
#pragma unroll
        for (int mt = 0; mt < 4; ++mt)
          sc[mt][3 + j] = __builtin_amdgcn_mfma_f32_16x16x32_bf16(a[mt], b1[j], sc[mt][3 + j], 0, 0, 0);
    }
  }

  // softmax over f (384 cols), rows e = mt*16 + l4*4 + r; sc is already scaled
  float rmax[4][4];
#pragma unroll
  for (int mt = 0; mt < 4; ++mt) {
#pragma unroll
    for (int r = 0; r < 4; ++r) {
      float m = -1e30f;
#pragma unroll
      for (int s = 0; s < 6; ++s) m = fmaxf(m, sc[mt][s][r]);
      m = fmaxf(m, __shfl_xor(m, 1));
      m = fmaxf(m, __shfl_xor(m, 2));
      m = fmaxf(m, __shfl_xor(m, 4));
      m = fmaxf(m, __shfl_xor(m, 8));
      rmax[mt][r] = m;
    }
  }
  if (l15 == 0) {
#pragma unroll
    for (int mt = 0; mt < 4; ++mt)
#pragma unroll
      for (int r = 0; r < 4; ++r)
        red[wv * 64 + mt * 16 + l4 * 4 + r] = rmax[mt][r];
  }
  __syncthreads();
#pragma unroll
  for (int mt = 0; mt < 4; ++mt) {
#pragma unroll
    for (int r = 0; r < 4; ++r) {
      const int row = mt * 16 + l4 * 4 + r;
      rmax[mt][r] = fmaxf(fmaxf(red[row], red[64 + row]), fmaxf(red[128 + row], red[192 + row]));
    }
  }

  float rsum[4][4];
#pragma unroll
  for (int mt = 0; mt < 4; ++mt) {
#pragma unroll
    for (int r = 0; r < 4; ++r) {
      float sSum = 0.f;
#pragma unroll
      for (int s = 0; s < 6; ++s) {
        float e = __expf(sc[mt][s][r] - rmax[mt][r]);
        sc[mt][s][r] = e;
        sSum += e;
      }
      sSum += __shfl_xor(sSum, 1);
      sSum += __shfl_xor(sSum, 2);
      sSum += __shfl_xor(sSum, 4);
      sSum += __shfl_xor(sSum, 8);
      rsum[mt][r] = sSum;
    }
  }
  if (l15 == 0) {
#pragma unroll
    for (int mt = 0; mt < 4; ++mt)
#pragma unroll
      for (int r = 0; r < 4; ++r)
        red2[wv * 64 + mt * 16 + l4 * 4 + r] = rsum[mt][r];
  }
  __syncthreads();
  float rinv[4][4];
#pragma unroll
  for (int mt = 0; mt < 4; ++mt) {
#pragma unroll
    for (int r = 0; r < 4; ++r) {
      const int row = mt * 16 + l4 * 4 + r;
      rinv[mt][r] = 1.0f / (red2[row] + red2[64 + row] + red2[128 + row] + red2[192 + row]);
    }
  }

  // column sums of A over this chunk's 64 rows -> cbufg
#pragma unroll
  for (int s = 0; s < 6; ++s) {
    float v = 0.f;
#pragma unroll
    for (int mt = 0; mt < 4; ++mt)
#pragma unroll
      for (int r = 0; r < 4; ++r)
        v += sc[mt][s][r] * rinv[mt][r];
    v += __shfl_xor(v, 16);
    v += __shfl_xor(v, 32);
    if (lane < 16)
      atomicAdd(&cbufg[p * NEPI + s * 64 + wv * 16 + lane], v);
  }
}

// ---------------- output kernel ----------------
// out[p] = (ftri[p] + (c^T Z_p) @ wv + 384*bv) / 384
// Z read from swizzled Zsw — 1 KB contiguous per wave-load.

__global__ __launch_bounds__(256) void out_kernel(
    const unsigned short* __restrict__ Zsw, const float* __restrict__ ftri,
    const float* __restrict__ cbufg, const float* __restrict__ wvw,
    const float* __restrict__ wvb, float* __restrict__ out) {
  __shared__ float cb[NEPI];
  __shared__ float part[16][257];
  __shared__ float u[DD];
  const int p = blockIdx.x, t = threadIdx.x;
  const int lane = t & 63, wv = t >> 6;
  const int l15 = lane & 15, l4 = lane >> 4;
  for (int i = t; i < NEPI; i += 256) cb[i] = cbufg[p * NEPI + i];
  __syncthreads();
  const unsigned short* Zsp = Zsw + (size_t)p * 98304;
  float a16[16];
#pragma unroll
  for (int j = 0; j < 16; ++j) a16[j] = 0.f;
#pragma unroll 4
  for (int grp = 0; grp < 24; ++grp) {
    const float w = cb[grp * 16 + l15];
    const uint4 z0 = *reinterpret_cast<const uint4*>(Zsp + grp * 4096 + wv * 512 + lane * 8);
    const uint4 z1 = *reinterpret_cast<const uint4*>(Zsp + grp * 4096 + (wv + 4) * 512 + lane * 8);
    a16[0] = fmaf(w, bf2f(z0.x & 0xffffu), a16[0]);
    a16[1] = fmaf(w, bf2f(z0.x >> 16), a16[1]);
    a16[2] = fmaf(w, bf2f(z0.y & 0xffffu), a16[2]);
    a16[3] = fmaf(w, bf2f(z0.y >> 16), a16[3]);
    a16[4] = fmaf(w, bf2f(z0.z & 0xffffu), a16[4]);
    a16[5] = fmaf(w, bf2f(z0.z >> 16), a16[5]);
    a16[6] = fmaf(w, bf2f(z0.w & 0xffffu), a16[6]);
    a16[7] = fmaf(w, bf2f(z0.w >> 16), a16[7]);
    a16[8]  = fmaf(w, bf2f(z1.x & 0xffffu), a16[8]);
    a16[9]  = fmaf(w, bf2f(z1.x >> 16), a16[9]);
    a16[10] = fmaf(w, bf2f(z1.y & 0xffffu), a16[10]);
    a16[11] = fmaf(w, bf2f(z1.y >> 16), a16[11]);
    a16[12] = fmaf(w, bf2f(z1.z & 0xffffu), a16[12]);
    a16[13] = fmaf(w, bf2f(z1.z >> 16), a16[13]);
    a16[14] = fmaf(w, bf2f(z1.w & 0xffffu), a16[14]);
    a16[15] = fmaf(w, bf2f(z1.w >> 16), a16[15]);
  }
#pragma unroll
  for (int j = 0; j < 8; ++j) part[l15][wv * 32 + l4 * 8 + j] = a16[j];
#pragma unroll
  for (int j = 0; j < 8; ++j) part[l15][128 + wv * 32 + l4 * 8 + j] = a16[8 + j];
  __syncthreads();
  float uu = 0.f;
#pragma unroll
  for (int g = 0; g < 16; ++g) uu += part[g][t];
  u[t] = uu;
  __syncthreads();
  float acc = ftri[p * DD + t] + 384.0f * wvb[t];
#pragma unroll 8
  for (int d = 0; d < DD; ++d)
    acc = fmaf(u[d], wvw[d * DD + t], acc);
  out[p * DD + t] = acc * (1.0f / 384.0f);
}

// ---------------- launch ----------------

extern "C" void kernel_launch(void* const* d_in, const int* in_sizes, int n_in,
                              void* d_out, int out_size, void* d_ws, size_t ws_size,
                              hipStream_t stream) {
  (void)in_sizes; (void)n_in; (void)out_size; (void)ws_size;
  const float* H = (const float*)d_in[0];
  const float* X = (const float*)d_in[1];
  const float* res_w1 = (const float*)d_in[4];
  const float* res_b1 = (const float*)d_in[5];
  const float* res_w2 = (const float*)d_in[6];
  const float* res_b2 = (const float*)d_in[7];
  const float* atom_w1 = (const float*)d_in[8];
  const float* atom_b1 = (const float*)d_in[9];
  const float* atom_w2 = (const float*)d_in[10];
  const float* atom_b2 = (const float*)d_in[11];
  const float* simw = (const float*)d_in[12];
  const float* int_w1 = (const float*)d_in[13];
  const float* int_b1 = (const float*)d_in[14];
  const float* int_w2 = (const float*)d_in[15];
  const float* int_b2 = (const float*)d_in[16];
  const float* wl = (const float*)d_in[17];
  const float* wr = (const float*)d_in[18];
  const float* wg_w = (const float*)d_in[19];
  const float* wg_b = (const float*)d_in[20];
  const float* wq_w = (const float*)d_in[21];
  const float* wq_b = (const float*)d_in[22];
  const float* wk_w = (const float*)d_in[23];
  const float* wv_w = (const float*)d_in[25];
  const float* wv_b = (const float*)d_in[26];

  char* ws = (char*)d_ws;
  unsigned short* wpack = (unsigned short*)(ws + 0);      //  655360 B (5 slots)
  float* MrF   = (float*)(ws + 655360);
  float* MaF   = (float*)(ws + 917504);
  float* WqkF  = (float*)(ws + 1179648);
  float* wkT   = (float*)(ws + 1441792);
  float* cvec  = (float*)(ws + 1703936);
  float* gv    = (float*)(ws + 1704960);
  float* P1    = (float*)(ws + 1705984);
  float* P2    = (float*)(ws + 2099200);
  float* Hpl   = (float*)(ws + 2492416);
  float* Her   = (float*)(ws + 2885632);
  float* ftri  = (float*)(ws + 3278848);                  //  393216 B
  float* cbufg = (float*)(ws + 3672064);                  //  589824 B
  unsigned short* Zsw = (unsigned short*)(ws + 4261888);  // 75497472 B (MFMA frag order)

  hipMemsetAsync(ftri, 0, 393216 + 589824, stream);       // ftri + cbufg (contiguous)
  hipMemsetAsync(cvec, 0, DD * sizeof(float), stream);
  prep_kernel<<<2184, 256, 0, stream>>>(H, wl, wr, int_w1, res_w2, atom_w2,
                                        res_b2, atom_b2, int_b1, simw, wq_b, wk_w,
                                        Hpl, Her, P1, P2, MrF, MaF, cvec, gv, wkT);
  mm_rows<<<256, 256, 0, stream>>>(wq_w, wkT, WqkF);        // Wqk = wq @ wk^T
  pack_kernel<<<1280, 256, 0, stream>>>(MrF, MaF, int_w2, wg_w, WqkF, wpack);
  pair_kernel<<<2304, 256, 0, stream>>>(X, res_w1, res_b1, atom_w1, atom_b1,
                                        int_b2, wg_b, wpack, cvec,
                                        P1, P2, Hpl, Her, ftri, Zsw);
  attn_kernel<<<2304, 256, 0, stream>>>(Zsw, gv, wpack, cbufg);
  out_kernel<<<384, 256, 0, stream>>>(Zsw, ftri, cbufg, wv_w, wv_b, (float*)d_out);
  hipMemcpyAsync((float*)d_out + NPAR * DD, H + NPAR * DD,
                 (1024 - NPAR) * DD * sizeof(float), hipMemcpyDeviceToDevice, stream);
}

// Round 10
// 347.372 us; speedup vs baseline: 2.9107x; 1.0662x over previous
//
#include <hip/hip_runtime.h>

#define NPAR 384
#define NEPI 384
#define DD   256
#define NTAB 4096
#define SMAX 96.0f
#define SDELTA (SMAX / NTAB)
#define SINVD (NTAB / SMAX)

using bf16x8 = __bf16 __attribute__((ext_vector_type(8)));
using bf16x2 = __bf16 __attribute__((ext_vector_type(2)));
using f32x4  = float __attribute__((ext_vector_type(4)));

#if defined(__has_builtin)
#if __has_builtin(__builtin_amdgcn_cvt_pk_bf16_f32)
#define HAVE_PK_BF16 1
#endif
#endif

__device__ __forceinline__ float sigm(float x) { return 1.0f / (1.0f + __expf(-x)); }
__device__ __forceinline__ float silu(float x) { return x / (1.0f + __expf(-x)); }
__device__ __forceinline__ unsigned short f2bf(float f) {
  unsigned u = __float_as_uint(f);
  u += 0x7fffu + ((u >> 16) & 1u);
  return (unsigned short)(u >> 16);
}
__device__ __forceinline__ float bf2f(unsigned u16) {
  return __uint_as_float(u16 << 16);
}
__device__ __forceinline__ float bf2f_lo(unsigned w) {   // low 16 bits
  return __uint_as_float(w << 16);
}
__device__ __forceinline__ float bf2f_hi(unsigned w) {   // high 16 bits
  return __uint_as_float(w & 0xffff0000u);
}
__device__ __forceinline__ uint2 pack4(float a, float b, float c, float d) {
  uint2 r;
#ifdef HAVE_PK_BF16
  bf16x2 lo = __builtin_amdgcn_cvt_pk_bf16_f32(a, b);
  bf16x2 hi = __builtin_amdgcn_cvt_pk_bf16_f32(c, d);
  r.x = __builtin_bit_cast(unsigned, lo);
  r.y = __builtin_bit_cast(unsigned, hi);
#else
  r.x = (unsigned)f2bf(a) | ((unsigned)f2bf(b) << 16);
  r.y = (unsigned)f2bf(c) | ((unsigned)f2bf(d) << 16);
#endif
  return r;
}

// ---------------- fused precompute kernel ----------------
// block ranges: [0,64) transpose wk->wkT ; [64,576) fold Mr/Ma ; [576,584) cvec ;
// [584,648) gvec ; [648,2184) mm_rows4 (Hpl/Her/P1/P2)

__global__ void prep_kernel(
    const float* __restrict__ H, const float* __restrict__ wl,
    const float* __restrict__ wr, const float* __restrict__ int_w1,
    const float* __restrict__ res_w2, const float* __restrict__ atom_w2,
    const float* __restrict__ res_b2, const float* __restrict__ atom_b2,
    const float* __restrict__ int_b1, const float* __restrict__ simw,
    const float* __restrict__ wq_b, const float* __restrict__ wk_w,
    float* __restrict__ Hpl, float* __restrict__ Her,
    float* __restrict__ P1, float* __restrict__ P2,
    float* __restrict__ MrF, float* __restrict__ MaF,
    float* __restrict__ cvec, float* __restrict__ gv,
    float* __restrict__ wkT) {
  __shared__ float tile[32][33];
  const int b = blockIdx.x, t = threadIdx.x;
  if (b < 64) {
    const int bx = b & 7, by = b >> 3;
    const int tx = t & 31, ty = t >> 5;
    for (int r = 0; r < 32; r += 8)
      tile[ty + r][tx] = wk_w[(by * 32 + ty + r) * 256 + bx * 32 + tx];
    __syncthreads();
    for (int r = 0; r < 32; r += 8)
      wkT[(bx * 32 + ty + r) * 256 + by * 32 + tx] = tile[tx][ty + r];
  } else if (b < 576) {
    const int bb = b - 64;
    const int i = bb & 255;
    const bool isMa = bb >= 256;
    const float wmix = 1.0f / (1.0f + __expf(-simw[0]));
    const float sc = isMa ? (1.0f - wmix) : wmix;
    const float* W2 = isMa ? atom_w2 : res_w2;
    float acc = 0.f;
#pragma unroll 8
    for (int k = 0; k < 256; ++k)
      acc += W2[i * 256 + k] * int_w1[(512 + k) * 256 + t];
    (isMa ? MaF : MrF)[i * 256 + t] = acc * sc;
  } else if (b < 584) {
    const int bb = b - 576;
    const float wmix = 1.0f / (1.0f + __expf(-simw[0]));
    float acc = (bb == 0) ? int_b1[t] : 0.f;
#pragma unroll
    for (int k = bb * 32; k < bb * 32 + 32; ++k) {
      float bm = wmix * res_b2[k] + (1.0f - wmix) * atom_b2[k];
      acc += bm * int_w1[(512 + k) * 256 + t];
    }
    atomicAdd(&cvec[t], acc);
  } else if (b < 648) {
    const int lane = t & 63, w = t >> 6;
    const int d = (b - 584) * 4 + w;
    float acc = 0.f;
#pragma unroll
    for (int i = 0; i < 4; ++i) {
      const int c = i * 64 + lane;
      acc += wk_w[d * 256 + c] * wq_b[c];
    }
    acc += __shfl_xor(acc, 1);
    acc += __shfl_xor(acc, 2);
    acc += __shfl_xor(acc, 4);
    acc += __shfl_xor(acc, 8);
    acc += __shfl_xor(acc, 16);
    acc += __shfl_xor(acc, 32);
    if (lane == 0) gv[d] = acc;
  } else {
    const int idx = b - 648;
    const int seg = idx / 384, r = idx % 384;
    const float* A;
    const float* B;
    float* C;
    switch (seg) {
      case 0:  A = H + r * 256;            B = wl;              C = Hpl + r * 256; break;
      case 1:  A = H + (NPAR + r) * 256;   B = wr;              C = Her + r * 256; break;
      case 2:  A = H + r * 256;            B = int_w1;          C = P1 + r * 256;  break;
      default: A = H + (NPAR + r) * 256;   B = int_w1 + 65536;  C = P2 + r * 256;  break;
    }
    float acc = 0.f;
#pragma unroll 8
    for (int k = 0; k < 256; ++k)
      acc += A[k] * B[k * 256 + t];
    C[t] = acc;
  }
}

// C[r][j] = sum_k A[r][k] * B[k][j]  (grid = #rows) — for Wqk = wq @ wkT
__global__ void mm_rows(const float* __restrict__ A, const float* __restrict__ B,
                        float* __restrict__ C) {
  const int r = blockIdx.x, j = threadIdx.x;
  float acc = 0.f;
#pragma unroll 8
  for (int k = 0; k < 256; ++k)
    acc += A[r * 256 + k] * B[k * 256 + j];
  C[r * 256 + j] = acc;
}

// pack 5 [256,256] matrices into MFMA fragment order:
// wpack[m][((ks*16+tile)*64 + lane)*8 + j] = W[k = ks*32 + (lane>>4)*8 + j][n = tile*16 + (lane&15)]
// slots: 0=Mr 1=Ma 2=int_w2 3=wg 4=Wqk
__global__ void pack_kernel(const float* __restrict__ MrF, const float* __restrict__ MaF,
                            const float* __restrict__ w2, const float* __restrict__ wg,
                            const float* __restrict__ WqkF, unsigned short* __restrict__ wpack) {
  const int idx = blockIdx.x * 256 + threadIdx.x;
  const int m = idx >> 16;
  const int r = idx & 65535;
  const int chunk = r >> 9;
  const int lane = (r >> 3) & 63;
  const int j = r & 7;
  const int k = (chunk >> 4) * 32 + (lane >> 4) * 8 + j;
  const int n = (chunk & 15) * 16 + (lane & 15);
  const float* src;
  switch (m) {
    case 0: src = MrF; break;
    case 1: src = MaF; break;
    case 2: src = w2; break;
    case 3: src = wg; break;
    default: src = WqkF; break;
  }
  wpack[idx] = f2bf(src[k * 256 + n]);
}

// ---------------- shared GEMM helpers ----------------

__device__ __forceinline__ void zero_acc4(f32x4 (&acc)[4][4]) {
#pragma unroll
  for (int mt = 0; mt < 4; ++mt)
#pragma unroll
    for (int nt = 0; nt < 4; ++nt)
      acc[mt][nt] = (f32x4){0.f, 0.f, 0.f, 0.f};
}

// transposed-acc: mfma(Wfrag, ActFrag) -> acc^T[d][e]
// d = wv*64 + mt*16 + l4*4 + r, e = nt*16 + l15
__device__ __forceinline__ void gemm4(f32x4 (&acc)[4][4],
                                      const unsigned short* __restrict__ wp,
                                      const unsigned short* ub, int lane, int wv) {
  const int l15 = lane & 15, l4 = lane >> 4;
#pragma unroll
  for (int ks = 0; ks < 8; ++ks) {
    bf16x8 a[4];
#pragma unroll
    for (int mt = 0; mt < 4; ++mt)
      a[mt] = *reinterpret_cast<const bf16x8*>(wp + ((ks * 16 + wv * 4 + mt) * 64 + lane) * 8);
#pragma unroll
    for (int nt = 0; nt < 4; ++nt) {
      bf16x8 b = *reinterpret_cast<const bf16x8*>(ub + (nt * 16 + l15) * 264 + ks * 32 + l4 * 8);
#pragma unroll
      for (int mt = 0; mt < 4; ++mt)
        acc[mt][nt] = __builtin_amdgcn_mfma_f32_16x16x32_bf16(a[mt], b, acc[mt][nt], 0, 0, 0);
    }
  }
}

// fill ubuf[e][d] = silu(Sv[e]*w1[d] + b1[d]) ; thread owns 8 contiguous d, b128 writes
__device__ __forceinline__ void fill_u(unsigned short* ub, const float* Sv,
                                       const float* __restrict__ w1,
                                       const float* __restrict__ b1, int t) {
  const int dg = t & 31, rb = t >> 5;
  const f32x4 w1a = *reinterpret_cast<const f32x4*>(&w1[dg * 8]);
  const f32x4 w1b = *reinterpret_cast<const f32x4*>(&w1[dg * 8 + 4]);
  const f32x4 b1a = *reinterpret_cast<const f32x4*>(&b1[dg * 8]);
  const f32x4 b1b = *reinterpret_cast<const f32x4*>(&b1[dg * 8 + 4]);
#pragma unroll
  for (int i = 0; i < 8; ++i) {
    const int e = rb + i * 8;
    const float s = Sv[e];
    uint2 lo = pack4(silu(fmaf(s, w1a[0], b1a[0])), silu(fmaf(s, w1a[1], b1a[1])),
                     silu(fmaf(s, w1a[2], b1a[2])), silu(fmaf(s, w1a[3], b1a[3])));
    uint2 hi = pack4(silu(fmaf(s, w1b[0], b1b[0])), silu(fmaf(s, w1b[1], b1b[1])),
                     silu(fmaf(s, w1b[2], b1b[2])), silu(fmaf(s, w1b[3], b1b[3])));
    uint4 pk = {lo.x, lo.y, hi.x, hi.y};
    *reinterpret_cast<uint4*>(&ub[e * 264 + dg * 8]) = pk;
  }
}

// ---------------- table build kernel: tab[n][d] = F(n*SDELTA)[d] ----------------
// F(s) = silu(s*w1r+b1r)@Mr + silu(s*w1a+b1a)@Ma   (uses wpack slots 0,1)

__global__ __launch_bounds__(256, 3) void tab_kernel(
    const float* __restrict__ res_w1, const float* __restrict__ res_b1,
    const float* __restrict__ atom_w1, const float* __restrict__ atom_b1,
    const unsigned short* __restrict__ wpack, unsigned short* __restrict__ tab) {
  __shared__ __align__(16) unsigned short ubuf[64 * 264];
  __shared__ float Sv[64];
  const int t = threadIdx.x, lane = t & 63, wv = t >> 6;
  const int l15 = lane & 15, l4 = lane >> 4;
  const int n0 = blockIdx.x * 64;
  if (t < 64) Sv[t] = (n0 + t) * SDELTA;
  __syncthreads();
  f32x4 acc[4][4];
  zero_acc4(acc);
  fill_u(ubuf, Sv, res_w1, res_b1, t);
  __syncthreads();
  gemm4(acc, wpack + 0 * 65536, ubuf, lane, wv);
  __syncthreads();
  fill_u(ubuf, Sv, atom_w1, atom_b1, t);
  __syncthreads();
  gemm4(acc, wpack + 1 * 65536, ubuf, lane, wv);
  // store row-major bf16: node = n0 + nt*16 + l15, d = wv*64 + mt*16 + l4*4
#pragma unroll
  for (int mt = 0; mt < 4; ++mt) {
    const int d = wv * 64 + mt * 16 + l4 * 4;
#pragma unroll
    for (int nt = 0; nt < 4; ++nt) {
      const int n = n0 + nt * 16 + l15;
      *reinterpret_cast<uint2*>(&tab[n * 256 + d]) =
          pack4(acc[mt][nt][0], acc[mt][nt][1], acc[mt][nt][2], acc[mt][nt][3]);
    }
  }
}

// ---------------- pairwise kernel (64-row tiles): table-interp h + 2 GEMMs ----------------

__global__ __launch_bounds__(256, 3) void pair_kernel(
    const float* __restrict__ Xg, const unsigned short* __restrict__ tab,
    const float* __restrict__ int_b2, const float* __restrict__ wg_b,
    const unsigned short* __restrict__ wpack, const float* __restrict__ cvec,
    const float* __restrict__ P1, const float* __restrict__ P2,
    const float* __restrict__ Hpl, const float* __restrict__ Her,
    float* __restrict__ ftri, unsigned short* __restrict__ Zsw) {
  __shared__ __align__(16) unsigned short ubuf[64 * 264];
  __shared__ float Sv[64];
  __shared__ float pc[DD];
  const int t = threadIdx.x, lane = t & 63, wv = t >> 6;
  const int l15 = lane & 15, l4 = lane >> 4;
  const int p = blockIdx.x / 6, cc = blockIdx.x % 6, e0 = cc * 64;
  const int d0 = wv * 64;

  if (t < 64) {
    const int e = e0 + t;
    float dx = Xg[p * 42 + 3] - Xg[(NPAR + e) * 42 + 3];
    float dy = Xg[p * 42 + 4] - Xg[(NPAR + e) * 42 + 4];
    float dz = Xg[p * 42 + 5] - Xg[(NPAR + e) * 42 + 5];
    Sv[t] = dx * dx + dy * dy + dz * dz;
  }
  pc[t] = P1[p * DD + t] + cvec[t];
  __syncthreads();

  // h-fill: h[e][d] = silu(lerp(tab, S[e])[d] + pc[d] + P2[e][d]) -> ubuf
  {
    const int dg = t & 31, rb = t >> 5;
    const f32x4 pca = *reinterpret_cast<const f32x4*>(&pc[dg * 8]);
    const f32x4 pcb = *reinterpret_cast<const f32x4*>(&pc[dg * 8 + 4]);
#pragma unroll
    for (int i = 0; i < 8; ++i) {
      const int e = rb + i * 8;
      float sv = Sv[e] * SINVD;
      int idx = (int)sv;
      idx = idx > (NTAB - 2) ? (NTAB - 2) : idx;
      const float fr = sv - (float)idx;
      const uint4 t0 = *reinterpret_cast<const uint4*>(&tab[idx * 256 + dg * 8]);
      const uint4 t1 = *reinterpret_cast<const uint4*>(&tab[(idx + 1) * 256 + dg * 8]);
      const f32x4 p2a = *reinterpret_cast<const f32x4*>(&P2[(e0 + e) * DD + dg * 8]);
      const f32x4 p2b = *reinterpret_cast<const f32x4*>(&P2[(e0 + e) * DD + dg * 8 + 4]);
      float z0 = bf2f_lo(t0.x), z1 = bf2f_hi(t0.x), z2 = bf2f_lo(t0.y), z3 = bf2f_hi(t0.y);
      float z4 = bf2f_lo(t0.z), z5 = bf2f_hi(t0.z), z6 = bf2f_lo(t0.w), z7 = bf2f_hi(t0.w);
      z0 = fmaf(fr, bf2f_lo(t1.x) - z0, z0) + pca[0] + p2a[0];
      z1 = fmaf(fr, bf2f_hi(t1.x) - z1, z1) + pca[1] + p2a[1];
      z2 = fmaf(fr, bf2f_lo(t1.y) - z2, z2) + pca[2] + p2a[2];
      z3 = fmaf(fr, bf2f_hi(t1.y) - z3, z3) + pca[3] + p2a[3];
      z4 = fmaf(fr, bf2f_lo(t1.z) - z4, z4) + pcb[0] + p2b[0];
      z5 = fmaf(fr, bf2f_hi(t1.z) - z5, z5) + pcb[1] + p2b[1];
      z6 = fmaf(fr, bf2f_lo(t1.w) - z6, z6) + pcb[2] + p2b[2];
      z7 = fmaf(fr, bf2f_hi(t1.w) - z7, z7) + pcb[3] + p2b[3];
      uint2 lo = pack4(silu(z0), silu(z1), silu(z2), silu(z3));
      uint2 hi = pack4(silu(z4), silu(z5), silu(z6), silu(z7));
      uint4 pk = {lo.x, lo.y, hi.x, hi.y};
      *reinterpret_cast<uint4*>(&ubuf[e * 264 + dg * 8]) = pk;
    }
  }
  __syncthreads();

  // Z = h @ int_w2 + int_b2 -> ubuf
  f32x4 acc[4][4];
  zero_acc4(acc);
  gemm4(acc, wpack + 2 * 65536, ubuf, lane, wv);
  __syncthreads();
#pragma unroll
  for (int mt = 0; mt < 4; ++mt) {
    const int d = d0 + mt * 16 + l4 * 4;
    const f32x4 bb = *reinterpret_cast<const f32x4*>(&int_b2[d]);
#pragma unroll
    for (int nt = 0; nt < 4; ++nt) {
      const int e = nt * 16 + l15;
      *reinterpret_cast<uint2*>(&ubuf[e * 264 + d]) =
          pack4(acc[mt][nt][0] + bb[0], acc[mt][nt][1] + bb[1],
                acc[mt][nt][2] + bb[2], acc[mt][nt][3] + bb[3]);
    }
  }
  __syncthreads();

  // swizzled MFMA-fragment-order store: grp = cc*4 + wv, e = grp*16 + l15
  {
    unsigned short* Zd = Zsw + (size_t)p * 98304 + (size_t)(cc * 4 + wv) * 4096 + lane * 8;
#pragma unroll
    for (int ks = 0; ks < 8; ++ks) {
      *reinterpret_cast<uint4*>(Zd + ks * 512) =
          *reinterpret_cast<const uint4*>(&ubuf[(wv * 16 + l15) * 264 + ks * 32 + l4 * 8]);
    }
  }

  // gate: f_tri[d] += Hpl[p][d] * sum_e sigm(Z@wg + b) * Her[e][d]
  zero_acc4(acc);
  gemm4(acc, wpack + 3 * 65536, ubuf, lane, wv);
#pragma unroll
  for (int mt = 0; mt < 4; ++mt) {
    const int d = d0 + mt * 16 + l4 * 4;
    const f32x4 bb = *reinterpret_cast<const f32x4*>(&wg_b[d]);
    const f32x4 hl = *reinterpret_cast<const f32x4*>(&Hpl[p * DD + d]);
    f32x4 fs = (f32x4){0.f, 0.f, 0.f, 0.f};
#pragma unroll
    for (int nt = 0; nt < 4; ++nt) {
      const int e = e0 + nt * 16 + l15;
      const f32x4 hr = *reinterpret_cast<const f32x4*>(&Her[e * DD + d]);
#pragma unroll
      for (int r = 0; r < 4; ++r)
        fs[r] += sigm(acc[mt][nt][r] + bb[r]) * hr[r];
    }
#pragma unroll
    for (int r = 0; r < 4; ++r) {
      float v = fs[r] * hl[r];
      v += __shfl_xor(v, 1);
      v += __shfl_xor(v, 2);
      v += __shfl_xor(v, 4);
      v += __shfl_xor(v, 8);
      if (l15 == 0) atomicAdd(&ftri[p * DD + d + r], v);
    }
  }
}

// ---------------- fused attention kernel: block = (p, 64-row chunk) ----------------
// scores = (Z_c Wqk + 1*gv^T) Z^T / 16 — gv and 1/16 folded into T.
// col-sums of softmax -> cbufg[p].

__global__ __launch_bounds__(256, 3) void attn_kernel(
    const unsigned short* __restrict__ Zsw, const float* __restrict__ gv,
    const unsigned short* __restrict__ wpack, float* __restrict__ cbufg) {
  __shared__ __align__(16) unsigned short Tc[64 * 264];
  __shared__ float red[256];
  __shared__ float red2[256];
  const int t = threadIdx.x, lane = t & 63, wv = t >> 6;
  const int l15 = lane & 15, l4 = lane >> 4;
  // XCD swizzle: all 6 chunks of one p land on the same XCD (xcd = blk % 8)
  const int xcd = blockIdx.x & 7, inner = blockIdx.x >> 3;
  const int p = (inner / 6) * 8 + xcd, c = inner % 6;
  const unsigned short* Zsp = Zsw + (size_t)p * 98304;
  const unsigned short* wqk = wpack + 4 * 65536;

  // T' = (Zc @ Wqk + gv) / 16, b-frags double-buffered from Zsw
  {
    f32x4 ta[4][4];
#pragma unroll
    for (int mt = 0; mt < 4; ++mt)
#pragma unroll
      for (int nt = 0; nt < 4; ++nt) ta[mt][nt] = (f32x4){0.f, 0.f, 0.f, 0.f};
    const unsigned short* Tb = Zsp + (size_t)(c * 4) * 4096 + lane * 8;
    bf16x8 bcur[4], bnxt[4];
#pragma unroll
    for (int nt = 0; nt < 4; ++nt)
      bcur[nt] = *reinterpret_cast<const bf16x8*>(Tb + nt * 4096);
#pragma unroll
    for (int ks = 0; ks < 8; ++ks) {
      if (ks < 7) {
#pragma unroll
        for (int nt = 0; nt < 4; ++nt)
          bnxt[nt] = *reinterpret_cast<const bf16x8*>(Tb + nt * 4096 + (ks + 1) * 512);
      }
      bf16x8 a[4];
#pragma unroll
      for (int mt = 0; mt < 4; ++mt)
        a[mt] = *reinterpret_cast<const bf16x8*>(wqk + ((ks * 16 + wv * 4 + mt) * 64 + lane) * 8);
#pragma unroll
      for (int nt = 0; nt < 4; ++nt)
#pragma unroll
        for (int mt = 0; mt < 4; ++mt)
          ta[mt][nt] = __builtin_amdgcn_mfma_f32_16x16x32_bf16(a[mt], bcur[nt], ta[mt][nt], 0, 0, 0);
      if (ks < 7) {
#pragma unroll
        for (int nt = 0; nt < 4; ++nt) bcur[nt] = bnxt[nt];
      }
    }
#pragma unroll
    for (int mt = 0; mt < 4; ++mt) {
      const int d = wv * 64 + mt * 16 + l4 * 4;
      const f32x4 gq = *reinterpret_cast<const f32x4*>(&gv[d]);
#pragma unroll
      for (int nt = 0; nt < 4; ++nt) {
        const int e = nt * 16 + l15;
        *reinterpret_cast<uint2*>(&Tc[e * 264 + d]) =
            pack4((ta[mt][nt][0] + gq[0]) * 0.0625f, (ta[mt][nt][1] + gq[1]) * 0.0625f,
                  (ta[mt][nt][2] + gq[2]) * 0.0625f, (ta[mt][nt][3] + gq[3]) * 0.0625f);
      }
    }
  }
  __syncthreads();

  // S = Tc @ Z^T; a-frags from LDS, b-frags rolling 3+3 prefetch from Zsw
  f32x4 sc[4][6];
#pragma unroll
  for (int mt = 0; mt < 4; ++mt)
#pragma unroll
    for (int s = 0; s < 6; ++s) sc[mt][s] = (f32x4){0.f, 0.f, 0.f, 0.f};

  {
    const unsigned short* Sb = Zsp + (size_t)wv * 4096 + lane * 8;
    bf16x8 b0[3], b1[3];
#pragma unroll
    for (int j = 0; j < 3; ++j)
      b0[j] = *reinterpret_cast<const bf16x8*>(Sb + j * 16384);
#pragma unroll
    for (int ks = 0; ks < 8; ++ks) {
#pragma unroll
      for (int j = 0; j < 3; ++j)
        b1[j] = *reinterpret_cast<const bf16x8*>(Sb + (3 + j) * 16384 + ks * 512);
      bf16x8 a[4];
#pragma unroll
      for (int mt = 0; mt < 4; ++mt)
        a[mt] = *reinterpret_cast<const bf16x8*>(&Tc[(mt * 16 + l15) * 264 + ks * 32 + l4 * 8]);
#pragma unroll
      for (int j = 0; j < 3; ++j)
#pragma unroll
        for (int mt = 0; mt < 4; ++mt)
          sc[mt][j] = __builtin_amdgcn_mfma_f32_16x16x32_bf16(a[mt], b0[j], sc[mt][j], 0, 0, 0);
      if (ks < 7) {
#pragma unroll
        for (int j = 0; j < 3; ++j)
          b0[j] = *reinterpret_cast<const bf16x8*>(Sb + j * 16384 + (ks + 1) * 512);
      }
#pragma unroll
      for (int j = 0; j < 3; ++j)
#pragma unroll
        for (int mt = 0; mt < 4; ++mt)
          sc[mt][3 + j] = __builtin_amdgcn_mfma_f32_16x16x32_bf16(a[mt], b1[j], sc[mt][3 + j], 0, 0, 0);
    }
  }

  // softmax over f (384 cols), rows e = mt*16 + l4*4 + r; sc is already scaled
  float rmax[4][4];
#pragma unroll
  for (int mt = 0; mt < 4; ++mt) {
#pragma unroll
    for (int r = 0; r < 4; ++r) {
      float m = -1e30f;
#pragma unroll
      for (int s = 0; s < 6; ++s) m = fmaxf(m, sc[mt][s][r]);
      m = fmaxf(m, __shfl_xor(m, 1));
      m = fmaxf(m, __shfl_xor(m, 2));
      m = fmaxf(m, __shfl_xor(m, 4));
      m = fmaxf(m, __shfl_xor(m, 8));
      rmax[mt][r] = m;
    }
  }
  if (l15 == 0) {
#pragma unroll
    for (int mt = 0; mt < 4; ++mt)
#pragma unroll
      for (int r = 0; r < 4; ++r)
        red[wv * 64 + mt * 16 + l4 * 4 + r] = rmax[mt][r];
  }
  __syncthreads();
#pragma unroll
  for (int mt = 0; mt < 4; ++mt) {
#pragma unroll
    for (int r = 0; r < 4; ++r) {
      const int row = mt * 16 + l4 * 4 + r;
      rmax[mt][r] = fmaxf(fmaxf(red[row], red[64 + row]), fmaxf(red[128 + row], red[192 + row]));
    }
  }

  float rsum[4][4];
#pragma unroll
  for (int mt = 0; mt < 4; ++mt) {
#pragma unroll
    for (int r = 0; r < 4; ++r) {
      float sSum = 0.f;
#pragma unroll
      for (int s = 0; s < 6; ++s) {
        float e = __expf(sc[mt][s][r] - rmax[mt][r]);
        sc[mt][s][r] = e;
        sSum += e;
      }
      sSum += __shfl_xor(sSum, 1);
      sSum += __shfl_xor(sSum, 2);
      sSum += __shfl_xor(sSum, 4);
      sSum += __shfl_xor(sSum, 8);
      rsum[mt][r] = sSum;
    }
  }
  if (l15 == 0) {
#pragma unroll
    for (int mt = 0; mt < 4; ++mt)
#pragma unroll
      for (int r = 0; r < 4; ++r)
        red2[wv * 64 + mt * 16 + l4 * 4 + r] = rsum[mt][r];
  }
  __syncthreads();
  float rinv[4][4];
#pragma unroll
  for (int mt = 0; mt < 4; ++mt) {
#pragma unroll
    for (int r = 0; r < 4; ++r) {
      const int row = mt * 16 + l4 * 4 + r;
      rinv[mt][r] = 1.0f / (red2[row] + red2[64 + row] + red2[128 + row] + red2[192 + row]);
    }
  }

  // column sums of A over this chunk's 64 rows -> cbufg
#pragma unroll
  for (int s = 0; s < 6; ++s) {
    float v = 0.f;
#pragma unroll
    for (int mt = 0; mt < 4; ++mt)
#pragma unroll
      for (int r = 0; r < 4; ++r)
        v += sc[mt][s][r] * rinv[mt][r];
    v += __shfl_xor(v, 16);
    v += __shfl_xor(v, 32);
    if (lane < 16)
      atomicAdd(&cbufg[p * NEPI + s * 64 + wv * 16 + lane], v);
  }
}

// ---------------- output kernel ----------------
// out[p] = (ftri[p] + (c^T Z_p) @ wv + 384*bv) / 384
// Z read from swizzled Zsw — 1 KB contiguous per wave-load.

__global__ __launch_bounds__(256) void out_kernel(
    const unsigned short* __restrict__ Zsw, const float* __restrict__ ftri,
    const float* __restrict__ cbufg, const float* __restrict__ wvw,
    const float* __restrict__ wvb, float* __restrict__ out) {
  __shared__ float cb[NEPI];
  __shared__ float part[16][257];
  __shared__ float u[DD];
  const int p = blockIdx.x, t = threadIdx.x;
  const int lane = t & 63, wv = t >> 6;
  const int l15 = lane & 15, l4 = lane >> 4;
  for (int i = t; i < NEPI; i += 256) cb[i] = cbufg[p * NEPI + i];
  __syncthreads();
  const unsigned short* Zsp = Zsw + (size_t)p * 98304;
  float a16[16];
#pragma unroll
  for (int j = 0; j < 16; ++j) a16[j] = 0.f;
#pragma unroll 4
  for (int grp = 0; grp < 24; ++grp) {
    const float w = cb[grp * 16 + l15];
    const uint4 z0 = *reinterpret_cast<const uint4*>(Zsp + grp * 4096 + wv * 512 + lane * 8);
    const uint4 z1 = *reinterpret_cast<const uint4*>(Zsp + grp * 4096 + (wv + 4) * 512 + lane * 8);
    a16[0] = fmaf(w, bf2f(z0.x & 0xffffu), a16[0]);
    a16[1] = fmaf(w, bf2f(z0.x >> 16), a16[1]);
    a16[2] = fmaf(w, bf2f(z0.y & 0xffffu), a16[2]);
    a16[3] = fmaf(w, bf2f(z0.y >> 16), a16[3]);
    a16[4] = fmaf(w, bf2f(z0.z & 0xffffu), a16[4]);
    a16[5] = fmaf(w, bf2f(z0.z >> 16), a16[5]);
    a16[6] = fmaf(w, bf2f(z0.w & 0xffffu), a16[6]);
    a16[7] = fmaf(w, bf2f(z0.w >> 16), a16[7]);
    a16[8]  = fmaf(w, bf2f(z1.x & 0xffffu), a16[8]);
    a16[9]  = fmaf(w, bf2f(z1.x >> 16), a16[9]);
    a16[10] = fmaf(w, bf2f(z1.y & 0xffffu), a16[10]);
    a16[11] = fmaf(w, bf2f(z1.y >> 16), a16[11]);
    a16[12] = fmaf(w, bf2f(z1.z & 0xffffu), a16[12]);
    a16[13] = fmaf(w, bf2f(z1.z >> 16), a16[13]);
    a16[14] = fmaf(w, bf2f(z1.w & 0xffffu), a16[14]);
    a16[15] = fmaf(w, bf2f(z1.w >> 16), a16[15]);
  }
#pragma unroll
  for (int j = 0; j < 8; ++j) part[l15][wv * 32 + l4 * 8 + j] = a16[j];
#pragma unroll
  for (int j = 0; j < 8; ++j) part[l15][128 + wv * 32 + l4 * 8 + j] = a16[8 + j];
  __syncthreads();
  float uu = 0.f;
#pragma unroll
  for (int g = 0; g < 16; ++g) uu += part[g][t];
  u[t] = uu;
  __syncthreads();
  float acc = ftri[p * DD + t] + 384.0f * wvb[t];
#pragma unroll 8
  for (int d = 0; d < DD; ++d)
    acc = fmaf(u[d], wvw[d * DD + t], acc);
  out[p * DD + t] = acc * (1.0f / 384.0f);
}

// ---------------- launch ----------------

extern "C" void kernel_launch(void* const* d_in, const int* in_sizes, int n_in,
                              void* d_out, int out_size, void* d_ws, size_t ws_size,
                              hipStream_t stream) {
  (void)in_sizes; (void)n_in; (void)out_size; (void)ws_size;
  const float* H = (const float*)d_in[0];
  const float* X = (const float*)d_in[1];
  const float* res_w1 = (const float*)d_in[4];
  const float* res_b1 = (const float*)d_in[5];
  const float* res_w2 = (const float*)d_in[6];
  const float* res_b2 = (const float*)d_in[7];
  const float* atom_w1 = (const float*)d_in[8];
  const float* atom_b1 = (const float*)d_in[9];
  const float* atom_w2 = (const float*)d_in[10];
  const float* atom_b2 = (const float*)d_in[11];
  const float* simw = (const float*)d_in[12];
  const float* int_w1 = (const float*)d_in[13];
  const float* int_b1 = (const float*)d_in[14];
  const float* int_w2 = (const float*)d_in[15];
  const float* int_b2 = (const float*)d_in[16];
  const float* wl = (const float*)d_in[17];
  const float* wr = (const float*)d_in[18];
  const float* wg_w = (const float*)d_in[19];
  const float* wg_b = (const float*)d_in[20];
  const float* wq_w = (const float*)d_in[21];
  const float* wq_b = (const float*)d_in[22];
  const float* wk_w = (const float*)d_in[23];
  const float* wv_w = (const float*)d_in[25];
  const float* wv_b = (const float*)d_in[26];

  char* ws = (char*)d_ws;
  unsigned short* wpack = (unsigned short*)(ws + 0);      //  655360 B (5 slots)
  float* MrF   = (float*)(ws + 655360);
  float* MaF   = (float*)(ws + 917504);
  float* WqkF  = (float*)(ws + 1179648);
  float* wkT   = (float*)(ws + 1441792);
  float* cvec  = (float*)(ws + 1703936);
  float* gv    = (float*)(ws + 1704960);
  float* P1    = (float*)(ws + 1705984);
  float* P2    = (float*)(ws + 2099200);
  float* Hpl   = (float*)(ws + 2492416);
  float* Her   = (float*)(ws + 2885632);
  float* ftri  = (float*)(ws + 3278848);                  //  393216 B
  float* cbufg = (float*)(ws + 3672064);                  //  589824 B
  unsigned short* Zsw = (unsigned short*)(ws + 4261888);  // 75497472 B (MFMA frag order)
  unsigned short* tab = (unsigned short*)(ws + 79759360); //  2097152 B (NTAB x 256 bf16)

  hipMemsetAsync(ftri, 0, 393216 + 589824, stream);       // ftri + cbufg (contiguous)
  hipMemsetAsync(cvec, 0, DD * sizeof(float), stream);
  prep_kernel<<<2184, 256, 0, stream>>>(H, wl, wr, int_w1, res_w2, atom_w2,
                                        res_b2, atom_b2, int_b1, simw, wq_b, wk_w,
                                        Hpl, Her, P1, P2, MrF, MaF, cvec, gv, wkT);
  mm_rows<<<256, 256, 0, stream>>>(wq_w, wkT, WqkF);        // Wqk = wq @ wk^T
  pack_kernel<<<1280, 256, 0, stream>>>(MrF, MaF, int_w2, wg_w, WqkF, wpack);
  tab_kernel<<<NTAB / 64, 256, 0, stream>>>(res_w1, res_b1, atom_w1, atom_b1, wpack, tab);
  pair_kernel<<<2304, 256, 0, stream>>>(X, tab, int_b2, wg_b, wpack, cvec,
                                        P1, P2, Hpl, Her, ftri, Zsw);
  attn_kernel<<<2304, 256, 0, stream>>>(Zsw, gv, wpack, cbufg);
  out_kernel<<<384, 256, 0, stream>>>(Zsw, ftri, cbufg, wv_w, wv_b, (float*)d_out);
  hipMemcpyAsync((float*)d_out + NPAR * DD, H + NPAR * DD,
                 (1024 - NPAR) * DD * sizeof(float), hipMemcpyDeviceToDevice, stream);
}